// Round 1
// baseline (1790.716 us; speedup 1.0000x reference)
//
#include <hip/hip_runtime.h>
#include <cstddef>

#define EPSBN 1e-5f

// ---------------- workspace layout (in floats) ----------------
static constexpr size_t SZ_WT1 = (size_t)4608 * 128;
static constexpr size_t SZ_WT2 = (size_t)1152 * 32;
static constexpr size_t SZ_Y   = (size_t)4 * 128 * 4096;
static constexpr size_t SZ_QK  = (size_t)4 * 4096 * 16;

static constexpr size_t OFF_WT1P = 0;
static constexpr size_t OFF_B1P  = OFF_WT1P + SZ_WT1;
static constexpr size_t OFF_WT1C = OFF_B1P + 128;
static constexpr size_t OFF_B1C  = OFF_WT1C + SZ_WT1;
static constexpr size_t OFF_WT2P = OFF_B1C + 128;
static constexpr size_t OFF_B2P  = OFF_WT2P + SZ_WT2;
static constexpr size_t OFF_WT2C = OFF_B2P + 32;
static constexpr size_t OFF_B2C  = OFF_WT2C + SZ_WT2;
static constexpr size_t OFF_YP   = OFF_B2C + 32;
static constexpr size_t OFF_YC   = OFF_YP + SZ_Y;
static constexpr size_t OFF_Q    = OFF_YC + SZ_Y;
static constexpr size_t OFF_K    = OFF_Q + SZ_QK;
static constexpr size_t OFF_V    = OFF_K + SZ_QK;
static constexpr size_t OFF_P    = OFF_V + SZ_Y;
static constexpr size_t OFF_CC   = OFF_P + SZ_Y;
static constexpr size_t OFF_G    = OFF_CC + SZ_Y;   // [4][128][128]

// ---------------- fold BN into transposed conv weights ----------------
// wt[(c*9+tap)*Cout + o] = w[o][c][tap] * g[o]/sqrt(v[o]+eps)
// bias[o] = b[o] - m[o]*scale
__global__ void prep_conv(const float* __restrict__ w, const float* __restrict__ g,
                          const float* __restrict__ bb, const float* __restrict__ m,
                          const float* __restrict__ v, float* __restrict__ wt,
                          float* __restrict__ bias, int cin9, int cout)
{
    int idx = blockIdx.x * 256 + threadIdx.x;
    if (idx < cout) {
        float sc = g[idx] * rsqrtf(v[idx] + EPSBN);
        bias[idx] = bb[idx] - m[idx] * sc;
    }
    if (idx < cin9 * cout) {
        int o = idx % cout;
        float sc = g[o] * rsqrtf(v[o] + EPSBN);
        wt[idx] = w[o * cin9 + (idx / cout)] * sc;
    }
}

// ---------------- 3x3 conv + folded BN + ReLU (implicit GEMM) ----------------
// grid.x = B*64 (one output row per block), grid.y = COUT/OCB, 256 threads.
template<int CIN, int COUT, int OCB, bool ADD>
__global__ __launch_bounds__(256) void conv3x3_bn_relu(
    const float* __restrict__ xin, const float* __restrict__ wt,
    const float* __restrict__ bias, float* __restrict__ out)
{
    static_assert(OCB == 64 || OCB == 32, "");
    constexpr int OPT = OCB / 16;              // out-channels per thread
    const int row = blockIdx.x;
    const int b = row >> 6, h = row & 63;
    const int obase = blockIdx.y * OCB;
    const int t = threadIdx.x;
    const int pg = t & 15;                     // pixel group: 4 px
    const int og = t >> 4;                     // out-channel group
    const int w0 = pg * 4;

    __shared__ __align__(16) float lds_x[16][3][68];   // 16 in-ch x 3 rows x 66(+2) cols
    __shared__ __align__(16) float lds_w[144][OCB];    // [c*9+tap][o]

    float acc[OPT][4];
#pragma unroll
    for (int o = 0; o < OPT; ++o)
#pragma unroll
        for (int p = 0; p < 4; ++p) acc[o][p] = 0.f;

    for (int cb = 0; cb < CIN; cb += 16) {
        for (int i = t; i < 16 * 3 * 66; i += 256) {
            int c = i / 198;
            int rem = i - c * 198;
            int r = rem / 66;
            int wc = rem - r * 66;
            int hh = h - 1 + r;
            int ww = wc - 1;
            float val = 0.f;
            if ((unsigned)hh < 64u && (unsigned)ww < 64u)
                val = xin[(((size_t)b * CIN + cb + c) * 64 + hh) * 64 + ww];
            lds_x[c][r][wc] = val;
        }
        for (int i = t; i < 144 * OCB; i += 256) {
            int o = i & (OCB - 1);
            int j = i / OCB;
            lds_w[j][o] = wt[((size_t)cb * 9 + j) * COUT + obase + o];
        }
        __syncthreads();
        for (int c = 0; c < 16; ++c) {
#pragma unroll
            for (int kh = 0; kh < 3; ++kh) {
                float4 xa = *(const float4*)&lds_x[c][kh][w0];
                float4 xb = *(const float4*)&lds_x[c][kh][w0 + 4];
                float xv[8] = {xa.x, xa.y, xa.z, xa.w, xb.x, xb.y, xb.z, xb.w};
#pragma unroll
                for (int kw = 0; kw < 3; ++kw) {
                    const float* wrow = &lds_w[c * 9 + kh * 3 + kw][og * OPT];
                    float wv[OPT];
                    if constexpr (OPT == 4) {
                        float4 w4 = *(const float4*)wrow;
                        wv[0] = w4.x; wv[1] = w4.y; wv[2] = w4.z; wv[3] = w4.w;
                    } else {
                        float2 w2 = *(const float2*)wrow;
                        wv[0] = w2.x; wv[1] = w2.y;
                    }
#pragma unroll
                    for (int o = 0; o < OPT; ++o)
#pragma unroll
                        for (int p = 0; p < 4; ++p)
                            acc[o][p] += wv[o] * xv[p + kw];
                }
            }
        }
        __syncthreads();
    }
#pragma unroll
    for (int o = 0; o < OPT; ++o) {
        int oc = obase + og * OPT + o;
        float bv = bias[oc];
#pragma unroll
        for (int p = 0; p < 4; ++p) {
            float val = fmaxf(acc[o][p] + bv, 0.f);
            size_t idx = (((size_t)b * COUT + oc) * 64 + h) * 64 + (w0 + p);
            if (ADD) out[idx] += val; else out[idx] = val;
        }
    }
}

// ---------------- PAM projections: q,k (16) and d (128) as 1x1 convs ----------------
// Q,K stored [b][n][16]; V = d^T stored [b][n][128]. grid (64, B), 256 threads.
__global__ __launch_bounds__(256) void pam_proj(
    const float* __restrict__ yp,
    const float* __restrict__ wb, const float* __restrict__ bbq,
    const float* __restrict__ wc, const float* __restrict__ bck,
    const float* __restrict__ wd, const float* __restrict__ bdv,
    float* __restrict__ Qg, float* __restrict__ Kg, float* __restrict__ Vg)
{
    const int b = blockIdx.y;
    const int n0 = blockIdx.x * 64;
    const int t = threadIdx.x;
    const int px = t & 63;
    const int og = t >> 6;                      // 4 groups of 4 consecutive outs

    __shared__ __align__(16) float lds_y[64][64];     // [c][px]
    __shared__ __align__(16) float lds_w[64][164];    // [c][o] (160 outs, padded)

    float acc[10][4];
#pragma unroll
    for (int s = 0; s < 10; ++s) { acc[s][0] = acc[s][1] = acc[s][2] = acc[s][3] = 0.f; }

    for (int cb = 0; cb < 128; cb += 64) {
        for (int i = t; i < 4096; i += 256) {
            int c = i >> 6, p = i & 63;
            lds_y[c][p] = yp[(((size_t)b * 128 + cb + c) << 12) + n0 + p];
        }
        for (int i = t; i < 160 * 64; i += 256) {
            int c = i & 63, o = i >> 6;
            const float* src = (o < 16) ? (wb + o * 128)
                             : (o < 32) ? (wc + (o - 16) * 128)
                                        : (wd + (o - 32) * 128);
            lds_w[c][o] = src[cb + c];
        }
        __syncthreads();
        for (int c = 0; c < 64; ++c) {
            float yv = lds_y[c][px];
#pragma unroll
            for (int s = 0; s < 10; ++s) {
                const float4 w4 = *(const float4*)&lds_w[c][s * 16 + og * 4];
                acc[s][0] += w4.x * yv; acc[s][1] += w4.y * yv;
                acc[s][2] += w4.z * yv; acc[s][3] += w4.w * yv;
            }
        }
        __syncthreads();
    }
    const int n = n0 + px;
#pragma unroll
    for (int s = 0; s < 10; ++s) {
        const int ob = s * 16 + og * 4;
        const float4 bv4 = *(const float4*)((s == 0) ? (bbq + ob)
                              : (s == 1) ? (bck + ob - 16) : (bdv + ob - 32));
        float4 o4 = make_float4(acc[s][0] + bv4.x, acc[s][1] + bv4.y,
                                acc[s][2] + bv4.z, acc[s][3] + bv4.w);
        if (s == 0)      *(float4*)&Qg[(((size_t)b << 12) + n) * 16 + ob] = o4;
        else if (s == 1) *(float4*)&Kg[(((size_t)b << 12) + n) * 16 + (ob - 16)] = o4;
        else             *(float4*)&Vg[((((size_t)b << 12) + n) << 7) + (ob - 32)] = o4;
    }
}

// ---------------- PAM fused attention (two-pass flash style) ----------------
// grid (64, B), 512 threads. Per block: 64 queries, loop 64-key chunks.
__global__ __launch_bounds__(512) void pam_attn(
    const float* __restrict__ Qg, const float* __restrict__ Kg,
    const float* __restrict__ Vg, const float* __restrict__ yp,
    const float* __restrict__ alpha_p, float* __restrict__ P)
{
    const int b = blockIdx.y;
    const int q0 = blockIdx.x * 64;
    const int t = threadIdx.x;
    const int iA = t & 63, jgA = t >> 6;        // score role: 8 groups x 8 keys
    const int r256 = t & 255;
    const int jh = t >> 8;                      // 0/1: key half for accum role
    const int qp = r256 >> 3, cg = r256 & 7;    // accum role: 2 queries x 16 channels
    const int swz = (cg >> 1) & 3;

    __shared__ __align__(16) float lds_k[64][16];
    __shared__ __align__(16) float lds_v[64][128];   // XOR-swizzled columns
    __shared__ __align__(16) float lds_p[64][64];    // [j][i]

    float qa[16];
    {
        const float* qrow = Qg + (((size_t)b << 12) + q0 + iA) * 16;
#pragma unroll
        for (int c = 0; c < 16; ++c) qa[c] = qrow[c];
    }

    // ---- pass 1: exact row max ----
    float mA = -3.0e38f;
    for (int kk = 0; kk < 64; ++kk) {
        const int k0 = kk * 64;
        for (int i = t; i < 1024; i += 512) {
            int nn = i >> 4, c = i & 15;
            lds_k[nn][c] = Kg[(((size_t)b << 12) + k0 + nn) * 16 + c];
        }
        __syncthreads();
#pragma unroll
        for (int jj = 0; jj < 8; ++jj) {
            const int j = jgA * 8 + jj;
            const float4* kp = (const float4*)&lds_k[j][0];
            float4 k0v = kp[0], k1v = kp[1], k2v = kp[2], k3v = kp[3];
            float s0 = qa[0]*k0v.x + qa[1]*k0v.y + qa[2]*k0v.z + qa[3]*k0v.w;
            float s1 = qa[4]*k1v.x + qa[5]*k1v.y + qa[6]*k1v.z + qa[7]*k1v.w;
            float s2 = qa[8]*k2v.x + qa[9]*k2v.y + qa[10]*k2v.z + qa[11]*k2v.w;
            float s3 = qa[12]*k3v.x + qa[13]*k3v.y + qa[14]*k3v.z + qa[15]*k3v.w;
            mA = fmaxf(mA, (s0 + s1) + (s2 + s3));
        }
        __syncthreads();
    }
    lds_p[jgA][iA] = mA;
    __syncthreads();
    {
        float m = lds_p[0][iA];
#pragma unroll
        for (int g2 = 1; g2 < 8; ++g2) m = fmaxf(m, lds_p[g2][iA]);
        mA = m;
    }

    // ---- pass 2: p = exp(s - m); acc += p * V; l += p ----
    float acc0[16], acc1[16];
#pragma unroll
    for (int ci = 0; ci < 16; ++ci) { acc0[ci] = 0.f; acc1[ci] = 0.f; }
    float l0 = 0.f, l1 = 0.f;

    for (int kk = 0; kk < 64; ++kk) {
        const int k0 = kk * 64;
        for (int i = t; i < 1024; i += 512) {
            int nn = i >> 4, c = i & 15;
            lds_k[nn][c] = Kg[(((size_t)b << 12) + k0 + nn) * 16 + c];
        }
        for (int i = t; i < 8192; i += 512) {
            int j = i >> 7, c = i & 127;
            int cs = c ^ (((c >> 5) & 3) << 2);
            lds_v[j][cs] = Vg[((((size_t)b << 12) + k0 + j) << 7) + c];
        }
        __syncthreads();
#pragma unroll
        for (int jj = 0; jj < 8; ++jj) {
            const int j = jgA * 8 + jj;
            const float4* kp = (const float4*)&lds_k[j][0];
            float4 k0v = kp[0], k1v = kp[1], k2v = kp[2], k3v = kp[3];
            float s0 = qa[0]*k0v.x + qa[1]*k0v.y + qa[2]*k0v.z + qa[3]*k0v.w;
            float s1 = qa[4]*k1v.x + qa[5]*k1v.y + qa[6]*k1v.z + qa[7]*k1v.w;
            float s2 = qa[8]*k2v.x + qa[9]*k2v.y + qa[10]*k2v.z + qa[11]*k2v.w;
            float s3 = qa[12]*k3v.x + qa[13]*k3v.y + qa[14]*k3v.z + qa[15]*k3v.w;
            lds_p[j][iA] = __expf(((s0 + s1) + (s2 + s3)) - mA);
        }
        __syncthreads();
#pragma unroll 4
        for (int jj = 0; jj < 32; ++jj) {
            const int j = jh * 32 + jj;
            const float2 pv = *(const float2*)&lds_p[j][qp * 2];
            l0 += pv.x; l1 += pv.y;
#pragma unroll
            for (int ui = 0; ui < 4; ++ui) {
                const float4 vv = *(const float4*)&lds_v[j][(cg << 4) + ((ui ^ swz) << 2)];
                acc0[ui*4+0] += pv.x * vv.x; acc0[ui*4+1] += pv.x * vv.y;
                acc0[ui*4+2] += pv.x * vv.z; acc0[ui*4+3] += pv.x * vv.w;
                acc1[ui*4+0] += pv.y * vv.x; acc1[ui*4+1] += pv.y * vv.y;
                acc1[ui*4+2] += pv.y * vv.z; acc1[ui*4+3] += pv.y * vv.w;
            }
        }
        __syncthreads();
    }

    // combine the two key halves, then write alpha*(acc/l) + yp
    float* red  = &lds_v[0][0];
    float* redl = &lds_p[0][0];
    const int slot = ((qp << 3) + cg) << 5;
    if (jh == 1) {
#pragma unroll
        for (int ci = 0; ci < 16; ++ci) { red[slot + ci] = acc0[ci]; red[slot + 16 + ci] = acc1[ci]; }
        redl[((qp << 3) + cg) * 2 + 0] = l0;
        redl[((qp << 3) + cg) * 2 + 1] = l1;
    }
    __syncthreads();
    if (jh == 0) {
#pragma unroll
        for (int ci = 0; ci < 16; ++ci) { acc0[ci] += red[slot + ci]; acc1[ci] += red[slot + 16 + ci]; }
        l0 += redl[((qp << 3) + cg) * 2 + 0];
        l1 += redl[((qp << 3) + cg) * 2 + 1];
        const float al = alpha_p[0];
        const float inv0 = 1.f / l0, inv1 = 1.f / l1;
        const int n0q = q0 + (qp << 1);
#pragma unroll
        for (int ci = 0; ci < 16; ++ci) {
            const int c = (cg << 4) + ci;
            const size_t base = (((size_t)b << 7) + c) << 12;
            const float2 ypv = *(const float2*)&yp[base + n0q];
            float2 o2;
            o2.x = al * (acc0[ci] * inv0) + ypv.x;
            o2.y = al * (acc1[ci] * inv1) + ypv.y;
            *(float2*)&P[base + n0q] = o2;
        }
    }
}

// ---------------- CAM: Gram matrix (split over n, atomic accumulate) ----------------
// grid (32, B): 128 positions per block. G must be zeroed beforehand.
__global__ __launch_bounds__(256) void cam_gram(const float* __restrict__ yc, float* __restrict__ G)
{
    const int b = blockIdx.y;
    const int n0 = blockIdx.x * 128;
    const int t = threadIdx.x;
    const int rg = t & 15, cgg = t >> 4;
    __shared__ float a_t[64][133];               // [n][c], padded
    float acc[8][8];
#pragma unroll
    for (int r = 0; r < 8; ++r)
#pragma unroll
        for (int c = 0; c < 8; ++c) acc[r][c] = 0.f;

    for (int ch = 0; ch < 2; ++ch) {
        const int nb = n0 + ch * 64;
        for (int i = t; i < 8192; i += 256) {
            int c = i >> 6, nn = i & 63;
            a_t[nn][c] = yc[(((size_t)b * 128 + c) << 12) + nb + nn];
        }
        __syncthreads();
        for (int nn = 0; nn < 64; ++nn) {
            float av[8], bv[8];
#pragma unroll
            for (int u = 0; u < 8; ++u) av[u] = a_t[nn][rg * 8 + u];
#pragma unroll
            for (int u = 0; u < 8; ++u) bv[u] = a_t[nn][cgg * 8 + u];
#pragma unroll
            for (int r = 0; r < 8; ++r)
#pragma unroll
                for (int c = 0; c < 8; ++c)
                    acc[r][c] += av[r] * bv[c];
        }
        __syncthreads();
    }
#pragma unroll
    for (int r = 0; r < 8; ++r)
#pragma unroll
        for (int c = 0; c < 8; ++c)
            atomicAdd(&G[((size_t)b << 14) + (size_t)(rg * 8 + r) * 128 + cgg * 8 + c], acc[r][c]);
}

// ---------------- CAM: softmax(max-g) rows + apply + beta residual ----------------
// grid.x = 32: (cchunk 0..3)<<3 | ns 0..7 ; grid.y = B. 256 threads.
__global__ __launch_bounds__(256) void cam_apply(
    const float* __restrict__ G, const float* __restrict__ yc,
    const float* __restrict__ beta_p, float* __restrict__ Cc)
{
    const int b = blockIdx.y;
    const int cchunk = blockIdx.x >> 3;
    const int ns = blockIdx.x & 7;
    const int t = threadIdx.x;

    __shared__ float att_t[128][32];             // transposed att rows (local)
    __shared__ float s_buf[128 * 64];            // phase1: gram rows; phase2: yc tile

    for (int i = t; i < 4096; i += 256)
        s_buf[i] = G[((size_t)b << 14) + (size_t)cchunk * 32 * 128 + i];
    __syncthreads();
    {
        // softmax(max_d g - g) over d  ==  exp(min_d g - g_d) / sum
        const int r = t >> 3, seg = t & 7;
        float vals[16];
        float gmin = 3.0e38f;
#pragma unroll
        for (int u = 0; u < 16; ++u) {
            vals[u] = s_buf[r * 128 + seg * 16 + u];
            gmin = fminf(gmin, vals[u]);
        }
        gmin = fminf(gmin, __shfl_xor(gmin, 1));
        gmin = fminf(gmin, __shfl_xor(gmin, 2));
        gmin = fminf(gmin, __shfl_xor(gmin, 4));
        float sum = 0.f;
#pragma unroll
        for (int u = 0; u < 16; ++u) { vals[u] = __expf(gmin - vals[u]); sum += vals[u]; }
        sum += __shfl_xor(sum, 1);
        sum += __shfl_xor(sum, 2);
        sum += __shfl_xor(sum, 4);
        const float inv = 1.f / sum;
#pragma unroll
        for (int u = 0; u < 16; ++u)
            att_t[seg * 16 + u][r] = vals[u] * inv;
    }
    __syncthreads();

    const float be = beta_p[0];
    const int nc = t & 31, cgp = t >> 5;         // cols (nc, nc+32); 4 channels
    for (int chunk = 0; chunk < 8; ++chunk) {
        const int nb = ns * 512 + chunk * 64;
        for (int i = t; i < 8192; i += 256) {
            int d = i >> 6, nn = i & 63;
            s_buf[d * 64 + nn] = yc[(((size_t)b * 128 + d) << 12) + nb + nn];
        }
        __syncthreads();
        float a0[4] = {0, 0, 0, 0}, a1[4] = {0, 0, 0, 0};
        for (int d = 0; d < 128; ++d) {
            const float y0 = s_buf[d * 64 + nc];
            const float y1 = s_buf[d * 64 + nc + 32];
#pragma unroll
            for (int o = 0; o < 4; ++o) {
                const float wv = att_t[d][cgp * 4 + o];
                a0[o] += wv * y0; a1[o] += wv * y1;
            }
        }
#pragma unroll
        for (int o = 0; o < 4; ++o) {
            const int cl = cgp * 4 + o;
            const int c = cchunk * 32 + cl;
            const size_t base = (((size_t)b * 128 + c) << 12) + nb;
            Cc[base + nc]      = be * a0[o] + s_buf[c * 64 + nc];
            Cc[base + nc + 32] = be * a1[o] + s_buf[c * 64 + nc + 32];
        }
        __syncthreads();
    }
}

// ---------------- launcher ----------------
extern "C" void kernel_launch(void* const* d_in, const int* in_sizes, int n_in,
                              void* d_out, int out_size, void* d_ws, size_t ws_size,
                              hipStream_t stream)
{
    (void)in_sizes; (void)n_in; (void)out_size; (void)ws_size;
    const float* x    = (const float*)d_in[0];
    const float* wp1  = (const float*)d_in[1];
    const float* gp1  = (const float*)d_in[2];
    const float* bp1  = (const float*)d_in[3];
    const float* mp1  = (const float*)d_in[4];
    const float* vp1  = (const float*)d_in[5];
    const float* wc1  = (const float*)d_in[6];
    const float* gc1  = (const float*)d_in[7];
    const float* bc1  = (const float*)d_in[8];
    const float* mc1  = (const float*)d_in[9];
    const float* vc1  = (const float*)d_in[10];
    const float* pwb  = (const float*)d_in[11];
    const float* pbb  = (const float*)d_in[12];
    const float* pwc  = (const float*)d_in[13];
    const float* pbc  = (const float*)d_in[14];
    const float* pwd  = (const float*)d_in[15];
    const float* pbd  = (const float*)d_in[16];
    const float* alpha= (const float*)d_in[17];
    const float* beta = (const float*)d_in[18];
    const float* wp2  = (const float*)d_in[19];
    const float* gp2  = (const float*)d_in[20];
    const float* bp2  = (const float*)d_in[21];
    const float* mp2  = (const float*)d_in[22];
    const float* vp2  = (const float*)d_in[23];
    const float* wc2  = (const float*)d_in[24];
    const float* gc2  = (const float*)d_in[25];
    const float* bc2  = (const float*)d_in[26];
    const float* mc2  = (const float*)d_in[27];
    const float* vc2  = (const float*)d_in[28];

    float* W = (float*)d_ws;
    float* wt1p = W + OFF_WT1P;  float* b1p = W + OFF_B1P;
    float* wt1c = W + OFF_WT1C;  float* b1c = W + OFF_B1C;
    float* wt2p = W + OFF_WT2P;  float* b2p = W + OFF_B2P;
    float* wt2c = W + OFF_WT2C;  float* b2c = W + OFF_B2C;
    float* yp   = W + OFF_YP;
    float* yc   = W + OFF_YC;
    float* Qg   = W + OFF_Q;
    float* Kg   = W + OFF_K;
    float* Vg   = W + OFF_V;
    float* Pp   = W + OFF_P;
    float* Cc   = W + OFF_CC;
    float* G    = W + OFF_G;
    float* out  = (float*)d_out;

    // ws is poisoned 0xAA each call: zero the atomic Gram accumulator.
    hipMemsetAsync(G, 0, (size_t)4 * 128 * 128 * sizeof(float), stream);

    prep_conv<<<2304, 256, 0, stream>>>(wp1, gp1, bp1, mp1, vp1, wt1p, b1p, 4608, 128);
    prep_conv<<<2304, 256, 0, stream>>>(wc1, gc1, bc1, mc1, vc1, wt1c, b1c, 4608, 128);
    prep_conv<<<144,  256, 0, stream>>>(wp2, gp2, bp2, mp2, vp2, wt2p, b2p, 1152, 32);
    prep_conv<<<144,  256, 0, stream>>>(wc2, gc2, bc2, mc2, vc2, wt2c, b2c, 1152, 32);

    conv3x3_bn_relu<512, 128, 64, false><<<dim3(256, 2), 256, 0, stream>>>(x, wt1p, b1p, yp);
    conv3x3_bn_relu<512, 128, 64, false><<<dim3(256, 2), 256, 0, stream>>>(x, wt1c, b1c, yc);

    pam_proj<<<dim3(64, 4), 256, 0, stream>>>(yp, pwb, pbb, pwc, pbc, pwd, pbd, Qg, Kg, Vg);
    pam_attn<<<dim3(64, 4), 512, 0, stream>>>(Qg, Kg, Vg, yp, alpha, Pp);

    cam_gram <<<dim3(32, 4), 256, 0, stream>>>(yc, G);
    cam_apply<<<dim3(32, 4), 256, 0, stream>>>(G, yc, beta, Cc);

    conv3x3_bn_relu<128, 32, 32, false><<<dim3(256, 1), 256, 0, stream>>>(Pp, wt2p, b2p, out);
    conv3x3_bn_relu<128, 32, 32, true ><<<dim3(256, 1), 256, 0, stream>>>(Cc, wt2c, b2c, out);
}

// Round 2
// 1131.547 us; speedup vs baseline: 1.5825x; 1.5825x over previous
//
#include <hip/hip_runtime.h>
#include <cstddef>
#include <cstdint>

#define EPSBN 1e-5f

typedef __attribute__((ext_vector_type(8))) __bf16 bf16x8;
typedef __attribute__((ext_vector_type(8))) short short8v;
typedef __attribute__((ext_vector_type(4))) float f32x4;

// ---------------- workspace layout (in floats) ----------------
static constexpr size_t SZ_WB2 = 294912;     // 4608*128 ushorts / 2
static constexpr size_t SZ_WT2 = 36864;      // 1152*32
static constexpr size_t SZ_Y   = 2097152;    // 4*128*4096
static constexpr size_t SZ_QK  = 262144;     // 4*4096*16

static constexpr size_t OFF_WB2P = 0;
static constexpr size_t OFF_B1P  = OFF_WB2P + SZ_WB2;
static constexpr size_t OFF_WB2C = OFF_B1P + 128;
static constexpr size_t OFF_B1C  = OFF_WB2C + SZ_WB2;
static constexpr size_t OFF_WT2P = OFF_B1C + 128;
static constexpr size_t OFF_B2P  = OFF_WT2P + SZ_WT2;
static constexpr size_t OFF_WT2C = OFF_B2P + 32;
static constexpr size_t OFF_B2C  = OFF_WT2C + SZ_WT2;
static constexpr size_t OFF_YP   = OFF_B2C + 32;
static constexpr size_t OFF_YC   = OFF_YP + SZ_Y;
static constexpr size_t OFF_Q    = OFF_YC + SZ_Y;
static constexpr size_t OFF_K    = OFF_Q + SZ_QK;
static constexpr size_t OFF_V    = OFF_K + SZ_QK;
static constexpr size_t OFF_P    = OFF_V + SZ_Y;
static constexpr size_t OFF_CC   = OFF_P + SZ_Y;
static constexpr size_t OFF_G    = OFF_CC + SZ_Y;   // [4][128][128]
static constexpr size_t OFF_Z    = OFF_G + 65536;   // 16KB zero scratch
// xT (bf16, 8388608 ushorts = 4194304 floats) ALIASES [OFF_P, OFF_P+2*SZ_Y):
// it is only live during conv1_mfma; P and Cc are written strictly later.

__device__ __forceinline__ unsigned short f2bf(float f) {
    unsigned u = __float_as_uint(f);
    unsigned r = (u + 0x7fffu + ((u >> 16) & 1u)) >> 16;
    return (unsigned short)r;
}

__device__ __forceinline__ void gload_lds16(const void* g, void* l) {
    __builtin_amdgcn_global_load_lds((const __attribute__((address_space(1))) void*)g,
                                     (__attribute__((address_space(3))) void*)l, 16, 0, 0);
}

// ---------------- x (fp32 NCHW) -> xT (bf16 [b][h][w][c]) ----------------
__global__ __launch_bounds__(256) void x_transpose(const float* __restrict__ x,
                                                   unsigned short* __restrict__ xT)
{
    const int h = blockIdx.x, b = blockIdx.y, cb0 = blockIdx.z * 128;
    __shared__ float tile[64][129];
    const int t = threadIdx.x;
    for (int i = t; i < 8192; i += 256) {
        int c = i >> 6, w = i & 63;
        tile[w][c] = x[(((size_t)(b * 512 + cb0 + c) * 64) + h) * 64 + w];
    }
    __syncthreads();
    for (int i = t; i < 8192; i += 256) {
        int w = i >> 7, c = i & 127;
        xT[(((size_t)(b * 64 + h) * 64) + w) * 512 + cb0 + c] = f2bf(tile[w][c]);
    }
}

// ---------------- fold BN into conv1 weights, bf16, staged layout ----------------
// wb2 element order: [kh][cblk16][kw][u512][j8], u = oc*4 + (g ^ ((oc>>1)&3)),
// channel c = cblk*32 + g*8 + j. This is exactly the linear order conv1_mfma's
// global_load_lds stages, so staging loads are contiguous (swizzle pre-baked).
__global__ void prep_conv_mfma(const float* __restrict__ w, const float* __restrict__ g,
                               const float* __restrict__ bb, const float* __restrict__ m,
                               const float* __restrict__ v, unsigned short* __restrict__ wb2,
                               float* __restrict__ bias)
{
    int idx = blockIdx.x * 256 + threadIdx.x;
    if (idx < 128) {
        float sc = g[idx] * rsqrtf(v[idx] + EPSBN);
        bias[idx] = bb[idx] - m[idx] * sc;
    }
    if (idx >= 128 * 4608) return;
    int oc = idx / 4608;
    int rem = idx - oc * 4608;
    int c = rem / 9;
    int tap = rem - c * 9;
    int kh = tap / 3, kw = tap - kh * 3;
    float sc = g[oc] * rsqrtf(v[oc] + EPSBN);
    float val = w[idx] * sc;
    int u = (oc << 2) + (((c >> 3) & 3) ^ ((oc >> 1) & 3));
    size_t dst = ((size_t)((kh * 16 + (c >> 5)) * 3 + kw) * 512 + u) * 8 + (c & 7);
    wb2[dst] = f2bf(val);
}

// ---------------- conv1 (512->128, 3x3) via bf16 MFMA implicit GEMM ----------------
// grid (128, 2): x = b*32 + rowpair, y = conv select. 256 thr / 4 waves.
// Block tile: 128 oc x 128 px (2 image rows). Wave tile 64x64 (4 M-frag x 4 N-frag).
__global__ __launch_bounds__(256) void conv1_mfma(
    const unsigned short* __restrict__ xT,
    const unsigned short* __restrict__ wb2p, const unsigned short* __restrict__ wb2c,
    const float* __restrict__ b1p, const float* __restrict__ b1c,
    float* __restrict__ yp, float* __restrict__ yc,
    const unsigned short* __restrict__ zbuf)
{
    const int b = blockIdx.x >> 5;
    const int h0 = (blockIdx.x & 31) * 2;
    const bool isC = blockIdx.y != 0;
    const unsigned short* __restrict__ wb2 = isC ? wb2c : wb2p;
    const float* __restrict__ bias = isC ? b1c : b1p;
    float* __restrict__ y = isC ? yc : yp;

    const int t = threadIdx.x;
    const int wid = t >> 6, lane = t & 63;
    const int lhi = lane >> 4, llo = lane & 15;
    const int mrow = wid & 1, ncol = wid >> 1;

    __shared__ __align__(16) unsigned short lds_x[8192];   // 4 rows x (64 col x 4 g) x 8ch
    __shared__ __align__(16) unsigned short lds_w[12288];  // 3 kw x 512 u x 8ch

    f32x4 acc[4][4];
#pragma unroll
    for (int i = 0; i < 4; ++i)
#pragma unroll
        for (int j = 0; j < 4; ++j) acc[i][j] = (f32x4)0.0f;

    for (int cc = 0; cc < 16; ++cc) {
        const int cb = cc * 32;
        __syncthreads();   // protect LDS from previous iteration's readers
        // stage x: rows h0-1 .. h0+2, ch-contiguous 16B units, swizzle in src order
        for (int i = wid; i < 16; i += 4) {
            const int u = (i << 6) + lane;
            const int row = u >> 8;
            const int col = (u >> 2) & 63;
            const int g2 = (u & 3) ^ ((col >> 1) & 3);
            const int xrow = h0 - 1 + row;
            const unsigned short* src = ((unsigned)xrow < 64u)
                ? xT + (((size_t)((b << 6) + xrow) << 6) + col) * 512 + cb + (g2 << 3)
                : zbuf;
            gload_lds16(src, &lds_x[(size_t)i << 9]);
        }
        // stage w for kh = 0
        {
            const unsigned short* ws = wb2 + (size_t)(cc) * 1536 * 8;
            for (int i = wid; i < 24; i += 4)
                gload_lds16(ws + ((size_t)((i << 6) + lane) << 3), &lds_w[(size_t)i << 9]);
        }
        for (int kh = 0; kh < 3; ++kh) {
            if (kh) {
                __syncthreads();   // previous kh's reads done
                const unsigned short* ws = wb2 + (size_t)(kh * 16 + cc) * 1536 * 8;
                for (int i = wid; i < 24; i += 4)
                    gload_lds16(ws + ((size_t)((i << 6) + lane) << 3), &lds_w[(size_t)i << 9]);
            }
            __syncthreads();       // staged data visible (compiler drains vmcnt)
#pragma unroll
            for (int kw = 0; kw < 3; ++kw) {
                bf16x8 afr[4];
#pragma unroll
                for (int mf = 0; mf < 4; ++mf) {
                    const int oc = (mrow << 6) + (mf << 4) + llo;
                    const int un = (kw << 9) + (oc << 2) + (lhi ^ ((oc >> 1) & 3));
                    afr[mf] = *(const bf16x8*)&lds_x[0 + 0];  // placeholder overwritten below
                    afr[mf] = *(const bf16x8*)&lds_w[un << 3];
                }
                bf16x8 bfr[4];
#pragma unroll
                for (int nf = 0; nf < 4; ++nf) {
                    const int px = (nf << 4) + llo;
                    const int wc = px + kw - 1;
                    const bool inb = (unsigned)wc < 64u;
                    const int wcc = inb ? wc : 0;
                    const int un = ((((ncol + kh) << 6) + wcc) << 2) + (lhi ^ ((wcc >> 1) & 3));
                    short8v raw = *(const short8v*)&lds_x[un << 3];
                    short8v zz = {};
                    if (!inb) raw = zz;
                    bfr[nf] = __builtin_bit_cast(bf16x8, raw);
                }
#pragma unroll
                for (int mf = 0; mf < 4; ++mf)
#pragma unroll
                    for (int nf = 0; nf < 4; ++nf)
                        acc[mf][nf] = __builtin_amdgcn_mfma_f32_16x16x32_bf16(
                            afr[mf], bfr[nf], acc[mf][nf], 0, 0, 0);
            }
        }
    }

    // epilogue: bias + ReLU, coalesced 16-lane runs
    const int hout = h0 + ncol;
#pragma unroll
    for (int mf = 0; mf < 4; ++mf) {
#pragma unroll
        for (int r = 0; r < 4; ++r) {
            const int oc = (mrow << 6) + (mf << 4) + (lhi << 2) + r;
            const float bv = bias[oc];
            float* dst = y + (((size_t)(b * 128 + oc) << 6) + hout) * 64;
#pragma unroll
            for (int nf = 0; nf < 4; ++nf) {
                const int colw = (nf << 4) + llo;
                dst[colw] = fmaxf(acc[mf][nf][r] + bv, 0.f);
            }
        }
    }
}

// ---------------- fold BN into transposed conv weights (conv2 path) ----------------
__global__ void prep_conv(const float* __restrict__ w, const float* __restrict__ g,
                          const float* __restrict__ bb, const float* __restrict__ m,
                          const float* __restrict__ v, float* __restrict__ wt,
                          float* __restrict__ bias, int cin9, int cout)
{
    int idx = blockIdx.x * 256 + threadIdx.x;
    if (idx < cout) {
        float sc = g[idx] * rsqrtf(v[idx] + EPSBN);
        bias[idx] = bb[idx] - m[idx] * sc;
    }
    if (idx < cin9 * cout) {
        int o = idx % cout;
        float sc = g[o] * rsqrtf(v[o] + EPSBN);
        wt[idx] = w[o * cin9 + (idx / cout)] * sc;
    }
}

// ---------------- 3x3 conv + folded BN + ReLU (fp32, conv2 only) ----------------
template<int CIN, int COUT, int OCB, bool ADD>
__global__ __launch_bounds__(256) void conv3x3_bn_relu(
    const float* __restrict__ xin, const float* __restrict__ wt,
    const float* __restrict__ bias, float* __restrict__ out)
{
    static_assert(OCB == 64 || OCB == 32, "");
    constexpr int OPT = OCB / 16;
    const int row = blockIdx.x;
    const int b = row >> 6, h = row & 63;
    const int obase = blockIdx.y * OCB;
    const int t = threadIdx.x;
    const int pg = t & 15;
    const int og = t >> 4;
    const int w0 = pg * 4;

    __shared__ __align__(16) float lds_x[16][3][68];
    __shared__ __align__(16) float lds_w[144][OCB];

    float acc[OPT][4];
#pragma unroll
    for (int o = 0; o < OPT; ++o)
#pragma unroll
        for (int p = 0; p < 4; ++p) acc[o][p] = 0.f;

    for (int cb = 0; cb < CIN; cb += 16) {
        for (int i = t; i < 16 * 3 * 66; i += 256) {
            int c = i / 198;
            int rem = i - c * 198;
            int r = rem / 66;
            int wc = rem - r * 66;
            int hh = h - 1 + r;
            int ww = wc - 1;
            float val = 0.f;
            if ((unsigned)hh < 64u && (unsigned)ww < 64u)
                val = xin[(((size_t)b * CIN + cb + c) * 64 + hh) * 64 + ww];
            lds_x[c][r][wc] = val;
        }
        for (int i = t; i < 144 * OCB; i += 256) {
            int o = i & (OCB - 1);
            int j = i / OCB;
            lds_w[j][o] = wt[((size_t)cb * 9 + j) * COUT + obase + o];
        }
        __syncthreads();
        for (int c = 0; c < 16; ++c) {
#pragma unroll
            for (int kh = 0; kh < 3; ++kh) {
                float4 xa = *(const float4*)&lds_x[c][kh][w0];
                float4 xb = *(const float4*)&lds_x[c][kh][w0 + 4];
                float xv[8] = {xa.x, xa.y, xa.z, xa.w, xb.x, xb.y, xb.z, xb.w};
#pragma unroll
                for (int kw = 0; kw < 3; ++kw) {
                    const float* wrow = &lds_w[c * 9 + kh * 3 + kw][og * OPT];
                    float wv[OPT];
                    if constexpr (OPT == 4) {
                        float4 w4 = *(const float4*)wrow;
                        wv[0] = w4.x; wv[1] = w4.y; wv[2] = w4.z; wv[3] = w4.w;
                    } else {
                        float2 w2 = *(const float2*)wrow;
                        wv[0] = w2.x; wv[1] = w2.y;
                    }
#pragma unroll
                    for (int o = 0; o < OPT; ++o)
#pragma unroll
                        for (int p = 0; p < 4; ++p)
                            acc[o][p] += wv[o] * xv[p + kw];
                }
            }
        }
        __syncthreads();
    }
#pragma unroll
    for (int o = 0; o < OPT; ++o) {
        int oc = obase + og * OPT + o;
        float bv = bias[oc];
#pragma unroll
        for (int p = 0; p < 4; ++p) {
            float val = fmaxf(acc[o][p] + bv, 0.f);
            size_t idx = (((size_t)b * COUT + oc) * 64 + h) * 64 + (w0 + p);
            if (ADD) out[idx] += val; else out[idx] = val;
        }
    }
}

// ---------------- PAM projections ----------------
__global__ __launch_bounds__(256) void pam_proj(
    const float* __restrict__ yp,
    const float* __restrict__ wb, const float* __restrict__ bbq,
    const float* __restrict__ wc, const float* __restrict__ bck,
    const float* __restrict__ wd, const float* __restrict__ bdv,
    float* __restrict__ Qg, float* __restrict__ Kg, float* __restrict__ Vg)
{
    const int b = blockIdx.y;
    const int n0 = blockIdx.x * 64;
    const int t = threadIdx.x;
    const int px = t & 63;
    const int og = t >> 6;

    __shared__ __align__(16) float lds_y[64][64];
    __shared__ __align__(16) float lds_w[64][164];

    float acc[10][4];
#pragma unroll
    for (int s = 0; s < 10; ++s) { acc[s][0] = acc[s][1] = acc[s][2] = acc[s][3] = 0.f; }

    for (int cb = 0; cb < 128; cb += 64) {
        for (int i = t; i < 4096; i += 256) {
            int c = i >> 6, p = i & 63;
            lds_y[c][p] = yp[(((size_t)b * 128 + cb + c) << 12) + n0 + p];
        }
        for (int i = t; i < 160 * 64; i += 256) {
            int c = i & 63, o = i >> 6;
            const float* src = (o < 16) ? (wb + o * 128)
                             : (o < 32) ? (wc + (o - 16) * 128)
                                        : (wd + (o - 32) * 128);
            lds_w[c][o] = src[cb + c];
        }
        __syncthreads();
        for (int c = 0; c < 64; ++c) {
            float yv = lds_y[c][px];
#pragma unroll
            for (int s = 0; s < 10; ++s) {
                const float4 w4 = *(const float4*)&lds_w[c][s * 16 + og * 4];
                acc[s][0] += w4.x * yv; acc[s][1] += w4.y * yv;
                acc[s][2] += w4.z * yv; acc[s][3] += w4.w * yv;
            }
        }
        __syncthreads();
    }
    const int n = n0 + px;
#pragma unroll
    for (int s = 0; s < 10; ++s) {
        const int ob = s * 16 + og * 4;
        const float4 bv4 = *(const float4*)((s == 0) ? (bbq + ob)
                              : (s == 1) ? (bck + ob - 16) : (bdv + ob - 32));
        float4 o4 = make_float4(acc[s][0] + bv4.x, acc[s][1] + bv4.y,
                                acc[s][2] + bv4.z, acc[s][3] + bv4.w);
        if (s == 0)      *(float4*)&Qg[(((size_t)b << 12) + n) * 16 + ob] = o4;
        else if (s == 1) *(float4*)&Kg[(((size_t)b << 12) + n) * 16 + (ob - 16)] = o4;
        else             *(float4*)&Vg[((((size_t)b << 12) + n) << 7) + (ob - 32)] = o4;
    }
}

// ---------------- PAM fused attention (two-pass flash style) ----------------
__global__ __launch_bounds__(512) void pam_attn(
    const float* __restrict__ Qg, const float* __restrict__ Kg,
    const float* __restrict__ Vg, const float* __restrict__ yp,
    const float* __restrict__ alpha_p, float* __restrict__ P)
{
    const int b = blockIdx.y;
    const int q0 = blockIdx.x * 64;
    const int t = threadIdx.x;
    const int iA = t & 63, jgA = t >> 6;
    const int r256 = t & 255;
    const int jh = t >> 8;
    const int qp = r256 >> 3, cg = r256 & 7;
    const int swz = (cg >> 1) & 3;

    __shared__ __align__(16) float lds_k[64][16];
    __shared__ __align__(16) float lds_v[64][128];
    __shared__ __align__(16) float lds_p[64][64];

    float qa[16];
    {
        const float* qrow = Qg + (((size_t)b << 12) + q0 + iA) * 16;
#pragma unroll
        for (int c = 0; c < 16; ++c) qa[c] = qrow[c];
    }

    float mA = -3.0e38f;
    for (int kk = 0; kk < 64; ++kk) {
        const int k0 = kk * 64;
        for (int i = t; i < 1024; i += 512) {
            int nn = i >> 4, c = i & 15;
            lds_k[nn][c] = Kg[(((size_t)b << 12) + k0 + nn) * 16 + c];
        }
        __syncthreads();
#pragma unroll
        for (int jj = 0; jj < 8; ++jj) {
            const int j = jgA * 8 + jj;
            const float4* kp = (const float4*)&lds_k[j][0];
            float4 k0v = kp[0], k1v = kp[1], k2v = kp[2], k3v = kp[3];
            float s0 = qa[0]*k0v.x + qa[1]*k0v.y + qa[2]*k0v.z + qa[3]*k0v.w;
            float s1 = qa[4]*k1v.x + qa[5]*k1v.y + qa[6]*k1v.z + qa[7]*k1v.w;
            float s2 = qa[8]*k2v.x + qa[9]*k2v.y + qa[10]*k2v.z + qa[11]*k2v.w;
            float s3 = qa[12]*k3v.x + qa[13]*k3v.y + qa[14]*k3v.z + qa[15]*k3v.w;
            mA = fmaxf(mA, (s0 + s1) + (s2 + s3));
        }
        __syncthreads();
    }
    lds_p[jgA][iA] = mA;
    __syncthreads();
    {
        float m = lds_p[0][iA];
#pragma unroll
        for (int g2 = 1; g2 < 8; ++g2) m = fmaxf(m, lds_p[g2][iA]);
        mA = m;
    }

    float acc0[16], acc1[16];
#pragma unroll
    for (int ci = 0; ci < 16; ++ci) { acc0[ci] = 0.f; acc1[ci] = 0.f; }
    float l0 = 0.f, l1 = 0.f;

    for (int kk = 0; kk < 64; ++kk) {
        const int k0 = kk * 64;
        for (int i = t; i < 1024; i += 512) {
            int nn = i >> 4, c = i & 15;
            lds_k[nn][c] = Kg[(((size_t)b << 12) + k0 + nn) * 16 + c];
        }
        for (int i = t; i < 8192; i += 512) {
            int j = i >> 7, c = i & 127;
            int cs = c ^ (((c >> 5) & 3) << 2);
            lds_v[j][cs] = Vg[((((size_t)b << 12) + k0 + j) << 7) + c];
        }
        __syncthreads();
#pragma unroll
        for (int jj = 0; jj < 8; ++jj) {
            const int j = jgA * 8 + jj;
            const float4* kp = (const float4*)&lds_k[j][0];
            float4 k0v = kp[0], k1v = kp[1], k2v = kp[2], k3v = kp[3];
            float s0 = qa[0]*k0v.x + qa[1]*k0v.y + qa[2]*k0v.z + qa[3]*k0v.w;
            float s1 = qa[4]*k1v.x + qa[5]*k1v.y + qa[6]*k1v.z + qa[7]*k1v.w;
            float s2 = qa[8]*k2v.x + qa[9]*k2v.y + qa[10]*k2v.z + qa[11]*k2v.w;
            float s3 = qa[12]*k3v.x + qa[13]*k3v.y + qa[14]*k3v.z + qa[15]*k3v.w;
            lds_p[j][iA] = __expf(((s0 + s1) + (s2 + s3)) - mA);
        }
        __syncthreads();
#pragma unroll 4
        for (int jj = 0; jj < 32; ++jj) {
            const int j = jh * 32 + jj;
            const float2 pv = *(const float2*)&lds_p[j][qp * 2];
            l0 += pv.x; l1 += pv.y;
#pragma unroll
            for (int ui = 0; ui < 4; ++ui) {
                const float4 vv = *(const float4*)&lds_v[j][(cg << 4) + ((ui ^ swz) << 2)];
                acc0[ui*4+0] += pv.x * vv.x; acc0[ui*4+1] += pv.x * vv.y;
                acc0[ui*4+2] += pv.x * vv.z; acc0[ui*4+3] += pv.x * vv.w;
                acc1[ui*4+0] += pv.y * vv.x; acc1[ui*4+1] += pv.y * vv.y;
                acc1[ui*4+2] += pv.y * vv.z; acc1[ui*4+3] += pv.y * vv.w;
            }
        }
        __syncthreads();
    }

    float* red  = &lds_v[0][0];
    float* redl = &lds_p[0][0];
    const int slot = ((qp << 3) + cg) << 5;
    if (jh == 1) {
#pragma unroll
        for (int ci = 0; ci < 16; ++ci) { red[slot + ci] = acc0[ci]; red[slot + 16 + ci] = acc1[ci]; }
        redl[((qp << 3) + cg) * 2 + 0] = l0;
        redl[((qp << 3) + cg) * 2 + 1] = l1;
    }
    __syncthreads();
    if (jh == 0) {
#pragma unroll
        for (int ci = 0; ci < 16; ++ci) { acc0[ci] += red[slot + ci]; acc1[ci] += red[slot + 16 + ci]; }
        l0 += redl[((qp << 3) + cg) * 2 + 0];
        l1 += redl[((qp << 3) + cg) * 2 + 1];
        const float al = alpha_p[0];
        const float inv0 = 1.f / l0, inv1 = 1.f / l1;
        const int n0q = q0 + (qp << 1);
#pragma unroll
        for (int ci = 0; ci < 16; ++ci) {
            const int c = (cg << 4) + ci;
            const size_t base = (((size_t)b << 7) + c) << 12;
            const float2 ypv = *(const float2*)&yp[base + n0q];
            float2 o2;
            o2.x = al * (acc0[ci] * inv0) + ypv.x;
            o2.y = al * (acc1[ci] * inv1) + ypv.y;
            *(float2*)&P[base + n0q] = o2;
        }
    }
}

// ---------------- CAM: Gram matrix ----------------
__global__ __launch_bounds__(256) void cam_gram(const float* __restrict__ yc, float* __restrict__ G)
{
    const int b = blockIdx.y;
    const int n0 = blockIdx.x * 128;
    const int t = threadIdx.x;
    const int rg = t & 15, cgg = t >> 4;
    __shared__ float a_t[64][133];
    float acc[8][8];
#pragma unroll
    for (int r = 0; r < 8; ++r)
#pragma unroll
        for (int c = 0; c < 8; ++c) acc[r][c] = 0.f;

    for (int ch = 0; ch < 2; ++ch) {
        const int nb = n0 + ch * 64;
        for (int i = t; i < 8192; i += 256) {
            int c = i >> 6, nn = i & 63;
            a_t[nn][c] = yc[(((size_t)b * 128 + c) << 12) + nb + nn];
        }
        __syncthreads();
        for (int nn = 0; nn < 64; ++nn) {
            float av[8], bv[8];
#pragma unroll
            for (int u = 0; u < 8; ++u) av[u] = a_t[nn][rg * 8 + u];
#pragma unroll
            for (int u = 0; u < 8; ++u) bv[u] = a_t[nn][cgg * 8 + u];
#pragma unroll
            for (int r = 0; r < 8; ++r)
#pragma unroll
                for (int c = 0; c < 8; ++c)
                    acc[r][c] += av[r] * bv[c];
        }
        __syncthreads();
    }
#pragma unroll
    for (int r = 0; r < 8; ++r)
#pragma unroll
        for (int c = 0; c < 8; ++c)
            atomicAdd(&G[((size_t)b << 14) + (size_t)(rg * 8 + r) * 128 + cgg * 8 + c], acc[r][c]);
}

// ---------------- CAM: softmax + apply + beta residual ----------------
__global__ __launch_bounds__(256) void cam_apply(
    const float* __restrict__ G, const float* __restrict__ yc,
    const float* __restrict__ beta_p, float* __restrict__ Cc)
{
    const int b = blockIdx.y;
    const int cchunk = blockIdx.x >> 3;
    const int ns = blockIdx.x & 7;
    const int t = threadIdx.x;

    __shared__ float att_t[128][32];
    __shared__ float s_buf[128 * 64];

    for (int i = t; i < 4096; i += 256)
        s_buf[i] = G[((size_t)b << 14) + (size_t)cchunk * 32 * 128 + i];
    __syncthreads();
    {
        const int r = t >> 3, seg = t & 7;
        float vals[16];
        float gmin = 3.0e38f;
#pragma unroll
        for (int u = 0; u < 16; ++u) {
            vals[u] = s_buf[r * 128 + seg * 16 + u];
            gmin = fminf(gmin, vals[u]);
        }
        gmin = fminf(gmin, __shfl_xor(gmin, 1));
        gmin = fminf(gmin, __shfl_xor(gmin, 2));
        gmin = fminf(gmin, __shfl_xor(gmin, 4));
        float sum = 0.f;
#pragma unroll
        for (int u = 0; u < 16; ++u) { vals[u] = __expf(gmin - vals[u]); sum += vals[u]; }
        sum += __shfl_xor(sum, 1);
        sum += __shfl_xor(sum, 2);
        sum += __shfl_xor(sum, 4);
        const float inv = 1.f / sum;
#pragma unroll
        for (int u = 0; u < 16; ++u)
            att_t[seg * 16 + u][r] = vals[u] * inv;
    }
    __syncthreads();

    const float be = beta_p[0];
    const int nc = t & 31, cgp = t >> 5;
    for (int chunk = 0; chunk < 8; ++chunk) {
        const int nb = ns * 512 + chunk * 64;
        for (int i = t; i < 8192; i += 256) {
            int d = i >> 6, nn = i & 63;
            s_buf[d * 64 + nn] = yc[(((size_t)b * 128 + d) << 12) + nb + nn];
        }
        __syncthreads();
        float a0[4] = {0, 0, 0, 0}, a1[4] = {0, 0, 0, 0};
        for (int d = 0; d < 128; ++d) {
            const float y0 = s_buf[d * 64 + nc];
            const float y1 = s_buf[d * 64 + nc + 32];
#pragma unroll
            for (int o = 0; o < 4; ++o) {
                const float wv = att_t[d][cgp * 4 + o];
                a0[o] += wv * y0; a1[o] += wv * y1;
            }
        }
#pragma unroll
        for (int o = 0; o < 4; ++o) {
            const int cl = cgp * 4 + o;
            const int c = cchunk * 32 + cl;
            const size_t base = (((size_t)b * 128 + c) << 12) + nb;
            Cc[base + nc]      = be * a0[o] + s_buf[c * 64 + nc];
            Cc[base + nc + 32] = be * a1[o] + s_buf[c * 64 + nc + 32];
        }
        __syncthreads();
    }
}

// ---------------- launcher ----------------
extern "C" void kernel_launch(void* const* d_in, const int* in_sizes, int n_in,
                              void* d_out, int out_size, void* d_ws, size_t ws_size,
                              hipStream_t stream)
{
    (void)in_sizes; (void)n_in; (void)out_size; (void)ws_size;
    const float* x    = (const float*)d_in[0];
    const float* wp1  = (const float*)d_in[1];
    const float* gp1  = (const float*)d_in[2];
    const float* bp1  = (const float*)d_in[3];
    const float* mp1  = (const float*)d_in[4];
    const float* vp1  = (const float*)d_in[5];
    const float* wc1  = (const float*)d_in[6];
    const float* gc1  = (const float*)d_in[7];
    const float* bc1  = (const float*)d_in[8];
    const float* mc1  = (const float*)d_in[9];
    const float* vc1  = (const float*)d_in[10];
    const float* pwb  = (const float*)d_in[11];
    const float* pbb  = (const float*)d_in[12];
    const float* pwc  = (const float*)d_in[13];
    const float* pbc  = (const float*)d_in[14];
    const float* pwd  = (const float*)d_in[15];
    const float* pbd  = (const float*)d_in[16];
    const float* alpha= (const float*)d_in[17];
    const float* beta = (const float*)d_in[18];
    const float* wp2  = (const float*)d_in[19];
    const float* gp2  = (const float*)d_in[20];
    const float* bp2  = (const float*)d_in[21];
    const float* mp2  = (const float*)d_in[22];
    const float* vp2  = (const float*)d_in[23];
    const float* wc2  = (const float*)d_in[24];
    const float* gc2  = (const float*)d_in[25];
    const float* bc2  = (const float*)d_in[26];
    const float* vc2v = (const float*)d_in[28];
    const float* mc2  = (const float*)d_in[27];

    float* W = (float*)d_ws;
    unsigned short* wb2p16 = (unsigned short*)(W + OFF_WB2P);
    unsigned short* wb2c16 = (unsigned short*)(W + OFF_WB2C);
    float* b1p = W + OFF_B1P;
    float* b1c = W + OFF_B1C;
    float* wt2p = W + OFF_WT2P;  float* b2p = W + OFF_B2P;
    float* wt2c = W + OFF_WT2C;  float* b2c = W + OFF_B2C;
    float* yp   = W + OFF_YP;
    float* yc   = W + OFF_YC;
    float* Qg   = W + OFF_Q;
    float* Kg   = W + OFF_K;
    float* Vg   = W + OFF_V;
    float* Pp   = W + OFF_P;
    float* Cc   = W + OFF_CC;
    float* G    = W + OFF_G;
    unsigned short* xT16  = (unsigned short*)(W + OFF_P);   // alias, dead before Pp written
    unsigned short* zb16  = (unsigned short*)(W + OFF_Z);
    float* out  = (float*)d_out;

    // zero the Gram accumulator and the zero-row scratch (ws is 0xAA-poisoned)
    hipMemsetAsync(G, 0, (size_t)(65536 + 4096) * sizeof(float), stream);

    x_transpose<<<dim3(64, 4, 4), 256, 0, stream>>>(x, xT16);
    prep_conv_mfma<<<2304, 256, 0, stream>>>(wp1, gp1, bp1, mp1, vp1, wb2p16, b1p);
    prep_conv_mfma<<<2304, 256, 0, stream>>>(wc1, gc1, bc1, mc1, vc1, wb2c16, b1c);
    prep_conv<<<144, 256, 0, stream>>>(wp2, gp2, bp2, mp2, vp2, wt2p, b2p, 1152, 32);
    prep_conv<<<144, 256, 0, stream>>>(wc2, gc2, bc2, mc2, vc2v, wt2c, b2c, 1152, 32);

    conv1_mfma<<<dim3(128, 2), 256, 0, stream>>>(xT16, wb2p16, wb2c16, b1p, b1c, yp, yc, zb16);

    pam_proj<<<dim3(64, 4), 256, 0, stream>>>(yp, pwb, pbb, pwc, pbc, pwd, pbd, Qg, Kg, Vg);
    pam_attn<<<dim3(64, 4), 512, 0, stream>>>(Qg, Kg, Vg, yp, alpha, Pp);

    cam_gram <<<dim3(32, 4), 256, 0, stream>>>(yc, G);
    cam_apply<<<dim3(32, 4), 256, 0, stream>>>(G, yc, beta, Cc);

    conv3x3_bn_relu<128, 32, 32, false><<<dim3(256, 1), 256, 0, stream>>>(Pp, wt2p, b2p, out);
    conv3x3_bn_relu<128, 32, 32, true ><<<dim3(256, 1), 256, 0, stream>>>(Cc, wt2c, b2c, out);
}

// Round 3
// 594.259 us; speedup vs baseline: 3.0134x; 1.9041x over previous
//
#include <hip/hip_runtime.h>
#include <cstddef>
#include <cstdint>

#define EPSBN 1e-5f

typedef __attribute__((ext_vector_type(8))) __bf16 bf16x8;
typedef __attribute__((ext_vector_type(8))) short short8v;
typedef __attribute__((ext_vector_type(4))) float f32x4;

// ---------------- workspace layout (in floats) ----------------
static constexpr size_t SZ_WB2 = 294912;     // 4608*128 ushorts / 2
static constexpr size_t SZ_WT2 = 36864;      // 1152*32
static constexpr size_t SZ_Y   = 2097152;    // 4*128*4096
static constexpr size_t SZ_QK  = 262144;     // 4*4096*32 ushorts / 2

static constexpr size_t OFF_WB2P = 0;
static constexpr size_t OFF_B1P  = OFF_WB2P + SZ_WB2;
static constexpr size_t OFF_WB2C = OFF_B1P + 128;
static constexpr size_t OFF_B1C  = OFF_WB2C + SZ_WB2;
static constexpr size_t OFF_WT2P = OFF_B1C + 128;
static constexpr size_t OFF_B2P  = OFF_WT2P + SZ_WT2;
static constexpr size_t OFF_WT2C = OFF_B2P + 32;
static constexpr size_t OFF_B2C  = OFF_WT2C + SZ_WT2;
static constexpr size_t OFF_YP   = OFF_B2C + 32;
static constexpr size_t OFF_YC   = OFF_YP + SZ_Y;
static constexpr size_t OFF_Q    = OFF_YC + SZ_Y;     // Qb bf16 [4][4096][32]
static constexpr size_t OFF_K    = OFF_Q + SZ_QK;     // Kb bf16 [4][4096][32]
static constexpr size_t OFF_V    = OFF_K + SZ_QK;     // VF bf16 frag stream, 4MB
static constexpr size_t OFF_P    = OFF_V + SZ_Y;
static constexpr size_t OFF_CC   = OFF_P + SZ_Y;
static constexpr size_t OFF_G    = OFF_CC + SZ_Y;     // [4][128][128]
static constexpr size_t OFF_Z    = OFF_G + 65536;     // 16KB zero scratch
// xT (bf16, 16MB) ALIASES [OFF_P, OFF_P+2*SZ_Y): dead before P/Cc written.

__device__ __forceinline__ unsigned short f2bf(float f) {
    unsigned u = __float_as_uint(f);
    unsigned r = (u + 0x7fffu + ((u >> 16) & 1u)) >> 16;
    return (unsigned short)r;
}

__device__ __forceinline__ void gload_lds16(const void* g, void* l) {
    __builtin_amdgcn_global_load_lds((const __attribute__((address_space(1))) void*)g,
                                     (__attribute__((address_space(3))) void*)l, 16, 0, 0);
}

// ---------------- x (fp32 NCHW) -> xT (bf16 [b][h][w][c]) ----------------
__global__ __launch_bounds__(256) void x_transpose(const float* __restrict__ x,
                                                   unsigned short* __restrict__ xT)
{
    const int h = blockIdx.x, b = blockIdx.y, cb0 = blockIdx.z * 128;
    __shared__ float tile[64][129];
    const int t = threadIdx.x;
    for (int i = t; i < 8192; i += 256) {
        int c = i >> 6, w = i & 63;
        tile[w][c] = x[(((size_t)(b * 512 + cb0 + c) * 64) + h) * 64 + w];
    }
    __syncthreads();
    for (int i = t; i < 8192; i += 256) {
        int w = i >> 7, c = i & 127;
        xT[(((size_t)(b * 64 + h) * 64) + w) * 512 + cb0 + c] = f2bf(tile[w][c]);
    }
}

// ---------------- fold BN into conv1 weights, bf16, staged layout ----------------
__global__ void prep_conv_mfma(const float* __restrict__ w, const float* __restrict__ g,
                               const float* __restrict__ bb, const float* __restrict__ m,
                               const float* __restrict__ v, unsigned short* __restrict__ wb2,
                               float* __restrict__ bias)
{
    int idx = blockIdx.x * 256 + threadIdx.x;
    if (idx < 128) {
        float sc = g[idx] * rsqrtf(v[idx] + EPSBN);
        bias[idx] = bb[idx] - m[idx] * sc;
    }
    if (idx >= 128 * 4608) return;
    int oc = idx / 4608;
    int rem = idx - oc * 4608;
    int c = rem / 9;
    int tap = rem - c * 9;
    int kh = tap / 3, kw = tap - kh * 3;
    float sc = g[oc] * rsqrtf(v[oc] + EPSBN);
    float val = w[idx] * sc;
    int u = (oc << 2) + (((c >> 3) & 3) ^ ((oc >> 1) & 3));
    size_t dst = ((size_t)((kh * 16 + (c >> 5)) * 3 + kw) * 512 + u) * 8 + (c & 7);
    wb2[dst] = f2bf(val);
}

// ---------------- conv1 (512->128, 3x3) via bf16 MFMA implicit GEMM ----------------
__global__ __launch_bounds__(256) void conv1_mfma(
    const unsigned short* __restrict__ xT,
    const unsigned short* __restrict__ wb2p, const unsigned short* __restrict__ wb2c,
    const float* __restrict__ b1p, const float* __restrict__ b1c,
    float* __restrict__ yp, float* __restrict__ yc,
    const unsigned short* __restrict__ zbuf)
{
    const int b = blockIdx.x >> 5;
    const int h0 = (blockIdx.x & 31) * 2;
    const bool isC = blockIdx.y != 0;
    const unsigned short* __restrict__ wb2 = isC ? wb2c : wb2p;
    const float* __restrict__ bias = isC ? b1c : b1p;
    float* __restrict__ y = isC ? yc : yp;

    const int t = threadIdx.x;
    const int wid = t >> 6, lane = t & 63;
    const int lhi = lane >> 4, llo = lane & 15;
    const int mrow = wid & 1, ncol = wid >> 1;

    __shared__ __align__(16) unsigned short lds_x[8192];
    __shared__ __align__(16) unsigned short lds_w[12288];

    f32x4 acc[4][4];
#pragma unroll
    for (int i = 0; i < 4; ++i)
#pragma unroll
        for (int j = 0; j < 4; ++j) acc[i][j] = (f32x4)0.0f;

    for (int cc = 0; cc < 16; ++cc) {
        const int cb = cc * 32;
        __syncthreads();
        for (int i = wid; i < 16; i += 4) {
            const int u = (i << 6) + lane;
            const int row = u >> 8;
            const int col = (u >> 2) & 63;
            const int g2 = (u & 3) ^ ((col >> 1) & 3);
            const int xrow = h0 - 1 + row;
            const unsigned short* src = ((unsigned)xrow < 64u)
                ? xT + (((size_t)((b << 6) + xrow) << 6) + col) * 512 + cb + (g2 << 3)
                : zbuf;
            gload_lds16(src, &lds_x[(size_t)i << 9]);
        }
        {
            const unsigned short* ws = wb2 + (size_t)(cc) * 1536 * 8;
            for (int i = wid; i < 24; i += 4)
                gload_lds16(ws + ((size_t)((i << 6) + lane) << 3), &lds_w[(size_t)i << 9]);
        }
        for (int kh = 0; kh < 3; ++kh) {
            if (kh) {
                __syncthreads();
                const unsigned short* ws = wb2 + (size_t)(kh * 16 + cc) * 1536 * 8;
                for (int i = wid; i < 24; i += 4)
                    gload_lds16(ws + ((size_t)((i << 6) + lane) << 3), &lds_w[(size_t)i << 9]);
            }
            __syncthreads();
#pragma unroll
            for (int kw = 0; kw < 3; ++kw) {
                bf16x8 afr[4];
#pragma unroll
                for (int mf = 0; mf < 4; ++mf) {
                    const int oc = (mrow << 6) + (mf << 4) + llo;
                    const int un = (kw << 9) + (oc << 2) + (lhi ^ ((oc >> 1) & 3));
                    afr[mf] = *(const bf16x8*)&lds_w[un << 3];
                }
                bf16x8 bfr[4];
#pragma unroll
                for (int nf = 0; nf < 4; ++nf) {
                    const int px = (nf << 4) + llo;
                    const int wc = px + kw - 1;
                    const bool inb = (unsigned)wc < 64u;
                    const int wcc = inb ? wc : 0;
                    const int un = ((((ncol + kh) << 6) + wcc) << 2) + (lhi ^ ((wcc >> 1) & 3));
                    short8v raw = *(const short8v*)&lds_x[un << 3];
                    short8v zz = {};
                    if (!inb) raw = zz;
                    bfr[nf] = __builtin_bit_cast(bf16x8, raw);
                }
#pragma unroll
                for (int mf = 0; mf < 4; ++mf)
#pragma unroll
                    for (int nf = 0; nf < 4; ++nf)
                        acc[mf][nf] = __builtin_amdgcn_mfma_f32_16x16x32_bf16(
                            afr[mf], bfr[nf], acc[mf][nf], 0, 0, 0);
            }
        }
    }

    const int hout = h0 + ncol;
#pragma unroll
    for (int mf = 0; mf < 4; ++mf) {
#pragma unroll
        for (int r = 0; r < 4; ++r) {
            const int oc = (mrow << 6) + (mf << 4) + (lhi << 2) + r;
            const float bv = bias[oc];
            float* dst = y + (((size_t)(b * 128 + oc) << 6) + hout) * 64;
#pragma unroll
            for (int nf = 0; nf < 4; ++nf) {
                const int colw = (nf << 4) + llo;
                dst[colw] = fmaxf(acc[mf][nf][r] + bv, 0.f);
            }
        }
    }
}

// ---------------- fold BN into transposed conv weights (conv2 path) ----------------
__global__ void prep_conv(const float* __restrict__ w, const float* __restrict__ g,
                          const float* __restrict__ bb, const float* __restrict__ m,
                          const float* __restrict__ v, float* __restrict__ wt,
                          float* __restrict__ bias, int cin9, int cout)
{
    int idx = blockIdx.x * 256 + threadIdx.x;
    if (idx < cout) {
        float sc = g[idx] * rsqrtf(v[idx] + EPSBN);
        bias[idx] = bb[idx] - m[idx] * sc;
    }
    if (idx < cin9 * cout) {
        int o = idx % cout;
        float sc = g[o] * rsqrtf(v[o] + EPSBN);
        wt[idx] = w[o * cin9 + (idx / cout)] * sc;
    }
}

// ---------------- 3x3 conv + folded BN + ReLU (fp32, conv2 only) ----------------
template<int CIN, int COUT, int OCB, bool ADD>
__global__ __launch_bounds__(256) void conv3x3_bn_relu(
    const float* __restrict__ xin, const float* __restrict__ wt,
    const float* __restrict__ bias, float* __restrict__ out)
{
    static_assert(OCB == 64 || OCB == 32, "");
    constexpr int OPT = OCB / 16;
    const int row = blockIdx.x;
    const int b = row >> 6, h = row & 63;
    const int obase = blockIdx.y * OCB;
    const int t = threadIdx.x;
    const int pg = t & 15;
    const int og = t >> 4;
    const int w0 = pg * 4;

    __shared__ __align__(16) float lds_x[16][3][68];
    __shared__ __align__(16) float lds_w[144][OCB];

    float acc[OPT][4];
#pragma unroll
    for (int o = 0; o < OPT; ++o)
#pragma unroll
        for (int p = 0; p < 4; ++p) acc[o][p] = 0.f;

    for (int cb = 0; cb < CIN; cb += 16) {
        for (int i = t; i < 16 * 3 * 66; i += 256) {
            int c = i / 198;
            int rem = i - c * 198;
            int r = rem / 66;
            int wc = rem - r * 66;
            int hh = h - 1 + r;
            int ww = wc - 1;
            float val = 0.f;
            if ((unsigned)hh < 64u && (unsigned)ww < 64u)
                val = xin[(((size_t)b * CIN + cb + c) * 64 + hh) * 64 + ww];
            lds_x[c][r][wc] = val;
        }
        for (int i = t; i < 144 * OCB; i += 256) {
            int o = i & (OCB - 1);
            int j = i / OCB;
            lds_w[j][o] = wt[((size_t)cb * 9 + j) * COUT + obase + o];
        }
        __syncthreads();
        for (int c = 0; c < 16; ++c) {
#pragma unroll
            for (int kh = 0; kh < 3; ++kh) {
                float4 xa = *(const float4*)&lds_x[c][kh][w0];
                float4 xb = *(const float4*)&lds_x[c][kh][w0 + 4];
                float xv[8] = {xa.x, xa.y, xa.z, xa.w, xb.x, xb.y, xb.z, xb.w};
#pragma unroll
                for (int kw = 0; kw < 3; ++kw) {
                    const float* wrow = &lds_w[c * 9 + kh * 3 + kw][og * OPT];
                    float wv[OPT];
                    if constexpr (OPT == 4) {
                        float4 w4 = *(const float4*)wrow;
                        wv[0] = w4.x; wv[1] = w4.y; wv[2] = w4.z; wv[3] = w4.w;
                    } else {
                        float2 w2 = *(const float2*)wrow;
                        wv[0] = w2.x; wv[1] = w2.y;
                    }
#pragma unroll
                    for (int o = 0; o < OPT; ++o)
#pragma unroll
                        for (int p = 0; p < 4; ++p)
                            acc[o][p] += wv[o] * xv[p + kw];
                }
            }
        }
        __syncthreads();
    }
#pragma unroll
    for (int o = 0; o < OPT; ++o) {
        int oc = obase + og * OPT + o;
        float bv = bias[oc];
#pragma unroll
        for (int p = 0; p < 4; ++p) {
            float val = fmaxf(acc[o][p] + bv, 0.f);
            size_t idx = (((size_t)b * COUT + oc) * 64 + h) * 64 + (w0 + p);
            if (ADD) out[idx] += val; else out[idx] = val;
        }
    }
}

// ---------------- PAM projections: q,k -> bf16 [n][32]; d -> VF fragment stream ----
// VF layout: per (b, kt=key/32, cf=ch/16) a 1KB block; lane = ((key>>2)&3)*16 + (ch&15),
// slot j = (key&3) + 4*((key>>4)&1). Matches the in-register P^T packing of pam_attn.
__global__ __launch_bounds__(256) void pam_proj(
    const float* __restrict__ yp,
    const float* __restrict__ wb, const float* __restrict__ bbq,
    const float* __restrict__ wc, const float* __restrict__ bck,
    const float* __restrict__ wd, const float* __restrict__ bdv,
    unsigned short* __restrict__ Qb, unsigned short* __restrict__ Kb,
    unsigned short* __restrict__ VFo)
{
    const int b = blockIdx.y;
    const int n0 = blockIdx.x * 64;
    const int t = threadIdx.x;
    const int px = t & 63;
    const int og = t >> 6;

    __shared__ __align__(16) float lds_y[64][64];
    __shared__ __align__(16) float lds_w[64][164];

    float acc[10][4];
#pragma unroll
    for (int s = 0; s < 10; ++s) { acc[s][0] = acc[s][1] = acc[s][2] = acc[s][3] = 0.f; }

    for (int cb = 0; cb < 128; cb += 64) {
        for (int i = t; i < 4096; i += 256) {
            int c = i >> 6, p = i & 63;
            lds_y[c][p] = yp[(((size_t)b * 128 + cb + c) << 12) + n0 + p];
        }
        for (int i = t; i < 160 * 64; i += 256) {
            int c = i & 63, o = i >> 6;
            const float* src = (o < 16) ? (wb + o * 128)
                             : (o < 32) ? (wc + (o - 16) * 128)
                                        : (wd + (o - 32) * 128);
            lds_w[c][o] = src[cb + c];
        }
        __syncthreads();
        for (int c = 0; c < 64; ++c) {
            float yv = lds_y[c][px];
#pragma unroll
            for (int s = 0; s < 10; ++s) {
                const float4 w4 = *(const float4*)&lds_w[c][s * 16 + og * 4];
                acc[s][0] += w4.x * yv; acc[s][1] += w4.y * yv;
                acc[s][2] += w4.z * yv; acc[s][3] += w4.w * yv;
            }
        }
        __syncthreads();
    }
    const int n = n0 + px;
    const size_t qkrow = ((size_t)(b << 12) + n) << 5;
#pragma unroll
    for (int s = 0; s < 10; ++s) {
        const float* bsrc = (s == 0) ? (bbq + og * 4)
                          : (s == 1) ? (bck + og * 4)
                                     : (bdv + (s - 2) * 16 + og * 4);
        const float4 bv4 = *(const float4*)bsrc;
        float v0 = acc[s][0] + bv4.x, v1 = acc[s][1] + bv4.y;
        float v2 = acc[s][2] + bv4.z, v3 = acc[s][3] + bv4.w;
        if (s < 2) {
            unsigned short* dst = (s == 0) ? Qb : Kb;
            uint2 pk2;
            pk2.x = (unsigned)f2bf(v0) | ((unsigned)f2bf(v1) << 16);
            pk2.y = (unsigned)f2bf(v2) | ((unsigned)f2bf(v3) << 16);
            *(uint2*)&dst[qkrow + (og << 2)] = pk2;
            uint2 z2; z2.x = 0u; z2.y = 0u;
            *(uint2*)&dst[qkrow + 16 + (og << 2)] = z2;
        } else {
            const int cf = s - 2;
            const size_t blk = ((size_t)(b * 128 + (n >> 5)) * 8 + cf) << 9;
            const int gl = ((n >> 2) & 3) << 4;
            const int j = (n & 3) | (((n >> 4) & 1) << 2);
            const float vv[4] = {v0, v1, v2, v3};
#pragma unroll
            for (int u = 0; u < 4; ++u)
                VFo[blk + ((size_t)((gl | (og * 4 + u)) << 3)) + j] = f2bf(vv[u]);
        }
    }
}

// ---------------- PAM fused attention: bf16 MFMA, two-pass, register-resident ----
// grid (64, B), 512 thr = 8 waves: qg = wid&3 (16 queries each), kh = wid>>2 (key half).
__global__ __launch_bounds__(512) void pam_attn_mfma(
    const unsigned short* __restrict__ Qb, const unsigned short* __restrict__ Kb,
    const unsigned short* __restrict__ VF, const float* __restrict__ yp,
    const float* __restrict__ alpha_p, float* __restrict__ P)
{
    const int b = blockIdx.y;
    const int q0 = blockIdx.x * 64;
    const int t = threadIdx.x;
    const int wid = t >> 6, lane = t & 63;
    const int qg = wid & 3, kh = wid >> 2;
    const int g = lane >> 4, qi = lane & 15;
    const int qw0 = q0 + qg * 16;

    __shared__ float combO[4][64][33];
    __shared__ float combL[4][64];
    __shared__ float combM[4][2][16];

    const bf16x8 qf = *(const bf16x8*)&Qb[(((size_t)(b << 12) + qw0 + qi) << 5) + (g << 3)];
    const unsigned short* __restrict__ Kbase = Kb + ((size_t)b << 17);

    // ---- pass 1: exact row max (same bf16 MFMA scores as pass 2) ----
    float mA = -3.0e38f;
    for (int kf = 0; kf < 128; ++kf) {
        const int kb = (kh << 11) + (kf << 4);
        const bf16x8 ka = *(const bf16x8*)&Kbase[((size_t)(kb + qi) << 5) + (g << 3)];
        f32x4 z = {};
        f32x4 s = __builtin_amdgcn_mfma_f32_16x16x32_bf16(ka, qf, z, 0, 0, 0);
        mA = fmaxf(mA, fmaxf(fmaxf(s[0], s[1]), fmaxf(s[2], s[3])));
    }
    mA = fmaxf(mA, __shfl_xor(mA, 16));
    mA = fmaxf(mA, __shfl_xor(mA, 32));
    if (lane < 16) combM[qg][kh][lane] = mA;
    __syncthreads();
    mA = fmaxf(mA, combM[qg][kh ^ 1][qi]);

    // ---- pass 2: S^T -> exp -> bf16 P^T (register-pure) -> PV ----
    f32x4 accO[8];
#pragma unroll
    for (int cf = 0; cf < 8; ++cf) accO[cf] = (f32x4)0.0f;
    float lsum = 0.f;
    const unsigned short* __restrict__ VFb = VF + ((size_t)b << 19);

    for (int it = 0; it < 64; ++it) {
        const int kt = (kh << 6) + it;
        const int kb = kt << 5;
        const bf16x8 kaE = *(const bf16x8*)&Kbase[((size_t)(kb + qi) << 5) + (g << 3)];
        const bf16x8 kaO = *(const bf16x8*)&Kbase[((size_t)(kb + 16 + qi) << 5) + (g << 3)];
        f32x4 z = {};
        f32x4 sE = __builtin_amdgcn_mfma_f32_16x16x32_bf16(kaE, qf, z, 0, 0, 0);
        f32x4 sO = __builtin_amdgcn_mfma_f32_16x16x32_bf16(kaO, qf, z, 0, 0, 0);
        bf16x8 pb;
#pragma unroll
        for (int r = 0; r < 4; ++r) {
            const float e0 = __expf(sE[r] - mA);
            const float e1 = __expf(sO[r] - mA);
            lsum += e0 + e1;
            pb[r] = (__bf16)e0;
            pb[4 + r] = (__bf16)e1;
        }
        const unsigned short* vt = VFb + ((size_t)kt << 12) + (lane << 3);
#pragma unroll
        for (int cf = 0; cf < 8; ++cf) {
            const bf16x8 vf = *(const bf16x8*)&vt[(size_t)cf << 9];
            accO[cf] = __builtin_amdgcn_mfma_f32_16x16x32_bf16(vf, pb, accO[cf], 0, 0, 0);
        }
    }
    lsum += __shfl_xor(lsum, 16);
    lsum += __shfl_xor(lsum, 32);

    // ---- combine key halves, normalize, residual ----
    if (kh == 1) {
#pragma unroll
        for (int cf = 0; cf < 8; ++cf)
#pragma unroll
            for (int r = 0; r < 4; ++r)
                combO[qg][lane][cf * 4 + r] = accO[cf][r];
        combL[qg][lane] = lsum;
    }
    __syncthreads();
    if (kh == 0) {
#pragma unroll
        for (int cf = 0; cf < 8; ++cf)
#pragma unroll
            for (int r = 0; r < 4; ++r)
                accO[cf][r] += combO[qg][lane][cf * 4 + r];
        lsum += combL[qg][lane];
        const float sc = alpha_p[0] / lsum;
#pragma unroll
        for (int cf = 0; cf < 8; ++cf) {
#pragma unroll
            for (int r = 0; r < 4; ++r) {
                const int ch = cf * 16 + (g << 2) + r;
                const size_t o = (((size_t)(b * 128 + ch)) << 12) + qw0 + qi;
                P[o] = accO[cf][r] * sc + yp[o];
            }
        }
    }
}

// ---------------- CAM: Gram matrix ----------------
__global__ __launch_bounds__(256) void cam_gram(const float* __restrict__ yc, float* __restrict__ G)
{
    const int b = blockIdx.y;
    const int n0 = blockIdx.x * 128;
    const int t = threadIdx.x;
    const int rg = t & 15, cgg = t >> 4;
    __shared__ float a_t[64][133];
    float acc[8][8];
#pragma unroll
    for (int r = 0; r < 8; ++r)
#pragma unroll
        for (int c = 0; c < 8; ++c) acc[r][c] = 0.f;

    for (int ch = 0; ch < 2; ++ch) {
        const int nb = n0 + ch * 64;
        for (int i = t; i < 8192; i += 256) {
            int c = i >> 6, nn = i & 63;
            a_t[nn][c] = yc[(((size_t)b * 128 + c) << 12) + nb + nn];
        }
        __syncthreads();
        for (int nn = 0; nn < 64; ++nn) {
            float av[8], bv[8];
#pragma unroll
            for (int u = 0; u < 8; ++u) av[u] = a_t[nn][rg * 8 + u];
#pragma unroll
            for (int u = 0; u < 8; ++u) bv[u] = a_t[nn][cgg * 8 + u];
#pragma unroll
            for (int r = 0; r < 8; ++r)
#pragma unroll
                for (int c = 0; c < 8; ++c)
                    acc[r][c] += av[r] * bv[c];
        }
        __syncthreads();
    }
#pragma unroll
    for (int r = 0; r < 8; ++r)
#pragma unroll
        for (int c = 0; c < 8; ++c)
            atomicAdd(&G[((size_t)b << 14) + (size_t)(rg * 8 + r) * 128 + cgg * 8 + c], acc[r][c]);
}

// ---------------- CAM: softmax + apply + beta residual ----------------
__global__ __launch_bounds__(256) void cam_apply(
    const float* __restrict__ G, const float* __restrict__ yc,
    const float* __restrict__ beta_p, float* __restrict__ Cc)
{
    const int b = blockIdx.y;
    const int cchunk = blockIdx.x >> 3;
    const int ns = blockIdx.x & 7;
    const int t = threadIdx.x;

    __shared__ float att_t[128][32];
    __shared__ float s_buf[128 * 64];

    for (int i = t; i < 4096; i += 256)
        s_buf[i] = G[((size_t)b << 14) + (size_t)cchunk * 32 * 128 + i];
    __syncthreads();
    {
        const int r = t >> 3, seg = t & 7;
        float vals[16];
        float gmin = 3.0e38f;
#pragma unroll
        for (int u = 0; u < 16; ++u) {
            vals[u] = s_buf[r * 128 + seg * 16 + u];
            gmin = fminf(gmin, vals[u]);
        }
        gmin = fminf(gmin, __shfl_xor(gmin, 1));
        gmin = fminf(gmin, __shfl_xor(gmin, 2));
        gmin = fminf(gmin, __shfl_xor(gmin, 4));
        float sum = 0.f;
#pragma unroll
        for (int u = 0; u < 16; ++u) { vals[u] = __expf(gmin - vals[u]); sum += vals[u]; }
        sum += __shfl_xor(sum, 1);
        sum += __shfl_xor(sum, 2);
        sum += __shfl_xor(sum, 4);
        const float inv = 1.f / sum;
#pragma unroll
        for (int u = 0; u < 16; ++u)
            att_t[seg * 16 + u][r] = vals[u] * inv;
    }
    __syncthreads();

    const float be = beta_p[0];
    const int nc = t & 31, cgp = t >> 5;
    for (int chunk = 0; chunk < 8; ++chunk) {
        const int nb = ns * 512 + chunk * 64;
        for (int i = t; i < 8192; i += 256) {
            int d = i >> 6, nn = i & 63;
            s_buf[d * 64 + nn] = yc[(((size_t)b * 128 + d) << 12) + nb + nn];
        }
        __syncthreads();
        float a0[4] = {0, 0, 0, 0}, a1[4] = {0, 0, 0, 0};
        for (int d = 0; d < 128; ++d) {
            const float y0 = s_buf[d * 64 + nc];
            const float y1 = s_buf[d * 64 + nc + 32];
#pragma unroll
            for (int o = 0; o < 4; ++o) {
                const float wv = att_t[d][cgp * 4 + o];
                a0[o] += wv * y0; a1[o] += wv * y1;
            }
        }
#pragma unroll
        for (int o = 0; o < 4; ++o) {
            const int cl = cgp * 4 + o;
            const int c = cchunk * 32 + cl;
            const size_t base = (((size_t)b * 128 + c) << 12) + nb;
            Cc[base + nc]      = be * a0[o] + s_buf[c * 64 + nc];
            Cc[base + nc + 32] = be * a1[o] + s_buf[c * 64 + nc + 32];
        }
        __syncthreads();
    }
}

// ---------------- launcher ----------------
extern "C" void kernel_launch(void* const* d_in, const int* in_sizes, int n_in,
                              void* d_out, int out_size, void* d_ws, size_t ws_size,
                              hipStream_t stream)
{
    (void)in_sizes; (void)n_in; (void)out_size; (void)ws_size;
    const float* x    = (const float*)d_in[0];
    const float* wp1  = (const float*)d_in[1];
    const float* gp1  = (const float*)d_in[2];
    const float* bp1  = (const float*)d_in[3];
    const float* mp1  = (const float*)d_in[4];
    const float* vp1  = (const float*)d_in[5];
    const float* wc1  = (const float*)d_in[6];
    const float* gc1  = (const float*)d_in[7];
    const float* bc1  = (const float*)d_in[8];
    const float* mc1  = (const float*)d_in[9];
    const float* vc1  = (const float*)d_in[10];
    const float* pwb  = (const float*)d_in[11];
    const float* pbb  = (const float*)d_in[12];
    const float* pwc  = (const float*)d_in[13];
    const float* pbc  = (const float*)d_in[14];
    const float* pwd  = (const float*)d_in[15];
    const float* pbd  = (const float*)d_in[16];
    const float* alpha= (const float*)d_in[17];
    const float* beta = (const float*)d_in[18];
    const float* wp2  = (const float*)d_in[19];
    const float* gp2  = (const float*)d_in[20];
    const float* bp2  = (const float*)d_in[21];
    const float* mp2  = (const float*)d_in[22];
    const float* vp2  = (const float*)d_in[23];
    const float* wc2  = (const float*)d_in[24];
    const float* gc2  = (const float*)d_in[25];
    const float* bc2  = (const float*)d_in[26];
    const float* mc2  = (const float*)d_in[27];
    const float* vc2v = (const float*)d_in[28];

    float* W = (float*)d_ws;
    unsigned short* wb2p16 = (unsigned short*)(W + OFF_WB2P);
    unsigned short* wb2c16 = (unsigned short*)(W + OFF_WB2C);
    float* b1p = W + OFF_B1P;
    float* b1c = W + OFF_B1C;
    float* wt2p = W + OFF_WT2P;  float* b2p = W + OFF_B2P;
    float* wt2c = W + OFF_WT2C;  float* b2c = W + OFF_B2C;
    float* yp   = W + OFF_YP;
    float* yc   = W + OFF_YC;
    unsigned short* Qb16 = (unsigned short*)(W + OFF_Q);
    unsigned short* Kb16 = (unsigned short*)(W + OFF_K);
    unsigned short* VF16 = (unsigned short*)(W + OFF_V);
    float* Pp   = W + OFF_P;
    float* Cc   = W + OFF_CC;
    float* G    = W + OFF_G;
    unsigned short* xT16  = (unsigned short*)(W + OFF_P);   // alias, dead before Pp written
    unsigned short* zb16  = (unsigned short*)(W + OFF_Z);
    float* out  = (float*)d_out;

    // zero the Gram accumulator and the zero-row scratch (ws is 0xAA-poisoned)
    hipMemsetAsync(G, 0, (size_t)(65536 + 4096) * sizeof(float), stream);

    x_transpose<<<dim3(64, 4, 4), 256, 0, stream>>>(x, xT16);
    prep_conv_mfma<<<2304, 256, 0, stream>>>(wp1, gp1, bp1, mp1, vp1, wb2p16, b1p);
    prep_conv_mfma<<<2304, 256, 0, stream>>>(wc1, gc1, bc1, mc1, vc1, wb2c16, b1c);
    prep_conv<<<144, 256, 0, stream>>>(wp2, gp2, bp2, mp2, vp2, wt2p, b2p, 1152, 32);
    prep_conv<<<144, 256, 0, stream>>>(wc2, gc2, bc2, mc2, vc2v, wt2c, b2c, 1152, 32);

    conv1_mfma<<<dim3(128, 2), 256, 0, stream>>>(xT16, wb2p16, wb2c16, b1p, b1c, yp, yc, zb16);

    pam_proj<<<dim3(64, 4), 256, 0, stream>>>(yp, pwb, pbb, pwc, pbc, pwd, pbd, Qb16, Kb16, VF16);
    pam_attn_mfma<<<dim3(64, 4), 512, 0, stream>>>(Qb16, Kb16, VF16, yp, alpha, Pp);

    cam_gram <<<dim3(32, 4), 256, 0, stream>>>(yc, G);
    cam_apply<<<dim3(32, 4), 256, 0, stream>>>(G, yc, beta, Cc);

    conv3x3_bn_relu<128, 32, 32, false><<<dim3(256, 1), 256, 0, stream>>>(Pp, wt2p, b2p, out);
    conv3x3_bn_relu<128, 32, 32, true ><<<dim3(256, 1), 256, 0, stream>>>(Cc, wt2c, b2c, out);
}

// Round 4
// 528.224 us; speedup vs baseline: 3.3901x; 1.1250x over previous
//
#include <hip/hip_runtime.h>
#include <cstddef>
#include <cstdint>

#define EPSBN 1e-5f

typedef __attribute__((ext_vector_type(8))) __bf16 bf16x8;
typedef __attribute__((ext_vector_type(8))) short short8v;
typedef __attribute__((ext_vector_type(4))) float f32x4;

// ---------------- workspace layout (in floats) ----------------
static constexpr size_t SZ_WB2 = 294912;     // 4608*128 ushorts / 2
static constexpr size_t SZ_WT2 = 36864;      // 1152*32
static constexpr size_t SZ_Y   = 2097152;    // 4*128*4096
static constexpr size_t SZ_QK  = 262144;     // 4*4096*32 ushorts / 2

static constexpr size_t OFF_WB2P = 0;
static constexpr size_t OFF_B1P  = OFF_WB2P + SZ_WB2;
static constexpr size_t OFF_WB2C = OFF_B1P + 128;
static constexpr size_t OFF_B1C  = OFF_WB2C + SZ_WB2;
static constexpr size_t OFF_WT2P = OFF_B1C + 128;
static constexpr size_t OFF_B2P  = OFF_WT2P + SZ_WT2;
static constexpr size_t OFF_WT2C = OFF_B2P + 32;
static constexpr size_t OFF_B2C  = OFF_WT2C + SZ_WT2;
static constexpr size_t OFF_YP   = OFF_B2C + 32;
static constexpr size_t OFF_YC   = OFF_YP + SZ_Y;
static constexpr size_t OFF_Q    = OFF_YC + SZ_Y;     // Qb bf16 [4][4096][32]
static constexpr size_t OFF_K    = OFF_Q + SZ_QK;     // Kb bf16 [4][4096][32]
static constexpr size_t OFF_V    = OFF_K + SZ_QK;     // VF bf16 frag stream, 4MB
static constexpr size_t OFF_P    = OFF_V + SZ_Y;
static constexpr size_t OFF_CC   = OFF_P + SZ_Y;
static constexpr size_t OFF_G    = OFF_CC + SZ_Y;     // [4][128][128]
static constexpr size_t OFF_Z    = OFF_G + 65536;     // 16KB zero scratch
// xT (bf16, 16MB) ALIASES [OFF_P, OFF_P+2*SZ_Y): dead before P/Cc written.

__device__ __forceinline__ unsigned short f2bf(float f) {
    unsigned u = __float_as_uint(f);
    unsigned r = (u + 0x7fffu + ((u >> 16) & 1u)) >> 16;
    return (unsigned short)r;
}

__device__ __forceinline__ void gload_lds16(const void* g, void* l) {
    __builtin_amdgcn_global_load_lds((const __attribute__((address_space(1))) void*)g,
                                     (__attribute__((address_space(3))) void*)l, 16, 0, 0);
}

// ---------------- x (fp32 NCHW) -> xT (bf16 [b][h][w][c]) ----------------
__global__ __launch_bounds__(256) void x_transpose(const float* __restrict__ x,
                                                   unsigned short* __restrict__ xT)
{
    const int h = blockIdx.x, b = blockIdx.y, cb0 = blockIdx.z * 128;
    __shared__ float tile[64][129];
    const int t = threadIdx.x;
    for (int i = t; i < 8192; i += 256) {
        int c = i >> 6, w = i & 63;
        tile[w][c] = x[(((size_t)(b * 512 + cb0 + c) * 64) + h) * 64 + w];
    }
    __syncthreads();
    for (int i = t; i < 8192; i += 256) {
        int w = i >> 7, c = i & 127;
        xT[(((size_t)(b * 64 + h) * 64) + w) * 512 + cb0 + c] = f2bf(tile[w][c]);
    }
}

// ---------------- fold BN into conv1 weights, bf16, staged layout ----------------
__global__ void prep_conv_mfma(const float* __restrict__ w, const float* __restrict__ g,
                               const float* __restrict__ bb, const float* __restrict__ m,
                               const float* __restrict__ v, unsigned short* __restrict__ wb2,
                               float* __restrict__ bias)
{
    int idx = blockIdx.x * 256 + threadIdx.x;
    if (idx < 128) {
        float sc = g[idx] * rsqrtf(v[idx] + EPSBN);
        bias[idx] = bb[idx] - m[idx] * sc;
    }
    if (idx >= 128 * 4608) return;
    int oc = idx / 4608;
    int rem = idx - oc * 4608;
    int c = rem / 9;
    int tap = rem - c * 9;
    int kh = tap / 3, kw = tap - kh * 3;
    float sc = g[oc] * rsqrtf(v[oc] + EPSBN);
    float val = w[idx] * sc;
    int u = (oc << 2) + (((c >> 3) & 3) ^ ((oc >> 1) & 3));
    size_t dst = ((size_t)((kh * 16 + (c >> 5)) * 3 + kw) * 512 + u) * 8 + (c & 7);
    wb2[dst] = f2bf(val);
}

// ---------------- conv1 (512->128, 3x3) via bf16 MFMA implicit GEMM ----------------
// grid (128, 4): x = b*32 + rowpair; y = conv*2 + ochalf. 256 thr / 4 waves.
// Block tile: 64 oc x 128 px (2 image rows). Wave tile 64oc x 32px (4x2 frags).
__global__ __launch_bounds__(256) void conv1_mfma(
    const unsigned short* __restrict__ xT,
    const unsigned short* __restrict__ wb2p, const unsigned short* __restrict__ wb2c,
    const float* __restrict__ b1p, const float* __restrict__ b1c,
    float* __restrict__ yp, float* __restrict__ yc,
    const unsigned short* __restrict__ zbuf)
{
    const int b = blockIdx.x >> 5;
    const int h0 = (blockIdx.x & 31) * 2;
    const bool isC = (blockIdx.y >> 1) != 0;
    const int ohalf = blockIdx.y & 1;
    const int obase = ohalf << 6;
    const unsigned short* __restrict__ wb2 = isC ? wb2c : wb2p;
    const float* __restrict__ bias = isC ? b1c : b1p;
    float* __restrict__ y = isC ? yc : yp;

    const int t = threadIdx.x;
    const int wid = t >> 6, lane = t & 63;
    const int lhi = lane >> 4, llo = lane & 15;

    __shared__ __align__(16) unsigned short lds_x[8192];   // 4 rows x (64 col x 4 g) x 8ch
    __shared__ __align__(16) unsigned short lds_w[6144];   // 3 kw x 256 u x 8ch

    f32x4 acc[4][2];
#pragma unroll
    for (int i = 0; i < 4; ++i)
#pragma unroll
        for (int j = 0; j < 2; ++j) acc[i][j] = (f32x4)0.0f;

    for (int cc = 0; cc < 16; ++cc) {
        const int cb = cc * 32;
        __syncthreads();
        for (int i = wid; i < 16; i += 4) {
            const int u = (i << 6) + lane;
            const int row = u >> 8;
            const int col = (u >> 2) & 63;
            const int g2 = (u & 3) ^ ((col >> 1) & 3);
            const int xrow = h0 - 1 + row;
            const unsigned short* src = ((unsigned)xrow < 64u)
                ? xT + (((size_t)((b << 6) + xrow) << 6) + col) * 512 + cb + (g2 << 3)
                : zbuf;
            gload_lds16(src, &lds_x[(size_t)i << 9]);
        }
        {
            const unsigned short* ws = wb2 + ((size_t)(cc * 3) * 512 + (ohalf << 8)) * 8;
            for (int i = wid; i < 12; i += 4) {
                const int kw = i >> 2, seg = i & 3;
                gload_lds16(ws + ((size_t)(kw * 512 + (seg << 6) + lane) << 3),
                            &lds_w[(size_t)i << 9]);
            }
        }
        for (int kh = 0; kh < 3; ++kh) {
            if (kh) {
                __syncthreads();
                const unsigned short* ws = wb2 + ((size_t)((kh * 16 + cc) * 3) * 512 + (ohalf << 8)) * 8;
                for (int i = wid; i < 12; i += 4) {
                    const int kw = i >> 2, seg = i & 3;
                    gload_lds16(ws + ((size_t)(kw * 512 + (seg << 6) + lane) << 3),
                                &lds_w[(size_t)i << 9]);
                }
            }
            __syncthreads();
#pragma unroll
            for (int kw = 0; kw < 3; ++kw) {
                bf16x8 afr[4];
#pragma unroll
                for (int mf = 0; mf < 4; ++mf) {
                    const int ocl = (mf << 4) + llo;
                    const int un = (kw << 8) + (ocl << 2) + (lhi ^ ((ocl >> 1) & 3));
                    afr[mf] = *(const bf16x8*)&lds_w[un << 3];
                }
                bf16x8 bfr[2];
#pragma unroll
                for (int nf = 0; nf < 2; ++nf) {
                    const int px = (wid << 5) + (nf << 4) + llo;
                    const int orow = px >> 6;
                    const int wc = (px & 63) + kw - 1;
                    const bool inb = (unsigned)wc < 64u;
                    const int wcc = inb ? wc : 0;
                    const int un = (((orow + kh) << 6) + wcc) * 4 + (lhi ^ ((wcc >> 1) & 3));
                    short8v raw = *(const short8v*)&lds_x[un << 3];
                    short8v zz = {};
                    if (!inb) raw = zz;
                    bfr[nf] = __builtin_bit_cast(bf16x8, raw);
                }
#pragma unroll
                for (int mf = 0; mf < 4; ++mf)
#pragma unroll
                    for (int nf = 0; nf < 2; ++nf)
                        acc[mf][nf] = __builtin_amdgcn_mfma_f32_16x16x32_bf16(
                            afr[mf], bfr[nf], acc[mf][nf], 0, 0, 0);
            }
        }
    }

#pragma unroll
    for (int mf = 0; mf < 4; ++mf) {
#pragma unroll
        for (int r = 0; r < 4; ++r) {
            const int oc = obase + (mf << 4) + (lhi << 2) + r;
            const float bv = bias[oc];
#pragma unroll
            for (int nf = 0; nf < 2; ++nf) {
                const int px = (wid << 5) + (nf << 4) + llo;
                const int hout = h0 + (px >> 6);
                const int colw = px & 63;
                float* dst = y + (((size_t)(b * 128 + oc) << 6) + hout) * 64;
                dst[colw] = fmaxf(acc[mf][nf][r] + bv, 0.f);
            }
        }
    }
}

// ---------------- fold BN into transposed conv weights (conv2 path) ----------------
__global__ void prep_conv(const float* __restrict__ w, const float* __restrict__ g,
                          const float* __restrict__ bb, const float* __restrict__ m,
                          const float* __restrict__ v, float* __restrict__ wt,
                          float* __restrict__ bias, int cin9, int cout)
{
    int idx = blockIdx.x * 256 + threadIdx.x;
    if (idx < cout) {
        float sc = g[idx] * rsqrtf(v[idx] + EPSBN);
        bias[idx] = bb[idx] - m[idx] * sc;
    }
    if (idx < cin9 * cout) {
        int o = idx % cout;
        float sc = g[o] * rsqrtf(v[o] + EPSBN);
        wt[idx] = w[o * cin9 + (idx / cout)] * sc;
    }
}

// ---------------- 3x3 conv + folded BN + ReLU (fp32, conv2 only) ----------------
template<int CIN, int COUT, int OCB, bool ADD>
__global__ __launch_bounds__(256) void conv3x3_bn_relu(
    const float* __restrict__ xin, const float* __restrict__ wt,
    const float* __restrict__ bias, float* __restrict__ out)
{
    static_assert(OCB == 64 || OCB == 32, "");
    constexpr int OPT = OCB / 16;
    const int row = blockIdx.x;
    const int b = row >> 6, h = row & 63;
    const int obase = blockIdx.y * OCB;
    const int t = threadIdx.x;
    const int pg = t & 15;
    const int og = t >> 4;
    const int w0 = pg * 4;

    __shared__ __align__(16) float lds_x[16][3][68];
    __shared__ __align__(16) float lds_w[144][OCB];

    float acc[OPT][4];
#pragma unroll
    for (int o = 0; o < OPT; ++o)
#pragma unroll
        for (int p = 0; p < 4; ++p) acc[o][p] = 0.f;

    for (int cb = 0; cb < CIN; cb += 16) {
        for (int i = t; i < 16 * 3 * 66; i += 256) {
            int c = i / 198;
            int rem = i - c * 198;
            int r = rem / 66;
            int wc = rem - r * 66;
            int hh = h - 1 + r;
            int ww = wc - 1;
            float val = 0.f;
            if ((unsigned)hh < 64u && (unsigned)ww < 64u)
                val = xin[(((size_t)b * CIN + cb + c) * 64 + hh) * 64 + ww];
            lds_x[c][r][wc] = val;
        }
        for (int i = t; i < 144 * OCB; i += 256) {
            int o = i & (OCB - 1);
            int j = i / OCB;
            lds_w[j][o] = wt[((size_t)cb * 9 + j) * COUT + obase + o];
        }
        __syncthreads();
        for (int c = 0; c < 16; ++c) {
#pragma unroll
            for (int kh = 0; kh < 3; ++kh) {
                float4 xa = *(const float4*)&lds_x[c][kh][w0];
                float4 xb = *(const float4*)&lds_x[c][kh][w0 + 4];
                float xv[8] = {xa.x, xa.y, xa.z, xa.w, xb.x, xb.y, xb.z, xb.w};
#pragma unroll
                for (int kw = 0; kw < 3; ++kw) {
                    const float* wrow = &lds_w[c * 9 + kh * 3 + kw][og * OPT];
                    float wv[OPT];
                    if constexpr (OPT == 4) {
                        float4 w4 = *(const float4*)wrow;
                        wv[0] = w4.x; wv[1] = w4.y; wv[2] = w4.z; wv[3] = w4.w;
                    } else {
                        float2 w2 = *(const float2*)wrow;
                        wv[0] = w2.x; wv[1] = w2.y;
                    }
#pragma unroll
                    for (int o = 0; o < OPT; ++o)
#pragma unroll
                        for (int p = 0; p < 4; ++p)
                            acc[o][p] += wv[o] * xv[p + kw];
                }
            }
        }
        __syncthreads();
    }
#pragma unroll
    for (int o = 0; o < OPT; ++o) {
        int oc = obase + og * OPT + o;
        float bv = bias[oc];
#pragma unroll
        for (int p = 0; p < 4; ++p) {
            float val = fmaxf(acc[o][p] + bv, 0.f);
            size_t idx = (((size_t)b * COUT + oc) * 64 + h) * 64 + (w0 + p);
            if (ADD) out[idx] += val; else out[idx] = val;
        }
    }
}

// ---------------- PAM projections: q,k -> bf16 [n][32]; d -> VF fragment stream ----
__global__ __launch_bounds__(256) void pam_proj(
    const float* __restrict__ yp,
    const float* __restrict__ wb, const float* __restrict__ bbq,
    const float* __restrict__ wc, const float* __restrict__ bck,
    const float* __restrict__ wd, const float* __restrict__ bdv,
    unsigned short* __restrict__ Qb, unsigned short* __restrict__ Kb,
    unsigned short* __restrict__ VFo)
{
    const int b = blockIdx.y;
    const int n0 = blockIdx.x * 64;
    const int t = threadIdx.x;
    const int px = t & 63;
    const int og = t >> 6;

    __shared__ __align__(16) float lds_y[64][64];
    __shared__ __align__(16) float lds_w[64][164];

    float acc[10][4];
#pragma unroll
    for (int s = 0; s < 10; ++s) { acc[s][0] = acc[s][1] = acc[s][2] = acc[s][3] = 0.f; }

    for (int cb = 0; cb < 128; cb += 64) {
        for (int i = t; i < 4096; i += 256) {
            int c = i >> 6, p = i & 63;
            lds_y[c][p] = yp[(((size_t)b * 128 + cb + c) << 12) + n0 + p];
        }
        for (int i = t; i < 160 * 64; i += 256) {
            int c = i & 63, o = i >> 6;
            const float* src = (o < 16) ? (wb + o * 128)
                             : (o < 32) ? (wc + (o - 16) * 128)
                                        : (wd + (o - 32) * 128);
            lds_w[c][o] = src[cb + c];
        }
        __syncthreads();
        for (int c = 0; c < 64; ++c) {
            float yv = lds_y[c][px];
#pragma unroll
            for (int s = 0; s < 10; ++s) {
                const float4 w4 = *(const float4*)&lds_w[c][s * 16 + og * 4];
                acc[s][0] += w4.x * yv; acc[s][1] += w4.y * yv;
                acc[s][2] += w4.z * yv; acc[s][3] += w4.w * yv;
            }
        }
        __syncthreads();
    }
    const int n = n0 + px;
    const size_t qkrow = ((size_t)(b << 12) + n) << 5;
#pragma unroll
    for (int s = 0; s < 10; ++s) {
        const float* bsrc = (s == 0) ? (bbq + og * 4)
                          : (s == 1) ? (bck + og * 4)
                                     : (bdv + (s - 2) * 16 + og * 4);
        const float4 bv4 = *(const float4*)bsrc;
        float v0 = acc[s][0] + bv4.x, v1 = acc[s][1] + bv4.y;
        float v2 = acc[s][2] + bv4.z, v3 = acc[s][3] + bv4.w;
        if (s < 2) {
            unsigned short* dst = (s == 0) ? Qb : Kb;
            uint2 pk2;
            pk2.x = (unsigned)f2bf(v0) | ((unsigned)f2bf(v1) << 16);
            pk2.y = (unsigned)f2bf(v2) | ((unsigned)f2bf(v3) << 16);
            *(uint2*)&dst[qkrow + (og << 2)] = pk2;
            uint2 z2; z2.x = 0u; z2.y = 0u;
            *(uint2*)&dst[qkrow + 16 + (og << 2)] = z2;
        } else {
            const int cf = s - 2;
            const size_t blk = ((size_t)(b * 128 + (n >> 5)) * 8 + cf) << 9;
            const int gl = ((n >> 2) & 3) << 4;
            const int j = (n & 3) | (((n >> 4) & 1) << 2);
            const float vv[4] = {v0, v1, v2, v3};
#pragma unroll
            for (int u = 0; u < 4; ++u)
                VFo[blk + ((size_t)((gl | (og * 4 + u)) << 3)) + j] = f2bf(vv[u]);
        }
    }
}

// ---------------- PAM fused attention: bf16 MFMA, online softmax, 4-way key split --
// grid (128, B), 512 thr = 8 waves: qg = wid&1 (16 queries each), kq = wid>>1 (quarter).
__global__ __launch_bounds__(512, 4) void pam_attn_mfma(
    const unsigned short* __restrict__ Qb, const unsigned short* __restrict__ Kb,
    const unsigned short* __restrict__ VF, const float* __restrict__ yp,
    const float* __restrict__ alpha_p, float* __restrict__ P)
{
    const int b = blockIdx.y;
    const int q0 = blockIdx.x * 32;
    const int t = threadIdx.x;
    const int wid = t >> 6, lane = t & 63;
    const int qg = wid & 1, kq = wid >> 1;
    const int g = lane >> 4, qi = lane & 15;
    const int qw0 = q0 + qg * 16;

    __shared__ float combO[2][3][64][33];   // kq=1..3 partial O (padded: bank-safe)
    __shared__ float combL[2][4][16];
    __shared__ float combM[2][4][16];

    const bf16x8 qf = *(const bf16x8*)&Qb[(((size_t)(b << 12) + qw0 + qi) << 5) + (g << 3)];
    const unsigned short* __restrict__ Kbase = Kb + ((size_t)b << 17);
    const unsigned short* __restrict__ VFb = VF + ((size_t)b << 19);

    f32x4 accO[8];
#pragma unroll
    for (int cf = 0; cf < 8; ++cf) accO[cf] = (f32x4)0.0f;
    float lsum = 0.f;
    float m = -3.0e38f;

    const int ktbase = kq << 5;           // 32 kt (of 32 keys) per quarter
    bf16x8 kE = *(const bf16x8*)&Kbase[((size_t)((ktbase << 5) + qi) << 5) + (g << 3)];
    bf16x8 kO = *(const bf16x8*)&Kbase[((size_t)((ktbase << 5) + 16 + qi) << 5) + (g << 3)];

    for (int it = 0; it < 32; ++it) {
        const int kt = ktbase + it;
        const int itn = (it + 1 < 32) ? it + 1 : it;
        const int kbn = (ktbase + itn) << 5;
        const bf16x8 nkE = *(const bf16x8*)&Kbase[((size_t)(kbn + qi) << 5) + (g << 3)];
        const bf16x8 nkO = *(const bf16x8*)&Kbase[((size_t)(kbn + 16 + qi) << 5) + (g << 3)];

        f32x4 z = {};
        f32x4 sE = __builtin_amdgcn_mfma_f32_16x16x32_bf16(kE, qf, z, 0, 0, 0);
        f32x4 sO = __builtin_amdgcn_mfma_f32_16x16x32_bf16(kO, qf, z, 0, 0, 0);

        float pmax = fmaxf(fmaxf(fmaxf(sE[0], sE[1]), fmaxf(sE[2], sE[3])),
                           fmaxf(fmaxf(sO[0], sO[1]), fmaxf(sO[2], sO[3])));
        pmax = fmaxf(pmax, __shfl_xor(pmax, 16));
        pmax = fmaxf(pmax, __shfl_xor(pmax, 32));
        if (!__all(pmax <= m + 8.f)) {           // defer-max (T13): rare rescale
            const float nm = fmaxf(m, pmax);
            const float fac = __expf(m - nm);
            lsum *= fac;
#pragma unroll
            for (int cf = 0; cf < 8; ++cf) accO[cf] *= fac;
            m = nm;
        }
        bf16x8 pb;
        float es = 0.f;
#pragma unroll
        for (int r = 0; r < 4; ++r) {
            const float e0 = __expf(sE[r] - m);
            const float e1 = __expf(sO[r] - m);
            es += e0 + e1;
            pb[r] = (__bf16)e0;
            pb[4 + r] = (__bf16)e1;
        }
        lsum += es;
        const unsigned short* vt = VFb + ((size_t)kt << 12) + (lane << 3);
#pragma unroll
        for (int cf = 0; cf < 8; ++cf) {
            const bf16x8 vf = *(const bf16x8*)&vt[(size_t)cf << 9];
            accO[cf] = __builtin_amdgcn_mfma_f32_16x16x32_bf16(vf, pb, accO[cf], 0, 0, 0);
        }
        kE = nkE; kO = nkO;
    }
    lsum += __shfl_xor(lsum, 16);
    lsum += __shfl_xor(lsum, 32);

    if (lane < 16) { combM[qg][kq][lane] = m; combL[qg][kq][lane] = lsum; }
    __syncthreads();

    const float M = fmaxf(fmaxf(combM[qg][0][qi], combM[qg][1][qi]),
                          fmaxf(combM[qg][2][qi], combM[qg][3][qi]));
    const float fac = __expf(m - M);
#pragma unroll
    for (int cf = 0; cf < 8; ++cf) accO[cf] *= fac;

    if (kq > 0) {
#pragma unroll
        for (int cf = 0; cf < 8; ++cf)
#pragma unroll
            for (int r = 0; r < 4; ++r)
                combO[qg][kq - 1][lane][cf * 4 + r] = accO[cf][r];
    }
    __syncthreads();
    if (kq == 0) {
#pragma unroll
        for (int k2 = 0; k2 < 3; ++k2)
#pragma unroll
            for (int cf = 0; cf < 8; ++cf)
#pragma unroll
                for (int r = 0; r < 4; ++r)
                    accO[cf][r] += combO[qg][k2][lane][cf * 4 + r];
        float l = 0.f;
#pragma unroll
        for (int k2 = 0; k2 < 4; ++k2)
            l += __expf(combM[qg][k2][qi] - M) * combL[qg][k2][qi];
        const float sc = alpha_p[0] / l;
#pragma unroll
        for (int cf = 0; cf < 8; ++cf) {
#pragma unroll
            for (int r = 0; r < 4; ++r) {
                const int ch = cf * 16 + (g << 2) + r;
                const size_t o = (((size_t)(b * 128 + ch)) << 12) + qw0 + qi;
                P[o] = accO[cf][r] * sc + yp[o];
            }
        }
    }
}

// ---------------- CAM: Gram matrix ----------------
__global__ __launch_bounds__(256) void cam_gram(const float* __restrict__ yc, float* __restrict__ G)
{
    const int b = blockIdx.y;
    const int n0 = blockIdx.x * 128;
    const int t = threadIdx.x;
    const int rg = t & 15, cgg = t >> 4;
    __shared__ float a_t[64][133];
    float acc[8][8];
#pragma unroll
    for (int r = 0; r < 8; ++r)
#pragma unroll
        for (int c = 0; c < 8; ++c) acc[r][c] = 0.f;

    for (int ch = 0; ch < 2; ++ch) {
        const int nb = n0 + ch * 64;
        for (int i = t; i < 8192; i += 256) {
            int c = i >> 6, nn = i & 63;
            a_t[nn][c] = yc[(((size_t)b * 128 + c) << 12) + nb + nn];
        }
        __syncthreads();
        for (int nn = 0; nn < 64; ++nn) {
            float av[8], bv[8];
#pragma unroll
            for (int u = 0; u < 8; ++u) av[u] = a_t[nn][rg * 8 + u];
#pragma unroll
            for (int u = 0; u < 8; ++u) bv[u] = a_t[nn][cgg * 8 + u];
#pragma unroll
            for (int r = 0; r < 8; ++r)
#pragma unroll
                for (int c = 0; c < 8; ++c)
                    acc[r][c] += av[r] * bv[c];
        }
        __syncthreads();
    }
#pragma unroll
    for (int r = 0; r < 8; ++r)
#pragma unroll
        for (int c = 0; c < 8; ++c)
            atomicAdd(&G[((size_t)b << 14) + (size_t)(rg * 8 + r) * 128 + cgg * 8 + c], acc[r][c]);
}

// ---------------- CAM: softmax + apply + beta residual ----------------
__global__ __launch_bounds__(256) void cam_apply(
    const float* __restrict__ G, const float* __restrict__ yc,
    const float* __restrict__ beta_p, float* __restrict__ Cc)
{
    const int b = blockIdx.y;
    const int cchunk = blockIdx.x >> 3;
    const int ns = blockIdx.x & 7;
    const int t = threadIdx.x;

    __shared__ float att_t[128][32];
    __shared__ float s_buf[128 * 64];

    for (int i = t; i < 4096; i += 256)
        s_buf[i] = G[((size_t)b << 14) + (size_t)cchunk * 32 * 128 + i];
    __syncthreads();
    {
        const int r = t >> 3, seg = t & 7;
        float vals[16];
        float gmin = 3.0e38f;
#pragma unroll
        for (int u = 0; u < 16; ++u) {
            vals[u] = s_buf[r * 128 + seg * 16 + u];
            gmin = fminf(gmin, vals[u]);
        }
        gmin = fminf(gmin, __shfl_xor(gmin, 1));
        gmin = fminf(gmin, __shfl_xor(gmin, 2));
        gmin = fminf(gmin, __shfl_xor(gmin, 4));
        float sum = 0.f;
#pragma unroll
        for (int u = 0; u < 16; ++u) { vals[u] = __expf(gmin - vals[u]); sum += vals[u]; }
        sum += __shfl_xor(sum, 1);
        sum += __shfl_xor(sum, 2);
        sum += __shfl_xor(sum, 4);
        const float inv = 1.f / sum;
#pragma unroll
        for (int u = 0; u < 16; ++u)
            att_t[seg * 16 + u][r] = vals[u] * inv;
    }
    __syncthreads();

    const float be = beta_p[0];
    const int nc = t & 31, cgp = t >> 5;
    for (int chunk = 0; chunk < 8; ++chunk) {
        const int nb = ns * 512 + chunk * 64;
        for (int i = t; i < 8192; i += 256) {
            int d = i >> 6, nn = i & 63;
            s_buf[d * 64 + nn] = yc[(((size_t)b * 128 + d) << 12) + nb + nn];
        }
        __syncthreads();
        float a0[4] = {0, 0, 0, 0}, a1[4] = {0, 0, 0, 0};
        for (int d = 0; d < 128; ++d) {
            const float y0 = s_buf[d * 64 + nc];
            const float y1 = s_buf[d * 64 + nc + 32];
#pragma unroll
            for (int o = 0; o < 4; ++o) {
                const float wv = att_t[d][cgp * 4 + o];
                a0[o] += wv * y0; a1[o] += wv * y1;
            }
        }
#pragma unroll
        for (int o = 0; o < 4; ++o) {
            const int cl = cgp * 4 + o;
            const int c = cchunk * 32 + cl;
            const size_t base = (((size_t)b * 128 + c) << 12) + nb;
            Cc[base + nc]      = be * a0[o] + s_buf[c * 64 + nc];
            Cc[base + nc + 32] = be * a1[o] + s_buf[c * 64 + nc + 32];
        }
        __syncthreads();
    }
}

// ---------------- launcher ----------------
extern "C" void kernel_launch(void* const* d_in, const int* in_sizes, int n_in,
                              void* d_out, int out_size, void* d_ws, size_t ws_size,
                              hipStream_t stream)
{
    (void)in_sizes; (void)n_in; (void)out_size; (void)ws_size;
    const float* x    = (const float*)d_in[0];
    const float* wp1  = (const float*)d_in[1];
    const float* gp1  = (const float*)d_in[2];
    const float* bp1  = (const float*)d_in[3];
    const float* mp1  = (const float*)d_in[4];
    const float* vp1  = (const float*)d_in[5];
    const float* wc1  = (const float*)d_in[6];
    const float* gc1  = (const float*)d_in[7];
    const float* bc1  = (const float*)d_in[8];
    const float* mc1  = (const float*)d_in[9];
    const float* vc1  = (const float*)d_in[10];
    const float* pwb  = (const float*)d_in[11];
    const float* pbb  = (const float*)d_in[12];
    const float* pwc  = (const float*)d_in[13];
    const float* pbc  = (const float*)d_in[14];
    const float* pwd  = (const float*)d_in[15];
    const float* pbd  = (const float*)d_in[16];
    const float* alpha= (const float*)d_in[17];
    const float* beta = (const float*)d_in[18];
    const float* wp2  = (const float*)d_in[19];
    const float* gp2  = (const float*)d_in[20];
    const float* bp2  = (const float*)d_in[21];
    const float* mp2  = (const float*)d_in[22];
    const float* vp2  = (const float*)d_in[23];
    const float* wc2  = (const float*)d_in[24];
    const float* gc2  = (const float*)d_in[25];
    const float* bc2  = (const float*)d_in[26];
    const float* mc2  = (const float*)d_in[27];
    const float* vc2v = (const float*)d_in[28];

    float* W = (float*)d_ws;
    unsigned short* wb2p16 = (unsigned short*)(W + OFF_WB2P);
    unsigned short* wb2c16 = (unsigned short*)(W + OFF_WB2C);
    float* b1p = W + OFF_B1P;
    float* b1c = W + OFF_B1C;
    float* wt2p = W + OFF_WT2P;  float* b2p = W + OFF_B2P;
    float* wt2c = W + OFF_WT2C;  float* b2c = W + OFF_B2C;
    float* yp   = W + OFF_YP;
    float* yc   = W + OFF_YC;
    unsigned short* Qb16 = (unsigned short*)(W + OFF_Q);
    unsigned short* Kb16 = (unsigned short*)(W + OFF_K);
    unsigned short* VF16 = (unsigned short*)(W + OFF_V);
    float* Pp   = W + OFF_P;
    float* Cc   = W + OFF_CC;
    float* G    = W + OFF_G;
    unsigned short* xT16  = (unsigned short*)(W + OFF_P);   // alias, dead before Pp written
    unsigned short* zb16  = (unsigned short*)(W + OFF_Z);
    float* out  = (float*)d_out;

    // zero the Gram accumulator and the zero-row scratch (ws is 0xAA-poisoned)
    hipMemsetAsync(G, 0, (size_t)(65536 + 4096) * sizeof(float), stream);

    x_transpose<<<dim3(64, 4, 4), 256, 0, stream>>>(x, xT16);
    prep_conv_mfma<<<2304, 256, 0, stream>>>(wp1, gp1, bp1, mp1, vp1, wb2p16, b1p);
    prep_conv_mfma<<<2304, 256, 0, stream>>>(wc1, gc1, bc1, mc1, vc1, wb2c16, b1c);
    prep_conv<<<144, 256, 0, stream>>>(wp2, gp2, bp2, mp2, vp2, wt2p, b2p, 1152, 32);
    prep_conv<<<144, 256, 0, stream>>>(wc2, gc2, bc2, mc2, vc2v, wt2c, b2c, 1152, 32);

    conv1_mfma<<<dim3(128, 4), 256, 0, stream>>>(xT16, wb2p16, wb2c16, b1p, b1c, yp, yc, zb16);

    pam_proj<<<dim3(64, 4), 256, 0, stream>>>(yp, pwb, pbb, pwc, pbc, pwd, pbd, Qb16, Kb16, VF16);
    pam_attn_mfma<<<dim3(128, 4), 512, 0, stream>>>(Qb16, Kb16, VF16, yp, alpha, Pp);

    cam_gram <<<dim3(32, 4), 256, 0, stream>>>(yc, G);
    cam_apply<<<dim3(32, 4), 256, 0, stream>>>(G, yc, beta, Cc);

    conv3x3_bn_relu<128, 32, 32, false><<<dim3(256, 1), 256, 0, stream>>>(Pp, wt2p, b2p, out);
    conv3x3_bn_relu<128, 32, 32, true ><<<dim3(256, 1), 256, 0, stream>>>(Cc, wt2c, b2c, out);
}

// Round 5
// 347.333 us; speedup vs baseline: 5.1556x; 1.5208x over previous
//
#include <hip/hip_runtime.h>
#include <cstddef>
#include <cstdint>

#define EPSBN 1e-5f

typedef __attribute__((ext_vector_type(8))) __bf16 bf16x8;
typedef __attribute__((ext_vector_type(8))) short short8v;
typedef __attribute__((ext_vector_type(4))) float f32x4;

// ---------------- workspace layout (in floats) ----------------
static constexpr size_t SZ_WB2 = 294912;     // conv1 wb: 4608*128 ushorts / 2
static constexpr size_t SZ_WT2 = 36864;      // conv2 wb: 1152*32 ushorts fit easily
static constexpr size_t SZ_Y   = 2097152;    // 4*128*4096 fp32
static constexpr size_t SZ_QK  = 262144;     // 4*4096*32 ushorts / 2

static constexpr size_t OFF_WB2P = 0;
static constexpr size_t OFF_B1P  = OFF_WB2P + SZ_WB2;
static constexpr size_t OFF_WB2C = OFF_B1P + 128;
static constexpr size_t OFF_B1C  = OFF_WB2C + SZ_WB2;
static constexpr size_t OFF_WT2P = OFF_B1C + 128;
static constexpr size_t OFF_B2P  = OFF_WT2P + SZ_WT2;
static constexpr size_t OFF_WT2C = OFF_B2P + 32;
static constexpr size_t OFF_B2C  = OFF_WT2C + SZ_WT2;
static constexpr size_t OFF_YP   = OFF_B2C + 32;
static constexpr size_t OFF_YC   = OFF_YP + SZ_Y;
static constexpr size_t OFF_Q    = OFF_YC + SZ_Y;      // Qb bf16 [4][4096][32]
static constexpr size_t OFF_K    = OFF_Q + SZ_QK;      // Kb bf16 [4][4096][32]
static constexpr size_t OFF_V    = OFF_K + SZ_QK;      // VF bf16 frag stream, 4MB
static constexpr size_t OFF_PB   = OFF_V + SZ_Y;       // Pb bf16 [4][4096][128]
static constexpr size_t OFF_CB   = OFF_PB + 1048576;   // Cb bf16 [4][4096][128]
static constexpr size_t OFF_GP   = OFF_PB + 2097152;   // Gram partials [4][16][128][128] f32
static constexpr size_t OFF_G    = OFF_PB + 4194304;   // G [4][128][128] f32
static constexpr size_t OFF_Z    = OFF_G + 65536;      // 16KB zero scratch
// xT (bf16, 16MB = 4194304 float slots) ALIASES [OFF_PB, OFF_G): dead after conv1.

__device__ __forceinline__ unsigned short f2bf(float f) {
    unsigned u = __float_as_uint(f);
    unsigned r = (u + 0x7fffu + ((u >> 16) & 1u)) >> 16;
    return (unsigned short)r;
}

__device__ __forceinline__ void gload_lds16(const void* g, void* l) {
    __builtin_amdgcn_global_load_lds((const __attribute__((address_space(1))) void*)g,
                                     (__attribute__((address_space(3))) void*)l, 16, 0, 0);
}

// ---------------- x (fp32 NCHW) -> xT (bf16 [b][h][w][c]) ----------------
__global__ __launch_bounds__(256) void x_transpose(const float* __restrict__ x,
                                                   unsigned short* __restrict__ xT)
{
    const int h = blockIdx.x, b = blockIdx.y, cb0 = blockIdx.z * 128;
    __shared__ float tile[64][129];
    const int t = threadIdx.x;
    for (int i = t; i < 8192; i += 256) {
        int c = i >> 6, w = i & 63;
        tile[w][c] = x[(((size_t)(b * 512 + cb0 + c) * 64) + h) * 64 + w];
    }
    __syncthreads();
    for (int i = t; i < 8192; i += 256) {
        int w = i >> 7, c = i & 127;
        xT[(((size_t)(b * 64 + h) * 64) + w) * 512 + cb0 + c] = f2bf(tile[w][c]);
    }
}

// ---------------- fold BN into conv weights, bf16, staged layout (generic) ------
// wb2 order: [kh][cblk][kw][u = oc*4 + (g ^ ((oc>>1)&3))][j8], c = cblk*32+g*8+j.
__global__ void prep_conv_mfma(const float* __restrict__ w, const float* __restrict__ g,
                               const float* __restrict__ bb, const float* __restrict__ m,
                               const float* __restrict__ v, unsigned short* __restrict__ wb2,
                               float* __restrict__ bias, int cin, int cout)
{
    int idx = blockIdx.x * 256 + threadIdx.x;
    if (idx < cout) {
        float sc = g[idx] * rsqrtf(v[idx] + EPSBN);
        bias[idx] = bb[idx] - m[idx] * sc;
    }
    const int cin9 = cin * 9;
    if (idx >= cout * cin9) return;
    int oc = idx / cin9;
    int rem = idx - oc * cin9;
    int c = rem / 9;
    int tap = rem - c * 9;
    int kh = tap / 3, kw = tap - kh * 3;
    float sc = g[oc] * rsqrtf(v[oc] + EPSBN);
    float val = w[idx] * sc;
    int u = (oc << 2) + (((c >> 3) & 3) ^ ((oc >> 1) & 3));
    int ncb = cin >> 5;
    size_t dst = (((size_t)(kh * ncb + (c >> 5)) * 3 + kw) * ((size_t)cout << 2) + u) * 8 + (c & 7);
    wb2[dst] = f2bf(val);
}

// ---------------- conv1 (512->128, 3x3) via bf16 MFMA implicit GEMM ----------------
__global__ __launch_bounds__(256) void conv1_mfma(
    const unsigned short* __restrict__ xT,
    const unsigned short* __restrict__ wb2p, const unsigned short* __restrict__ wb2c,
    const float* __restrict__ b1p, const float* __restrict__ b1c,
    float* __restrict__ yp, float* __restrict__ yc,
    const unsigned short* __restrict__ zbuf)
{
    const int b = blockIdx.x >> 5;
    const int h0 = (blockIdx.x & 31) * 2;
    const bool isC = (blockIdx.y >> 1) != 0;
    const int ohalf = blockIdx.y & 1;
    const int obase = ohalf << 6;
    const unsigned short* __restrict__ wb2 = isC ? wb2c : wb2p;
    const float* __restrict__ bias = isC ? b1c : b1p;
    float* __restrict__ y = isC ? yc : yp;

    const int t = threadIdx.x;
    const int wid = t >> 6, lane = t & 63;
    const int lhi = lane >> 4, llo = lane & 15;

    __shared__ __align__(16) unsigned short lds_x[8192];
    __shared__ __align__(16) unsigned short lds_w[6144];

    f32x4 acc[4][2];
#pragma unroll
    for (int i = 0; i < 4; ++i)
#pragma unroll
        for (int j = 0; j < 2; ++j) acc[i][j] = (f32x4)0.0f;

    for (int cc = 0; cc < 16; ++cc) {
        const int cb = cc * 32;
        __syncthreads();
        for (int i = wid; i < 16; i += 4) {
            const int u = (i << 6) + lane;
            const int row = u >> 8;
            const int col = (u >> 2) & 63;
            const int g2 = (u & 3) ^ ((col >> 1) & 3);
            const int xrow = h0 - 1 + row;
            const unsigned short* src = ((unsigned)xrow < 64u)
                ? xT + (((size_t)((b << 6) + xrow) << 6) + col) * 512 + cb + (g2 << 3)
                : zbuf;
            gload_lds16(src, &lds_x[(size_t)i << 9]);
        }
        {
            const unsigned short* ws = wb2 + ((size_t)(cc * 3) * 512 + (ohalf << 8)) * 8;
            for (int i = wid; i < 12; i += 4) {
                const int kw = i >> 2, seg = i & 3;
                gload_lds16(ws + ((size_t)(kw * 512 + (seg << 6) + lane) << 3),
                            &lds_w[(size_t)i << 9]);
            }
        }
        for (int kh = 0; kh < 3; ++kh) {
            if (kh) {
                __syncthreads();
                const unsigned short* ws = wb2 + ((size_t)((kh * 16 + cc) * 3) * 512 + (ohalf << 8)) * 8;
                for (int i = wid; i < 12; i += 4) {
                    const int kw = i >> 2, seg = i & 3;
                    gload_lds16(ws + ((size_t)(kw * 512 + (seg << 6) + lane) << 3),
                                &lds_w[(size_t)i << 9]);
                }
            }
            __syncthreads();
#pragma unroll
            for (int kw = 0; kw < 3; ++kw) {
                bf16x8 afr[4];
#pragma unroll
                for (int mf = 0; mf < 4; ++mf) {
                    const int ocl = (mf << 4) + llo;
                    const int un = (kw << 8) + (ocl << 2) + (lhi ^ ((ocl >> 1) & 3));
                    afr[mf] = *(const bf16x8*)&lds_w[un << 3];
                }
                bf16x8 bfr[2];
#pragma unroll
                for (int nf = 0; nf < 2; ++nf) {
                    const int px = (wid << 5) + (nf << 4) + llo;
                    const int orow = px >> 6;
                    const int wc = (px & 63) + kw - 1;
                    const bool inb = (unsigned)wc < 64u;
                    const int wcc = inb ? wc : 0;
                    const int un = (((orow + kh) << 6) + wcc) * 4 + (lhi ^ ((wcc >> 1) & 3));
                    short8v raw = *(const short8v*)&lds_x[un << 3];
                    short8v zz = {};
                    if (!inb) raw = zz;
                    bfr[nf] = __builtin_bit_cast(bf16x8, raw);
                }
#pragma unroll
                for (int mf = 0; mf < 4; ++mf)
#pragma unroll
                    for (int nf = 0; nf < 2; ++nf)
                        acc[mf][nf] = __builtin_amdgcn_mfma_f32_16x16x32_bf16(
                            afr[mf], bfr[nf], acc[mf][nf], 0, 0, 0);
            }
        }
    }

#pragma unroll
    for (int mf = 0; mf < 4; ++mf) {
#pragma unroll
        for (int r = 0; r < 4; ++r) {
            const int oc = obase + (mf << 4) + (lhi << 2) + r;
            const float bv = bias[oc];
#pragma unroll
            for (int nf = 0; nf < 2; ++nf) {
                const int px = (wid << 5) + (nf << 4) + llo;
                const int hout = h0 + (px >> 6);
                const int colw = px & 63;
                float* dst = y + (((size_t)(b * 128 + oc) << 6) + hout) * 64;
                dst[colw] = fmaxf(acc[mf][nf][r] + bv, 0.f);
            }
        }
    }
}

// ---------------- conv2 pair (128->32 x2, 3x3) fused MFMA: out = relu(P*wp)+relu(C*wc)
// grid (128): b*32 + rowpair. 256 thr / 4 waves; wave: 32 px x 32 oc x 2 convs.
__global__ __launch_bounds__(256) void conv2_mfma(
    const unsigned short* __restrict__ Pb, const unsigned short* __restrict__ Cb,
    const unsigned short* __restrict__ wbp, const unsigned short* __restrict__ wbc,
    const float* __restrict__ b2p, const float* __restrict__ b2c,
    float* __restrict__ out, const unsigned short* __restrict__ zbuf)
{
    const int b = blockIdx.x >> 5;
    const int h0 = (blockIdx.x & 31) * 2;
    const int t = threadIdx.x;
    const int wid = t >> 6, lane = t & 63;
    const int lhi = lane >> 4, llo = lane & 15;

    __shared__ __align__(16) unsigned short xP[8192];
    __shared__ __align__(16) unsigned short xC[8192];
    __shared__ __align__(16) unsigned short wbuf[2][3072];

    f32x4 accP[2][2], accC[2][2];
#pragma unroll
    for (int i = 0; i < 2; ++i)
#pragma unroll
        for (int j = 0; j < 2; ++j) { accP[i][j] = (f32x4)0.0f; accC[i][j] = (f32x4)0.0f; }

    for (int cc = 0; cc < 4; ++cc) {
        const int cb = cc * 32;
        __syncthreads();
        for (int i = wid; i < 16; i += 4) {
            const int u = (i << 6) + lane;
            const int row = u >> 8;
            const int col = (u >> 2) & 63;
            const int g2 = (u & 3) ^ ((col >> 1) & 3);
            const int xrow = h0 - 1 + row;
            const bool inb = (unsigned)xrow < 64u;
            const size_t off = ((((size_t)((b << 6) + (inb ? xrow : 0)) << 6) + col) << 7) + cb + (g2 << 3);
            gload_lds16(inb ? (Pb + off) : zbuf, &xP[(size_t)i << 9]);
            gload_lds16(inb ? (Cb + off) : zbuf, &xC[(size_t)i << 9]);
        }
        {
            const size_t wb0 = (size_t)(cc * 3) * 1024;   // kh=0 base (ushorts)
            for (int i = wid; i < 12; i += 4) {
                const int cv = (i >= 6);
                const int ii = i - cv * 6;
                const unsigned short* ws = (cv ? wbc : wbp) + wb0;
                gload_lds16(ws + ((ii << 9) + (lane << 3)), &wbuf[cv][(size_t)ii << 9]);
            }
        }
        for (int kh = 0; kh < 3; ++kh) {
            if (kh) {
                __syncthreads();
                const size_t wb0 = (size_t)((kh * 4 + cc) * 3) * 1024;
                for (int i = wid; i < 12; i += 4) {
                    const int cv = (i >= 6);
                    const int ii = i - cv * 6;
                    const unsigned short* ws = (cv ? wbc : wbp) + wb0;
                    gload_lds16(ws + ((ii << 9) + (lane << 3)), &wbuf[cv][(size_t)ii << 9]);
                }
            }
            __syncthreads();
#pragma unroll
            for (int kw = 0; kw < 3; ++kw) {
                bf16x8 afrP[2], afrC[2];
#pragma unroll
                for (int mf = 0; mf < 2; ++mf) {
                    const int ocl = (mf << 4) + llo;
                    const int un = (kw << 7) + (ocl << 2) + (lhi ^ ((ocl >> 1) & 3));
                    afrP[mf] = *(const bf16x8*)&wbuf[0][un << 3];
                    afrC[mf] = *(const bf16x8*)&wbuf[1][un << 3];
                }
                bf16x8 bfrP[2], bfrC[2];
#pragma unroll
                for (int nf = 0; nf < 2; ++nf) {
                    const int px = (wid << 5) + (nf << 4) + llo;
                    const int orow = px >> 6;
                    const int wc = (px & 63) + kw - 1;
                    const bool inb = (unsigned)wc < 64u;
                    const int wcc = inb ? wc : 0;
                    const int un = (((orow + kh) << 6) + wcc) * 4 + (lhi ^ ((wcc >> 1) & 3));
                    short8v rawP = *(const short8v*)&xP[un << 3];
                    short8v rawC = *(const short8v*)&xC[un << 3];
                    short8v zz = {};
                    if (!inb) { rawP = zz; rawC = zz; }
                    bfrP[nf] = __builtin_bit_cast(bf16x8, rawP);
                    bfrC[nf] = __builtin_bit_cast(bf16x8, rawC);
                }
#pragma unroll
                for (int mf = 0; mf < 2; ++mf)
#pragma unroll
                    for (int nf = 0; nf < 2; ++nf) {
                        accP[mf][nf] = __builtin_amdgcn_mfma_f32_16x16x32_bf16(
                            afrP[mf], bfrP[nf], accP[mf][nf], 0, 0, 0);
                        accC[mf][nf] = __builtin_amdgcn_mfma_f32_16x16x32_bf16(
                            afrC[mf], bfrC[nf], accC[mf][nf], 0, 0, 0);
                    }
            }
        }
    }

#pragma unroll
    for (int mf = 0; mf < 2; ++mf) {
#pragma unroll
        for (int r = 0; r < 4; ++r) {
            const int oc = (mf << 4) + (lhi << 2) + r;
            const float bp = b2p[oc], bc = b2c[oc];
#pragma unroll
            for (int nf = 0; nf < 2; ++nf) {
                const int px = (wid << 5) + (nf << 4) + llo;
                const int hout = h0 + (px >> 6);
                const int colw = px & 63;
                const float val = fmaxf(accP[mf][nf][r] + bp, 0.f)
                                + fmaxf(accC[mf][nf][r] + bc, 0.f);
                out[(((size_t)(b * 32 + oc)) << 12) + (hout << 6) + colw] = val;
            }
        }
    }
}

// ---------------- PAM projections: q,k -> bf16 [n][32]; d -> VF fragment stream ----
__global__ __launch_bounds__(256) void pam_proj(
    const float* __restrict__ yp,
    const float* __restrict__ wb, const float* __restrict__ bbq,
    const float* __restrict__ wc, const float* __restrict__ bck,
    const float* __restrict__ wd, const float* __restrict__ bdv,
    unsigned short* __restrict__ Qb, unsigned short* __restrict__ Kb,
    unsigned short* __restrict__ VFo)
{
    const int b = blockIdx.y;
    const int n0 = blockIdx.x * 64;
    const int t = threadIdx.x;
    const int px = t & 63;
    const int og = t >> 6;

    __shared__ __align__(16) float lds_y[64][64];
    __shared__ __align__(16) float lds_w[64][164];

    float acc[10][4];
#pragma unroll
    for (int s = 0; s < 10; ++s) { acc[s][0] = acc[s][1] = acc[s][2] = acc[s][3] = 0.f; }

    for (int cb = 0; cb < 128; cb += 64) {
        for (int i = t; i < 4096; i += 256) {
            int c = i >> 6, p = i & 63;
            lds_y[c][p] = yp[(((size_t)b * 128 + cb + c) << 12) + n0 + p];
        }
        for (int i = t; i < 160 * 64; i += 256) {
            int c = i & 63, o = i >> 6;
            const float* src = (o < 16) ? (wb + o * 128)
                             : (o < 32) ? (wc + (o - 16) * 128)
                                        : (wd + (o - 32) * 128);
            lds_w[c][o] = src[cb + c];
        }
        __syncthreads();
        for (int c = 0; c < 64; ++c) {
            float yv = lds_y[c][px];
#pragma unroll
            for (int s = 0; s < 10; ++s) {
                const float4 w4 = *(const float4*)&lds_w[c][s * 16 + og * 4];
                acc[s][0] += w4.x * yv; acc[s][1] += w4.y * yv;
                acc[s][2] += w4.z * yv; acc[s][3] += w4.w * yv;
            }
        }
        __syncthreads();
    }
    const int n = n0 + px;
    const size_t qkrow = ((size_t)(b << 12) + n) << 5;
#pragma unroll
    for (int s = 0; s < 10; ++s) {
        const float* bsrc = (s == 0) ? (bbq + og * 4)
                          : (s == 1) ? (bck + og * 4)
                                     : (bdv + (s - 2) * 16 + og * 4);
        const float4 bv4 = *(const float4*)bsrc;
        float v0 = acc[s][0] + bv4.x, v1 = acc[s][1] + bv4.y;
        float v2 = acc[s][2] + bv4.z, v3 = acc[s][3] + bv4.w;
        if (s < 2) {
            unsigned short* dst = (s == 0) ? Qb : Kb;
            uint2 pk2;
            pk2.x = (unsigned)f2bf(v0) | ((unsigned)f2bf(v1) << 16);
            pk2.y = (unsigned)f2bf(v2) | ((unsigned)f2bf(v3) << 16);
            *(uint2*)&dst[qkrow + (og << 2)] = pk2;
            uint2 z2; z2.x = 0u; z2.y = 0u;
            *(uint2*)&dst[qkrow + 16 + (og << 2)] = z2;
        } else {
            const int cf = s - 2;
            const size_t blk = ((size_t)(b * 128 + (n >> 5)) * 8 + cf) << 9;
            const int gl = ((n >> 2) & 3) << 4;
            const int j = (n & 3) | (((n >> 4) & 1) << 2);
            const float vv[4] = {v0, v1, v2, v3};
#pragma unroll
            for (int u = 0; u < 4; ++u)
                VFo[blk + ((size_t)((gl | (og * 4 + u)) << 3)) + j] = f2bf(vv[u]);
        }
    }
}

// ---------------- PAM fused attention: bf16 MFMA, online softmax, 4-way key split --
// Writes Pb bf16 [b][n][128] (residual included) via LDS repack.
__global__ __launch_bounds__(512, 4) void pam_attn_mfma(
    const unsigned short* __restrict__ Qb, const unsigned short* __restrict__ Kb,
    const unsigned short* __restrict__ VF, const float* __restrict__ yp,
    const float* __restrict__ alpha_p, unsigned short* __restrict__ Pb)
{
    const int b = blockIdx.y;
    const int q0 = blockIdx.x * 32;
    const int t = threadIdx.x;
    const int wid = t >> 6, lane = t & 63;
    const int qg = wid & 1, kq = wid >> 1;
    const int g = lane >> 4, qi = lane & 15;
    const int qw0 = q0 + qg * 16;

    __shared__ float combO[2][3][64][33];
    __shared__ float combL[2][4][16];
    __shared__ float combM[2][4][16];
    unsigned short* smP = (unsigned short*)combO;   // reused after final reads

    const bf16x8 qf = *(const bf16x8*)&Qb[(((size_t)(b << 12) + qw0 + qi) << 5) + (g << 3)];
    const unsigned short* __restrict__ Kbase = Kb + ((size_t)b << 17);
    const unsigned short* __restrict__ VFb = VF + ((size_t)b << 19);

    f32x4 accO[8];
#pragma unroll
    for (int cf = 0; cf < 8; ++cf) accO[cf] = (f32x4)0.0f;
    float lsum = 0.f;
    float m = -3.0e38f;

    const int ktbase = kq << 5;
    bf16x8 kE = *(const bf16x8*)&Kbase[((size_t)((ktbase << 5) + qi) << 5) + (g << 3)];
    bf16x8 kO = *(const bf16x8*)&Kbase[((size_t)((ktbase << 5) + 16 + qi) << 5) + (g << 3)];

    for (int it = 0; it < 32; ++it) {
        const int kt = ktbase + it;
        const int itn = (it + 1 < 32) ? it + 1 : it;
        const int kbn = (ktbase + itn) << 5;
        const bf16x8 nkE = *(const bf16x8*)&Kbase[((size_t)(kbn + qi) << 5) + (g << 3)];
        const bf16x8 nkO = *(const bf16x8*)&Kbase[((size_t)(kbn + 16 + qi) << 5) + (g << 3)];

        f32x4 z = {};
        f32x4 sE = __builtin_amdgcn_mfma_f32_16x16x32_bf16(kE, qf, z, 0, 0, 0);
        f32x4 sO = __builtin_amdgcn_mfma_f32_16x16x32_bf16(kO, qf, z, 0, 0, 0);

        float pmax = fmaxf(fmaxf(fmaxf(sE[0], sE[1]), fmaxf(sE[2], sE[3])),
                           fmaxf(fmaxf(sO[0], sO[1]), fmaxf(sO[2], sO[3])));
        pmax = fmaxf(pmax, __shfl_xor(pmax, 16));
        pmax = fmaxf(pmax, __shfl_xor(pmax, 32));
        if (!__all(pmax <= m + 8.f)) {
            const float nm = fmaxf(m, pmax);
            const float fac = __expf(m - nm);
            lsum *= fac;
#pragma unroll
            for (int cf = 0; cf < 8; ++cf) accO[cf] *= fac;
            m = nm;
        }
        bf16x8 pb;
        float es = 0.f;
#pragma unroll
        for (int r = 0; r < 4; ++r) {
            const float e0 = __expf(sE[r] - m);
            const float e1 = __expf(sO[r] - m);
            es += e0 + e1;
            pb[r] = (__bf16)e0;
            pb[4 + r] = (__bf16)e1;
        }
        lsum += es;
        const unsigned short* vt = VFb + ((size_t)kt << 12) + (lane << 3);
#pragma unroll
        for (int cf = 0; cf < 8; ++cf) {
            const bf16x8 vf = *(const bf16x8*)&vt[(size_t)cf << 9];
            accO[cf] = __builtin_amdgcn_mfma_f32_16x16x32_bf16(vf, pb, accO[cf], 0, 0, 0);
        }
        kE = nkE; kO = nkO;
    }
    lsum += __shfl_xor(lsum, 16);
    lsum += __shfl_xor(lsum, 32);

    if (lane < 16) { combM[qg][kq][lane] = m; combL[qg][kq][lane] = lsum; }
    __syncthreads();

    const float M = fmaxf(fmaxf(combM[qg][0][qi], combM[qg][1][qi]),
                          fmaxf(combM[qg][2][qi], combM[qg][3][qi]));
    const float fac = __expf(m - M);
#pragma unroll
    for (int cf = 0; cf < 8; ++cf) accO[cf] *= fac;

    if (kq > 0) {
#pragma unroll
        for (int cf = 0; cf < 8; ++cf)
#pragma unroll
            for (int r = 0; r < 4; ++r)
                combO[qg][kq - 1][lane][cf * 4 + r] = accO[cf][r];
    }
    __syncthreads();
    float sc = 0.f;
    if (kq == 0) {
#pragma unroll
        for (int k2 = 0; k2 < 3; ++k2)
#pragma unroll
            for (int cf = 0; cf < 8; ++cf)
#pragma unroll
                for (int r = 0; r < 4; ++r)
                    accO[cf][r] += combO[qg][k2][lane][cf * 4 + r];
        float l = 0.f;
#pragma unroll
        for (int k2 = 0; k2 < 4; ++k2)
            l += __expf(combM[qg][k2][qi] - M) * combL[qg][k2][qi];
        sc = alpha_p[0] / l;
    }
    __syncthreads();              // all combO reads done; safe to reuse as smP
    if (kq == 0) {
#pragma unroll
        for (int cf = 0; cf < 8; ++cf) {
#pragma unroll
            for (int r = 0; r < 4; ++r) {
                const int ch = cf * 16 + (g << 2) + r;
                const size_t o = (((size_t)(b * 128 + ch)) << 12) + qw0 + qi;
                const float val = accO[cf][r] * sc + yp[o];
                smP[(qg * 16 + qi) * 128 + ch] = f2bf(val);
            }
        }
    }
    __syncthreads();
    // coalesced copy-out: 32 rows x 128 ushorts = 2048 u32
    unsigned* Pb32 = (unsigned*)Pb;
    const unsigned* sm32 = (const unsigned*)smP;
    for (int i = t; i < 2048; i += 512) {
        const int row = i >> 6, u = i & 63;
        Pb32[((size_t)(b << 12) + q0 + row) * 64 + u] = sm32[i];
    }
}

// ---------------- CAM Gram via MFMA, bf16 hi/lo split (fp32-accurate) ----------
// grid (16, B): K-chunk of 256 positions. Direct per-lane fragment loads, no LDS.
__global__ __launch_bounds__(256) void cam_gram_mfma(const float* __restrict__ yc,
                                                     float* __restrict__ GP)
{
    const int kb = blockIdx.x, b = blockIdx.y;
    const int t = threadIdx.x;
    const int wid = t >> 6, lane = t & 63;
    const int lhi = lane >> 4, llo = lane & 15;
    const int mr = (wid & 1) << 6, nr = (wid >> 1) << 6;
    const float* __restrict__ Y = yc + ((size_t)b << 19);

    f32x4 acc[4][4];
#pragma unroll
    for (int i = 0; i < 4; ++i)
#pragma unroll
        for (int j = 0; j < 4; ++j) acc[i][j] = (f32x4)0.0f;

    for (int ks = 0; ks < 8; ++ks) {
        const int n0 = (kb << 8) + (ks << 5) + (lhi << 3);
        bf16x8 ah[4], al[4], bh[4], bl[4];
#pragma unroll
        for (int mf = 0; mf < 4; ++mf) {
            const int row = mr + (mf << 4) + llo;
            const float* p = &Y[((size_t)row << 12) + n0];
            const float4 v0 = *(const float4*)p;
            const float4 v1 = *(const float4*)(p + 4);
            const float vv[8] = {v0.x, v0.y, v0.z, v0.w, v1.x, v1.y, v1.z, v1.w};
#pragma unroll
            for (int j = 0; j < 8; ++j) {
                const __bf16 h = (__bf16)vv[j];
                ah[mf][j] = h;
                al[mf][j] = (__bf16)(vv[j] - (float)h);
            }
        }
#pragma unroll
        for (int nf = 0; nf < 4; ++nf) {
            const int row = nr + (nf << 4) + llo;
            const float* p = &Y[((size_t)row << 12) + n0];
            const float4 v0 = *(const float4*)p;
            const float4 v1 = *(const float4*)(p + 4);
            const float vv[8] = {v0.x, v0.y, v0.z, v0.w, v1.x, v1.y, v1.z, v1.w};
#pragma unroll
            for (int j = 0; j < 8; ++j) {
                const __bf16 h = (__bf16)vv[j];
                bh[nf][j] = h;
                bl[nf][j] = (__bf16)(vv[j] - (float)h);
            }
        }
#pragma unroll
        for (int mf = 0; mf < 4; ++mf)
#pragma unroll
            for (int nf = 0; nf < 4; ++nf) {
                acc[mf][nf] = __builtin_amdgcn_mfma_f32_16x16x32_bf16(ah[mf], bh[nf], acc[mf][nf], 0, 0, 0);
                acc[mf][nf] = __builtin_amdgcn_mfma_f32_16x16x32_bf16(ah[mf], bl[nf], acc[mf][nf], 0, 0, 0);
                acc[mf][nf] = __builtin_amdgcn_mfma_f32_16x16x32_bf16(al[mf], bh[nf], acc[mf][nf], 0, 0, 0);
            }
    }
    const size_t base = ((size_t)((b << 4) + kb) << 14);
#pragma unroll
    for (int mf = 0; mf < 4; ++mf)
#pragma unroll
        for (int nf = 0; nf < 4; ++nf)
#pragma unroll
            for (int r = 0; r < 4; ++r) {
                const int c = mr + (mf << 4) + (lhi << 2) + r;
                const int d = nr + (nf << 4) + llo;
                GP[base + ((size_t)c << 7) + d] = acc[mf][nf][r];
            }
}

__global__ __launch_bounds__(256) void cam_gram_reduce(const float* __restrict__ GP,
                                                       float* __restrict__ G)
{
    const int b = blockIdx.y;
    const int i0 = blockIdx.x * 1024 + threadIdx.x * 4;
    float4 s = make_float4(0.f, 0.f, 0.f, 0.f);
#pragma unroll
    for (int kb = 0; kb < 16; ++kb) {
        const float4 v = *(const float4*)&GP[((size_t)((b << 4) + kb) << 14) + i0];
        s.x += v.x; s.y += v.y; s.z += v.z; s.w += v.w;
    }
    *(float4*)&G[((size_t)b << 14) + i0] = s;
}

// ---------------- CAM: softmax + apply + beta residual -> Cb bf16 [b][n][128] ----
__global__ __launch_bounds__(256) void cam_apply(
    const float* __restrict__ G, const float* __restrict__ yc,
    const float* __restrict__ beta_p, unsigned short* __restrict__ Cb)
{
    const int b = blockIdx.y;
    const int cchunk = blockIdx.x >> 3;
    const int ns = blockIdx.x & 7;
    const int t = threadIdx.x;

    __shared__ float att_t[128][32];
    __shared__ float s_buf[128 * 64];
    __shared__ unsigned short smC[64 * 32];

    for (int i = t; i < 4096; i += 256)
        s_buf[i] = G[((size_t)b << 14) + (size_t)cchunk * 32 * 128 + i];
    __syncthreads();
    {
        const int r = t >> 3, seg = t & 7;
        float vals[16];
        float gmin = 3.0e38f;
#pragma unroll
        for (int u = 0; u < 16; ++u) {
            vals[u] = s_buf[r * 128 + seg * 16 + u];
            gmin = fminf(gmin, vals[u]);
        }
        gmin = fminf(gmin, __shfl_xor(gmin, 1));
        gmin = fminf(gmin, __shfl_xor(gmin, 2));
        gmin = fminf(gmin, __shfl_xor(gmin, 4));
        float sum = 0.f;
#pragma unroll
        for (int u = 0; u < 16; ++u) { vals[u] = __expf(gmin - vals[u]); sum += vals[u]; }
        sum += __shfl_xor(sum, 1);
        sum += __shfl_xor(sum, 2);
        sum += __shfl_xor(sum, 4);
        const float inv = 1.f / sum;
#pragma unroll
        for (int u = 0; u < 16; ++u)
            att_t[seg * 16 + u][r] = vals[u] * inv;
    }
    __syncthreads();

    const float be = beta_p[0];
    const int nc = t & 31, cgp = t >> 5;
    unsigned* Cb32 = (unsigned*)Cb;
    const unsigned* smC32 = (const unsigned*)smC;
    for (int chunk = 0; chunk < 8; ++chunk) {
        const int nb = ns * 512 + chunk * 64;
        for (int i = t; i < 8192; i += 256) {
            int d = i >> 6, nn = i & 63;
            s_buf[d * 64 + nn] = yc[(((size_t)b * 128 + d) << 12) + nb + nn];
        }
        __syncthreads();
        float a0[4] = {0, 0, 0, 0}, a1[4] = {0, 0, 0, 0};
        for (int d = 0; d < 128; ++d) {
            const float y0 = s_buf[d * 64 + nc];
            const float y1 = s_buf[d * 64 + nc + 32];
#pragma unroll
            for (int o = 0; o < 4; ++o) {
                const float wv = att_t[d][cgp * 4 + o];
                a0[o] += wv * y0; a1[o] += wv * y1;
            }
        }
#pragma unroll
        for (int o = 0; o < 4; ++o) {
            const int cl = cgp * 4 + o;
            const int c = cchunk * 32 + cl;
            smC[nc * 32 + cl]        = f2bf(be * a0[o] + s_buf[c * 64 + nc]);
            smC[(nc + 32) * 32 + cl] = f2bf(be * a1[o] + s_buf[c * 64 + nc + 32]);
        }
        __syncthreads();
        for (int i = t; i < 1024; i += 256) {
            const int row = i >> 4, u = i & 15;
            Cb32[((size_t)(b << 12) + nb + row) * 64 + (cchunk << 4) + u] = smC32[i];
        }
        __syncthreads();
    }
}

// ---------------- launcher ----------------
extern "C" void kernel_launch(void* const* d_in, const int* in_sizes, int n_in,
                              void* d_out, int out_size, void* d_ws, size_t ws_size,
                              hipStream_t stream)
{
    (void)in_sizes; (void)n_in; (void)out_size; (void)ws_size;
    const float* x    = (const float*)d_in[0];
    const float* wp1  = (const float*)d_in[1];
    const float* gp1  = (const float*)d_in[2];
    const float* bp1  = (const float*)d_in[3];
    const float* mp1  = (const float*)d_in[4];
    const float* vp1  = (const float*)d_in[5];
    const float* wc1  = (const float*)d_in[6];
    const float* gc1  = (const float*)d_in[7];
    const float* bc1  = (const float*)d_in[8];
    const float* mc1  = (const float*)d_in[9];
    const float* vc1  = (const float*)d_in[10];
    const float* pwb  = (const float*)d_in[11];
    const float* pbb  = (const float*)d_in[12];
    const float* pwc  = (const float*)d_in[13];
    const float* pbc  = (const float*)d_in[14];
    const float* pwd  = (const float*)d_in[15];
    const float* pbd  = (const float*)d_in[16];
    const float* alpha= (const float*)d_in[17];
    const float* beta = (const float*)d_in[18];
    const float* wp2  = (const float*)d_in[19];
    const float* gp2  = (const float*)d_in[20];
    const float* bp2  = (const float*)d_in[21];
    const float* mp2  = (const float*)d_in[22];
    const float* vp2  = (const float*)d_in[23];
    const float* wc2  = (const float*)d_in[24];
    const float* gc2  = (const float*)d_in[25];
    const float* bc2  = (const float*)d_in[26];
    const float* mc2  = (const float*)d_in[27];
    const float* vc2  = (const float*)d_in[28];

    float* W = (float*)d_ws;
    unsigned short* wb2p16 = (unsigned short*)(W + OFF_WB2P);
    unsigned short* wb2c16 = (unsigned short*)(W + OFF_WB2C);
    float* b1p = W + OFF_B1P;
    float* b1c = W + OFF_B1C;
    unsigned short* wt2p16 = (unsigned short*)(W + OFF_WT2P);
    unsigned short* wt2c16 = (unsigned short*)(W + OFF_WT2C);
    float* b2p = W + OFF_B2P;
    float* b2c = W + OFF_B2C;
    float* yp   = W + OFF_YP;
    float* yc   = W + OFF_YC;
    unsigned short* Qb16 = (unsigned short*)(W + OFF_Q);
    unsigned short* Kb16 = (unsigned short*)(W + OFF_K);
    unsigned short* VF16 = (unsigned short*)(W + OFF_V);
    unsigned short* Pb16 = (unsigned short*)(W + OFF_PB);
    unsigned short* Cb16 = (unsigned short*)(W + OFF_CB);
    float* GP   = W + OFF_GP;
    float* G    = W + OFF_G;
    unsigned short* xT16  = (unsigned short*)(W + OFF_PB);  // alias, dead after conv1
    unsigned short* zb16  = (unsigned short*)(W + OFF_Z);
    float* out  = (float*)d_out;

    // zero the OOB-row scratch (ws is 0xAA-poisoned each call)
    hipMemsetAsync(zb16, 0, 4096 * sizeof(float), stream);

    x_transpose<<<dim3(64, 4, 4), 256, 0, stream>>>(x, xT16);
    prep_conv_mfma<<<2304, 256, 0, stream>>>(wp1, gp1, bp1, mp1, vp1, wb2p16, b1p, 512, 128);
    prep_conv_mfma<<<2304, 256, 0, stream>>>(wc1, gc1, bc1, mc1, vc1, wb2c16, b1c, 512, 128);
    prep_conv_mfma<<<144,  256, 0, stream>>>(wp2, gp2, bp2, mp2, vp2, wt2p16, b2p, 128, 32);
    prep_conv_mfma<<<144,  256, 0, stream>>>(wc2, gc2, bc2, mc2, vc2, wt2c16, b2c, 128, 32);

    conv1_mfma<<<dim3(128, 4), 256, 0, stream>>>(xT16, wb2p16, wb2c16, b1p, b1c, yp, yc, zb16);

    pam_proj<<<dim3(64, 4), 256, 0, stream>>>(yp, pwb, pbb, pwc, pbc, pwd, pbd, Qb16, Kb16, VF16);
    pam_attn_mfma<<<dim3(128, 4), 512, 0, stream>>>(Qb16, Kb16, VF16, yp, alpha, Pb16);

    cam_gram_mfma<<<dim3(16, 4), 256, 0, stream>>>(yc, GP);
    cam_gram_reduce<<<dim3(16, 4), 256, 0, stream>>>(GP, G);
    cam_apply<<<dim3(32, 4), 256, 0, stream>>>(G, yc, beta, Cb16);

    conv2_mfma<<<128, 256, 0, stream>>>(Pb16, Cb16, wt2p16, wt2c16, b2p, b2c, out, zb16);
}

// Round 6
// 340.364 us; speedup vs baseline: 5.2612x; 1.0205x over previous
//
#include <hip/hip_runtime.h>
#include <cstddef>
#include <cstdint>

#define EPSBN 1e-5f
#define LOG2E 1.4426950408889634f

typedef __attribute__((ext_vector_type(8))) __bf16 bf16x8;
typedef __attribute__((ext_vector_type(8))) short short8v;
typedef __attribute__((ext_vector_type(4))) float f32x4;

// ---------------- workspace layout (in floats) ----------------
static constexpr size_t SZ_WB2 = 294912;     // conv1 wb: 4608*128 ushorts / 2
static constexpr size_t SZ_WT2 = 36864;      // conv2 wb
static constexpr size_t SZ_Y   = 2097152;    // 4*128*4096 fp32
static constexpr size_t SZ_QK  = 262144;     // 4*4096*32 ushorts / 2

static constexpr size_t OFF_WB2P = 0;
static constexpr size_t OFF_B1P  = OFF_WB2P + SZ_WB2;
static constexpr size_t OFF_WB2C = OFF_B1P + 128;
static constexpr size_t OFF_B1C  = OFF_WB2C + SZ_WB2;
static constexpr size_t OFF_WT2P = OFF_B1C + 128;
static constexpr size_t OFF_B2P  = OFF_WT2P + SZ_WT2;
static constexpr size_t OFF_WT2C = OFF_B2P + 32;
static constexpr size_t OFF_B2C  = OFF_WT2C + SZ_WT2;
static constexpr size_t OFF_YP   = OFF_B2C + 32;
static constexpr size_t OFF_YC   = OFF_YP + SZ_Y;
static constexpr size_t OFF_Q    = OFF_YC + SZ_Y;      // Qb bf16 [4][4096][32] (pre-scaled by log2e)
static constexpr size_t OFF_K    = OFF_Q + SZ_QK;      // Kb bf16 [4][4096][32]
static constexpr size_t OFF_V    = OFF_K + SZ_QK;      // VF bf16 frag stream, 4MB
static constexpr size_t OFF_PB   = OFF_V + SZ_Y;       // Pb bf16 [4][4096][128]
static constexpr size_t OFF_CB   = OFF_PB + 1048576;   // Cb bf16 [4][4096][128]
static constexpr size_t OFF_GP   = OFF_PB + 2097152;   // Gram partials [4][16][128][128] f32
static constexpr size_t OFF_G    = OFF_PB + 4194304;   // G [4][128][128] f32
static constexpr size_t OFF_Z    = OFF_G + 65536;      // 16KB zero scratch
// xT (bf16, 16MB) ALIASES [OFF_PB, OFF_G): dead after conv1.

__device__ __forceinline__ unsigned short f2bf(float f) {
    unsigned u = __float_as_uint(f);
    unsigned r = (u + 0x7fffu + ((u >> 16) & 1u)) >> 16;
    return (unsigned short)r;
}

__device__ __forceinline__ void gload_lds16(const void* g, void* l) {
    __builtin_amdgcn_global_load_lds((const __attribute__((address_space(1))) void*)g,
                                     (__attribute__((address_space(3))) void*)l, 16, 0, 0);
}

// ---------------- x (fp32 NCHW) -> xT (bf16 [b][h][w][c]) ----------------
__global__ __launch_bounds__(256) void x_transpose(const float* __restrict__ x,
                                                   unsigned short* __restrict__ xT)
{
    const int h = blockIdx.x, b = blockIdx.y, cb0 = blockIdx.z * 128;
    __shared__ float tile[64][129];
    const int t = threadIdx.x;
    for (int i = t; i < 8192; i += 256) {
        int c = i >> 6, w = i & 63;
        tile[w][c] = x[(((size_t)(b * 512 + cb0 + c) * 64) + h) * 64 + w];
    }
    __syncthreads();
    for (int i = t; i < 8192; i += 256) {
        int w = i >> 7, c = i & 127;
        xT[(((size_t)(b * 64 + h) * 64) + w) * 512 + cb0 + c] = f2bf(tile[w][c]);
    }
}

// ---------------- fold BN into conv weights, bf16, staged layout (generic) ------
__global__ void prep_conv_mfma(const float* __restrict__ w, const float* __restrict__ g,
                               const float* __restrict__ bb, const float* __restrict__ m,
                               const float* __restrict__ v, unsigned short* __restrict__ wb2,
                               float* __restrict__ bias, int cin, int cout)
{
    int idx = blockIdx.x * 256 + threadIdx.x;
    if (idx < cout) {
        float sc = g[idx] * rsqrtf(v[idx] + EPSBN);
        bias[idx] = bb[idx] - m[idx] * sc;
    }
    const int cin9 = cin * 9;
    if (idx >= cout * cin9) return;
    int oc = idx / cin9;
    int rem = idx - oc * cin9;
    int c = rem / 9;
    int tap = rem - c * 9;
    int kh = tap / 3, kw = tap - kh * 3;
    float sc = g[oc] * rsqrtf(v[oc] + EPSBN);
    float val = w[idx] * sc;
    int u = (oc << 2) + (((c >> 3) & 3) ^ ((oc >> 1) & 3));
    int ncb = cin >> 5;
    size_t dst = (((size_t)(kh * ncb + (c >> 5)) * 3 + kw) * ((size_t)cout << 2) + u) * 8 + (c & 7);
    wb2[dst] = f2bf(val);
}

// ---------------- conv1 (512->128, 3x3) via bf16 MFMA implicit GEMM ----------------
__global__ __launch_bounds__(256) void conv1_mfma(
    const unsigned short* __restrict__ xT,
    const unsigned short* __restrict__ wb2p, const unsigned short* __restrict__ wb2c,
    const float* __restrict__ b1p, const float* __restrict__ b1c,
    float* __restrict__ yp, float* __restrict__ yc,
    const unsigned short* __restrict__ zbuf)
{
    const int b = blockIdx.x >> 5;
    const int h0 = (blockIdx.x & 31) * 2;
    const bool isC = (blockIdx.y >> 1) != 0;
    const int ohalf = blockIdx.y & 1;
    const int obase = ohalf << 6;
    const unsigned short* __restrict__ wb2 = isC ? wb2c : wb2p;
    const float* __restrict__ bias = isC ? b1c : b1p;
    float* __restrict__ y = isC ? yc : yp;

    const int t = threadIdx.x;
    const int wid = t >> 6, lane = t & 63;
    const int lhi = lane >> 4, llo = lane & 15;

    __shared__ __align__(16) unsigned short lds_x[8192];
    __shared__ __align__(16) unsigned short lds_w[6144];

    f32x4 acc[4][2];
#pragma unroll
    for (int i = 0; i < 4; ++i)
#pragma unroll
        for (int j = 0; j < 2; ++j) acc[i][j] = (f32x4)0.0f;

    for (int cc = 0; cc < 16; ++cc) {
        const int cb = cc * 32;
        __syncthreads();
        for (int i = wid; i < 16; i += 4) {
            const int u = (i << 6) + lane;
            const int row = u >> 8;
            const int col = (u >> 2) & 63;
            const int g2 = (u & 3) ^ ((col >> 1) & 3);
            const int xrow = h0 - 1 + row;
            const unsigned short* src = ((unsigned)xrow < 64u)
                ? xT + (((size_t)((b << 6) + xrow) << 6) + col) * 512 + cb + (g2 << 3)
                : zbuf;
            gload_lds16(src, &lds_x[(size_t)i << 9]);
        }
        {
            const unsigned short* ws = wb2 + ((size_t)(cc * 3) * 512 + (ohalf << 8)) * 8;
            for (int i = wid; i < 12; i += 4) {
                const int kw = i >> 2, seg = i & 3;
                gload_lds16(ws + ((size_t)(kw * 512 + (seg << 6) + lane) << 3),
                            &lds_w[(size_t)i << 9]);
            }
        }
        for (int kh = 0; kh < 3; ++kh) {
            if (kh) {
                __syncthreads();
                const unsigned short* ws = wb2 + ((size_t)((kh * 16 + cc) * 3) * 512 + (ohalf << 8)) * 8;
                for (int i = wid; i < 12; i += 4) {
                    const int kw = i >> 2, seg = i & 3;
                    gload_lds16(ws + ((size_t)(kw * 512 + (seg << 6) + lane) << 3),
                                &lds_w[(size_t)i << 9]);
                }
            }
            __syncthreads();
#pragma unroll
            for (int kw = 0; kw < 3; ++kw) {
                bf16x8 afr[4];
#pragma unroll
                for (int mf = 0; mf < 4; ++mf) {
                    const int ocl = (mf << 4) + llo;
                    const int un = (kw << 8) + (ocl << 2) + (lhi ^ ((ocl >> 1) & 3));
                    afr[mf] = *(const bf16x8*)&lds_w[un << 3];
                }
                bf16x8 bfr[2];
#pragma unroll
                for (int nf = 0; nf < 2; ++nf) {
                    const int px = (wid << 5) + (nf << 4) + llo;
                    const int orow = px >> 6;
                    const int wc = (px & 63) + kw - 1;
                    const bool inb = (unsigned)wc < 64u;
                    const int wcc = inb ? wc : 0;
                    const int un = (((orow + kh) << 6) + wcc) * 4 + (lhi ^ ((wcc >> 1) & 3));
                    short8v raw = *(const short8v*)&lds_x[un << 3];
                    short8v zz = {};
                    if (!inb) raw = zz;
                    bfr[nf] = __builtin_bit_cast(bf16x8, raw);
                }
#pragma unroll
                for (int mf = 0; mf < 4; ++mf)
#pragma unroll
                    for (int nf = 0; nf < 2; ++nf)
                        acc[mf][nf] = __builtin_amdgcn_mfma_f32_16x16x32_bf16(
                            afr[mf], bfr[nf], acc[mf][nf], 0, 0, 0);
            }
        }
    }

#pragma unroll
    for (int mf = 0; mf < 4; ++mf) {
#pragma unroll
        for (int r = 0; r < 4; ++r) {
            const int oc = obase + (mf << 4) + (lhi << 2) + r;
            const float bv = bias[oc];
#pragma unroll
            for (int nf = 0; nf < 2; ++nf) {
                const int px = (wid << 5) + (nf << 4) + llo;
                const int hout = h0 + (px >> 6);
                const int colw = px & 63;
                float* dst = y + (((size_t)(b * 128 + oc) << 6) + hout) * 64;
                dst[colw] = fmaxf(acc[mf][nf][r] + bv, 0.f);
            }
        }
    }
}

// ---------------- conv2 pair (128->32 x2, 3x3) fused MFMA ----------------
__global__ __launch_bounds__(256) void conv2_mfma(
    const unsigned short* __restrict__ Pb, const unsigned short* __restrict__ Cb,
    const unsigned short* __restrict__ wbp, const unsigned short* __restrict__ wbc,
    const float* __restrict__ b2p, const float* __restrict__ b2c,
    float* __restrict__ out, const unsigned short* __restrict__ zbuf)
{
    const int b = blockIdx.x >> 5;
    const int h0 = (blockIdx.x & 31) * 2;
    const int t = threadIdx.x;
    const int wid = t >> 6, lane = t & 63;
    const int lhi = lane >> 4, llo = lane & 15;

    __shared__ __align__(16) unsigned short xP[8192];
    __shared__ __align__(16) unsigned short xC[8192];
    __shared__ __align__(16) unsigned short wbuf[2][3072];

    f32x4 accP[2][2], accC[2][2];
#pragma unroll
    for (int i = 0; i < 2; ++i)
#pragma unroll
        for (int j = 0; j < 2; ++j) { accP[i][j] = (f32x4)0.0f; accC[i][j] = (f32x4)0.0f; }

    for (int cc = 0; cc < 4; ++cc) {
        const int cb = cc * 32;
        __syncthreads();
        for (int i = wid; i < 16; i += 4) {
            const int u = (i << 6) + lane;
            const int row = u >> 8;
            const int col = (u >> 2) & 63;
            const int g2 = (u & 3) ^ ((col >> 1) & 3);
            const int xrow = h0 - 1 + row;
            const bool inb = (unsigned)xrow < 64u;
            const size_t off = ((((size_t)((b << 6) + (inb ? xrow : 0)) << 6) + col) << 7) + cb + (g2 << 3);
            gload_lds16(inb ? (Pb + off) : zbuf, &xP[(size_t)i << 9]);
            gload_lds16(inb ? (Cb + off) : zbuf, &xC[(size_t)i << 9]);
        }
        {
            const size_t wb0 = (size_t)(cc * 3) * 1024;
            for (int i = wid; i < 12; i += 4) {
                const int cv = (i >= 6);
                const int ii = i - cv * 6;
                const unsigned short* ws = (cv ? wbc : wbp) + wb0;
                gload_lds16(ws + ((ii << 9) + (lane << 3)), &wbuf[cv][(size_t)ii << 9]);
            }
        }
        for (int kh = 0; kh < 3; ++kh) {
            if (kh) {
                __syncthreads();
                const size_t wb0 = (size_t)((kh * 4 + cc) * 3) * 1024;
                for (int i = wid; i < 12; i += 4) {
                    const int cv = (i >= 6);
                    const int ii = i - cv * 6;
                    const unsigned short* ws = (cv ? wbc : wbp) + wb0;
                    gload_lds16(ws + ((ii << 9) + (lane << 3)), &wbuf[cv][(size_t)ii << 9]);
                }
            }
            __syncthreads();
#pragma unroll
            for (int kw = 0; kw < 3; ++kw) {
                bf16x8 afrP[2], afrC[2];
#pragma unroll
                for (int mf = 0; mf < 2; ++mf) {
                    const int ocl = (mf << 4) + llo;
                    const int un = (kw << 7) + (ocl << 2) + (lhi ^ ((ocl >> 1) & 3));
                    afrP[mf] = *(const bf16x8*)&wbuf[0][un << 3];
                    afrC[mf] = *(const bf16x8*)&wbuf[1][un << 3];
                }
                bf16x8 bfrP[2], bfrC[2];
#pragma unroll
                for (int nf = 0; nf < 2; ++nf) {
                    const int px = (wid << 5) + (nf << 4) + llo;
                    const int orow = px >> 6;
                    const int wc = (px & 63) + kw - 1;
                    const bool inb = (unsigned)wc < 64u;
                    const int wcc = inb ? wc : 0;
                    const int un = (((orow + kh) << 6) + wcc) * 4 + (lhi ^ ((wcc >> 1) & 3));
                    short8v rawP = *(const short8v*)&xP[un << 3];
                    short8v rawC = *(const short8v*)&xC[un << 3];
                    short8v zz = {};
                    if (!inb) { rawP = zz; rawC = zz; }
                    bfrP[nf] = __builtin_bit_cast(bf16x8, rawP);
                    bfrC[nf] = __builtin_bit_cast(bf16x8, rawC);
                }
#pragma unroll
                for (int mf = 0; mf < 2; ++mf)
#pragma unroll
                    for (int nf = 0; nf < 2; ++nf) {
                        accP[mf][nf] = __builtin_amdgcn_mfma_f32_16x16x32_bf16(
                            afrP[mf], bfrP[nf], accP[mf][nf], 0, 0, 0);
                        accC[mf][nf] = __builtin_amdgcn_mfma_f32_16x16x32_bf16(
                            afrC[mf], bfrC[nf], accC[mf][nf], 0, 0, 0);
                    }
            }
        }
    }

#pragma unroll
    for (int mf = 0; mf < 2; ++mf) {
#pragma unroll
        for (int r = 0; r < 4; ++r) {
            const int oc = (mf << 4) + (lhi << 2) + r;
            const float bp = b2p[oc], bc = b2c[oc];
#pragma unroll
            for (int nf = 0; nf < 2; ++nf) {
                const int px = (wid << 5) + (nf << 4) + llo;
                const int hout = h0 + (px >> 6);
                const int colw = px & 63;
                const float val = fmaxf(accP[mf][nf][r] + bp, 0.f)
                                + fmaxf(accC[mf][nf][r] + bc, 0.f);
                out[(((size_t)(b * 32 + oc)) << 12) + (hout << 6) + colw] = val;
            }
        }
    }
}

// ---------------- PAM projections: q(scaled by log2e),k -> bf16 [n][32]; d -> VF ----
__global__ __launch_bounds__(256) void pam_proj(
    const float* __restrict__ yp,
    const float* __restrict__ wb, const float* __restrict__ bbq,
    const float* __restrict__ wc, const float* __restrict__ bck,
    const float* __restrict__ wd, const float* __restrict__ bdv,
    unsigned short* __restrict__ Qb, unsigned short* __restrict__ Kb,
    unsigned short* __restrict__ VFo)
{
    const int b = blockIdx.y;
    const int n0 = blockIdx.x * 64;
    const int t = threadIdx.x;
    const int px = t & 63;
    const int og = t >> 6;

    __shared__ __align__(16) float lds_y[64][64];
    __shared__ __align__(16) float lds_w[64][164];

    float acc[10][4];
#pragma unroll
    for (int s = 0; s < 10; ++s) { acc[s][0] = acc[s][1] = acc[s][2] = acc[s][3] = 0.f; }

    for (int cb = 0; cb < 128; cb += 64) {
        for (int i = t; i < 4096; i += 256) {
            int c = i >> 6, p = i & 63;
            lds_y[c][p] = yp[(((size_t)b * 128 + cb + c) << 12) + n0 + p];
        }
        for (int i = t; i < 160 * 64; i += 256) {
            int c = i & 63, o = i >> 6;
            const float* src = (o < 16) ? (wb + o * 128)
                             : (o < 32) ? (wc + (o - 16) * 128)
                                        : (wd + (o - 32) * 128);
            lds_w[c][o] = src[cb + c];
        }
        __syncthreads();
        for (int c = 0; c < 64; ++c) {
            float yv = lds_y[c][px];
#pragma unroll
            for (int s = 0; s < 10; ++s) {
                const float4 w4 = *(const float4*)&lds_w[c][s * 16 + og * 4];
                acc[s][0] += w4.x * yv; acc[s][1] += w4.y * yv;
                acc[s][2] += w4.z * yv; acc[s][3] += w4.w * yv;
            }
        }
        __syncthreads();
    }
    const int n = n0 + px;
    const size_t qkrow = ((size_t)(b << 12) + n) << 5;
#pragma unroll
    for (int s = 0; s < 10; ++s) {
        const float* bsrc = (s == 0) ? (bbq + og * 4)
                          : (s == 1) ? (bck + og * 4)
                                     : (bdv + (s - 2) * 16 + og * 4);
        const float4 bv4 = *(const float4*)bsrc;
        float v0 = acc[s][0] + bv4.x, v1 = acc[s][1] + bv4.y;
        float v2 = acc[s][2] + bv4.z, v3 = acc[s][3] + bv4.w;
        if (s == 0) { v0 *= LOG2E; v1 *= LOG2E; v2 *= LOG2E; v3 *= LOG2E; }
        if (s < 2) {
            unsigned short* dst = (s == 0) ? Qb : Kb;
            uint2 pk2;
            pk2.x = (unsigned)f2bf(v0) | ((unsigned)f2bf(v1) << 16);
            pk2.y = (unsigned)f2bf(v2) | ((unsigned)f2bf(v3) << 16);
            *(uint2*)&dst[qkrow + (og << 2)] = pk2;
            uint2 z2; z2.x = 0u; z2.y = 0u;
            *(uint2*)&dst[qkrow + 16 + (og << 2)] = z2;
        } else {
            const int cf = s - 2;
            const size_t blk = ((size_t)(b * 128 + (n >> 5)) * 8 + cf) << 9;
            const int gl = ((n >> 2) & 3) << 4;
            const int j = (n & 3) | (((n >> 4) & 1) << 2);
            const float vv[4] = {v0, v1, v2, v3};
#pragma unroll
            for (int u = 0; u < 4; ++u)
                VFo[blk + ((size_t)((gl | (og * 4 + u)) << 3)) + j] = f2bf(vv[u]);
        }
    }
}

// ---------------- PAM fused attention: unroll-2, MFMA lsum, exp2, XCD swizzle ----
// flat grid 512, 512 thr = 8 waves: qg = wid&1 (16 queries), kq = wid>>1 (quarter).
__global__ __launch_bounds__(512, 4) void pam_attn_mfma(
    const unsigned short* __restrict__ Qb, const unsigned short* __restrict__ Kb,
    const unsigned short* __restrict__ VF, const float* __restrict__ yp,
    const float* __restrict__ alpha_p, unsigned short* __restrict__ Pb)
{
    const int bid = blockIdx.x;
    const int xcd = bid & 7;
    const int b = xcd >> 1;                              // one batch per XCD pair
    const int q0 = ((((xcd & 1) << 6) | (bid >> 3))) << 5;
    const int t = threadIdx.x;
    const int wid = t >> 6, lane = t & 63;
    const int qg = wid & 1, kq = wid >> 1;
    const int g = lane >> 4, qi = lane & 15;
    const int qw0 = q0 + qg * 16;

    __shared__ float combO[2][3][64][33];
    __shared__ float combL[2][4][16];
    __shared__ float combM[2][4][16];
    unsigned short* smP = (unsigned short*)combO;

    const bf16x8 qf = *(const bf16x8*)&Qb[(((size_t)(b << 12) + qw0 + qi) << 5) + (g << 3)];
    const unsigned short* __restrict__ Kbase = Kb + ((size_t)b << 17);
    const unsigned short* __restrict__ VFb = VF + ((size_t)b << 19);

    bf16x8 ones;
#pragma unroll
    for (int j = 0; j < 8; ++j) ones[j] = (__bf16)1.0f;

    f32x4 accO[8];
#pragma unroll
    for (int cf = 0; cf < 8; ++cf) accO[cf] = (f32x4)0.0f;
    f32x4 accL = (f32x4)0.0f;
    float m = -3.0e38f;

    const int ktbase = kq << 5;
    #define KF(kt, half) (*(const bf16x8*)&Kbase[((size_t)((((kt) << 5) + (half)) + qi) << 5) + (g << 3)])
    bf16x8 kE0 = KF(ktbase, 0), kO0 = KF(ktbase, 16);
    bf16x8 kE1 = KF(ktbase + 1, 0), kO1 = KF(ktbase + 1, 16);

    for (int g2 = 0; g2 < 16; ++g2) {
        const int kt0 = ktbase + (g2 << 1);
        const unsigned short* vt0 = VFb + ((size_t)kt0 << 12) + (lane << 3);
        const unsigned short* vt1 = vt0 + 4096;
        // VF kt0 loads issued early (independent of scores)
        bf16x8 va0 = *(const bf16x8*)&vt0[0],    va1 = *(const bf16x8*)&vt0[512];
        bf16x8 va2 = *(const bf16x8*)&vt0[1024], va3 = *(const bf16x8*)&vt0[1536];
        bf16x8 va4 = *(const bf16x8*)&vt0[2048], va5 = *(const bf16x8*)&vt0[2560];
        bf16x8 va6 = *(const bf16x8*)&vt0[3072], va7 = *(const bf16x8*)&vt0[3584];
        f32x4 z = {};
        f32x4 sE0 = __builtin_amdgcn_mfma_f32_16x16x32_bf16(kE0, qf, z, 0, 0, 0);
        f32x4 sO0 = __builtin_amdgcn_mfma_f32_16x16x32_bf16(kO0, qf, z, 0, 0, 0);
        f32x4 sE1 = __builtin_amdgcn_mfma_f32_16x16x32_bf16(kE1, qf, z, 0, 0, 0);
        f32x4 sO1 = __builtin_amdgcn_mfma_f32_16x16x32_bf16(kO1, qf, z, 0, 0, 0);
        // prefetch next group's K
        const int ktn = (g2 < 15) ? kt0 + 2 : kt0;
        bf16x8 nkE0 = KF(ktn, 0), nkO0 = KF(ktn, 16);
        bf16x8 nkE1 = KF(ktn + 1, 0), nkO1 = KF(ktn + 1, 16);
        // one max-check per 64 keys
        float pm = fmaxf(fmaxf(fmaxf(sE0[0], sE0[1]), fmaxf(sE0[2], sE0[3])),
                         fmaxf(fmaxf(sO0[0], sO0[1]), fmaxf(sO0[2], sO0[3])));
        pm = fmaxf(pm, fmaxf(fmaxf(fmaxf(sE1[0], sE1[1]), fmaxf(sE1[2], sE1[3])),
                             fmaxf(fmaxf(sO1[0], sO1[1]), fmaxf(sO1[2], sO1[3]))));
        pm = fmaxf(pm, __shfl_xor(pm, 16));
        pm = fmaxf(pm, __shfl_xor(pm, 32));
        if (!__all(pm <= m + 8.f)) {                    // defer-max (log2 units)
            const float nm = fmaxf(m, pm);
            const float fac = exp2f(m - nm);
#pragma unroll
            for (int cf = 0; cf < 8; ++cf) accO[cf] *= fac;
            accL *= fac;
            m = nm;
        }
        bf16x8 pb0, pb1;
#pragma unroll
        for (int r = 0; r < 4; ++r) {
            pb0[r]     = (__bf16)exp2f(sE0[r] - m);
            pb0[4 + r] = (__bf16)exp2f(sO0[r] - m);
            pb1[r]     = (__bf16)exp2f(sE1[r] - m);
            pb1[4 + r] = (__bf16)exp2f(sO1[r] - m);
        }
        // PV kt0
        accO[0] = __builtin_amdgcn_mfma_f32_16x16x32_bf16(va0, pb0, accO[0], 0, 0, 0);
        accO[1] = __builtin_amdgcn_mfma_f32_16x16x32_bf16(va1, pb0, accO[1], 0, 0, 0);
        accO[2] = __builtin_amdgcn_mfma_f32_16x16x32_bf16(va2, pb0, accO[2], 0, 0, 0);
        accO[3] = __builtin_amdgcn_mfma_f32_16x16x32_bf16(va3, pb0, accO[3], 0, 0, 0);
        // VF kt1 loads
        bf16x8 vb0 = *(const bf16x8*)&vt1[0],    vb1 = *(const bf16x8*)&vt1[512];
        bf16x8 vb2 = *(const bf16x8*)&vt1[1024], vb3 = *(const bf16x8*)&vt1[1536];
        bf16x8 vb4 = *(const bf16x8*)&vt1[2048], vb5 = *(const bf16x8*)&vt1[2560];
        bf16x8 vb6 = *(const bf16x8*)&vt1[3072], vb7 = *(const bf16x8*)&vt1[3584];
        accO[4] = __builtin_amdgcn_mfma_f32_16x16x32_bf16(va4, pb0, accO[4], 0, 0, 0);
        accO[5] = __builtin_amdgcn_mfma_f32_16x16x32_bf16(va5, pb0, accO[5], 0, 0, 0);
        accO[6] = __builtin_amdgcn_mfma_f32_16x16x32_bf16(va6, pb0, accO[6], 0, 0, 0);
        accO[7] = __builtin_amdgcn_mfma_f32_16x16x32_bf16(va7, pb0, accO[7], 0, 0, 0);
        accL    = __builtin_amdgcn_mfma_f32_16x16x32_bf16(ones, pb0, accL, 0, 0, 0);
        // PV kt1
        accO[0] = __builtin_amdgcn_mfma_f32_16x16x32_bf16(vb0, pb1, accO[0], 0, 0, 0);
        accO[1] = __builtin_amdgcn_mfma_f32_16x16x32_bf16(vb1, pb1, accO[1], 0, 0, 0);
        accO[2] = __builtin_amdgcn_mfma_f32_16x16x32_bf16(vb2, pb1, accO[2], 0, 0, 0);
        accO[3] = __builtin_amdgcn_mfma_f32_16x16x32_bf16(vb3, pb1, accO[3], 0, 0, 0);
        accO[4] = __builtin_amdgcn_mfma_f32_16x16x32_bf16(vb4, pb1, accO[4], 0, 0, 0);
        accO[5] = __builtin_amdgcn_mfma_f32_16x16x32_bf16(vb5, pb1, accO[5], 0, 0, 0);
        accO[6] = __builtin_amdgcn_mfma_f32_16x16x32_bf16(vb6, pb1, accO[6], 0, 0, 0);
        accO[7] = __builtin_amdgcn_mfma_f32_16x16x32_bf16(vb7, pb1, accO[7], 0, 0, 0);
        accL    = __builtin_amdgcn_mfma_f32_16x16x32_bf16(ones, pb1, accL, 0, 0, 0);
        kE0 = nkE0; kO0 = nkO0; kE1 = nkE1; kO1 = nkO1;
    }
    #undef KF
    const float lsum = accL[0];     // every lane: full per-query sum over its quarter

    if (lane < 16) { combM[qg][kq][lane] = m; combL[qg][kq][lane] = lsum; }
    __syncthreads();

    const float M = fmaxf(fmaxf(combM[qg][0][qi], combM[qg][1][qi]),
                          fmaxf(combM[qg][2][qi], combM[qg][3][qi]));
    const float fac = exp2f(m - M);
#pragma unroll
    for (int cf = 0; cf < 8; ++cf) accO[cf] *= fac;

    if (kq > 0) {
#pragma unroll
        for (int cf = 0; cf < 8; ++cf)
#pragma unroll
            for (int r = 0; r < 4; ++r)
                combO[qg][kq - 1][lane][cf * 4 + r] = accO[cf][r];
    }
    __syncthreads();
    float sc = 0.f;
    if (kq == 0) {
#pragma unroll
        for (int k2 = 0; k2 < 3; ++k2)
#pragma unroll
            for (int cf = 0; cf < 8; ++cf)
#pragma unroll
                for (int r = 0; r < 4; ++r)
                    accO[cf][r] += combO[qg][k2][lane][cf * 4 + r];
        float l = 0.f;
#pragma unroll
        for (int k2 = 0; k2 < 4; ++k2)
            l += exp2f(combM[qg][k2][qi] - M) * combL[qg][k2][qi];
        sc = alpha_p[0] / l;
    }
    __syncthreads();              // all combO reads done; safe to reuse as smP
    if (kq == 0) {
#pragma unroll
        for (int cf = 0; cf < 8; ++cf) {
#pragma unroll
            for (int r = 0; r < 4; ++r) {
                const int ch = cf * 16 + (g << 2) + r;
                const size_t o = (((size_t)(b * 128 + ch)) << 12) + qw0 + qi;
                const float val = accO[cf][r] * sc + yp[o];
                smP[(qg * 16 + qi) * 128 + ch] = f2bf(val);
            }
        }
    }
    __syncthreads();
    unsigned* Pb32 = (unsigned*)Pb;
    const unsigned* sm32 = (const unsigned*)smP;
    for (int i = t; i < 2048; i += 512) {
        const int row = i >> 6, u = i & 63;
        Pb32[((size_t)(b << 12) + q0 + row) * 64 + u] = sm32[i];
    }
}

// ---------------- CAM Gram via MFMA, bf16 hi/lo split (fp32-accurate) ----------
__global__ __launch_bounds__(256) void cam_gram_mfma(const float* __restrict__ yc,
                                                     float* __restrict__ GP)
{
    const int kb = blockIdx.x, b = blockIdx.y;
    const int t = threadIdx.x;
    const int wid = t >> 6, lane = t & 63;
    const int lhi = lane >> 4, llo = lane & 15;
    const int mr = (wid & 1) << 6, nr = (wid >> 1) << 6;
    const float* __restrict__ Y = yc + ((size_t)b << 19);

    f32x4 acc[4][4];
#pragma unroll
    for (int i = 0; i < 4; ++i)
#pragma unroll
        for (int j = 0; j < 4; ++j) acc[i][j] = (f32x4)0.0f;

    for (int ks = 0; ks < 8; ++ks) {
        const int n0 = (kb << 8) + (ks << 5) + (lhi << 3);
        bf16x8 ah[4], al[4], bh[4], bl[4];
#pragma unroll
        for (int mf = 0; mf < 4; ++mf) {
            const int row = mr + (mf << 4) + llo;
            const float* p = &Y[((size_t)row << 12) + n0];
            const float4 v0 = *(const float4*)p;
            const float4 v1 = *(const float4*)(p + 4);
            const float vv[8] = {v0.x, v0.y, v0.z, v0.w, v1.x, v1.y, v1.z, v1.w};
#pragma unroll
            for (int j = 0; j < 8; ++j) {
                const __bf16 h = (__bf16)vv[j];
                ah[mf][j] = h;
                al[mf][j] = (__bf16)(vv[j] - (float)h);
            }
        }
#pragma unroll
        for (int nf = 0; nf < 4; ++nf) {
            const int row = nr + (nf << 4) + llo;
            const float* p = &Y[((size_t)row << 12) + n0];
            const float4 v0 = *(const float4*)p;
            const float4 v1 = *(const float4*)(p + 4);
            const float vv[8] = {v0.x, v0.y, v0.z, v0.w, v1.x, v1.y, v1.z, v1.w};
#pragma unroll
            for (int j = 0; j < 8; ++j) {
                const __bf16 h = (__bf16)vv[j];
                bh[nf][j] = h;
                bl[nf][j] = (__bf16)(vv[j] - (float)h);
            }
        }
#pragma unroll
        for (int mf = 0; mf < 4; ++mf)
#pragma unroll
            for (int nf = 0; nf < 4; ++nf) {
                acc[mf][nf] = __builtin_amdgcn_mfma_f32_16x16x32_bf16(ah[mf], bh[nf], acc[mf][nf], 0, 0, 0);
                acc[mf][nf] = __builtin_amdgcn_mfma_f32_16x16x32_bf16(ah[mf], bl[nf], acc[mf][nf], 0, 0, 0);
                acc[mf][nf] = __builtin_amdgcn_mfma_f32_16x16x32_bf16(al[mf], bh[nf], acc[mf][nf], 0, 0, 0);
            }
    }
    const size_t base = ((size_t)((b << 4) + kb) << 14);
#pragma unroll
    for (int mf = 0; mf < 4; ++mf)
#pragma unroll
        for (int nf = 0; nf < 4; ++nf)
#pragma unroll
            for (int r = 0; r < 4; ++r) {
                const int c = mr + (mf << 4) + (lhi << 2) + r;
                const int d = nr + (nf << 4) + llo;
                GP[base + ((size_t)c << 7) + d] = acc[mf][nf][r];
            }
}

__global__ __launch_bounds__(256) void cam_gram_reduce(const float* __restrict__ GP,
                                                       float* __restrict__ G)
{
    const int b = blockIdx.y;
    const int i0 = blockIdx.x * 1024 + threadIdx.x * 4;
    float4 s = make_float4(0.f, 0.f, 0.f, 0.f);
#pragma unroll
    for (int kb = 0; kb < 16; ++kb) {
        const float4 v = *(const float4*)&GP[((size_t)((b << 4) + kb) << 14) + i0];
        s.x += v.x; s.y += v.y; s.z += v.z; s.w += v.w;
    }
    *(float4*)&G[((size_t)b << 14) + i0] = s;
}

// ---------------- CAM: softmax + apply + beta residual -> Cb bf16 [b][n][128] ----
// grid (64,4): cchunk = x>>4 (32 channels), ns = x&15 (256 positions).
__global__ __launch_bounds__(256) void cam_apply(
    const float* __restrict__ G, const float* __restrict__ yc,
    const float* __restrict__ beta_p, unsigned short* __restrict__ Cb)
{
    const int b = blockIdx.y;
    const int cchunk = blockIdx.x >> 4;
    const int ns = blockIdx.x & 15;
    const int t = threadIdx.x;

    __shared__ float att_t[128][32];
    __shared__ float s_buf[128 * 64];
    __shared__ unsigned short smC[64 * 32];

    for (int i = t; i < 4096; i += 256)
        s_buf[i] = G[((size_t)b << 14) + (size_t)cchunk * 32 * 128 + i];
    __syncthreads();
    {
        const int r = t >> 3, seg = t & 7;
        float vals[16];
        float gmin = 3.0e38f;
#pragma unroll
        for (int u = 0; u < 16; ++u) {
            vals[u] = s_buf[r * 128 + seg * 16 + u];
            gmin = fminf(gmin, vals[u]);
        }
        gmin = fminf(gmin, __shfl_xor(gmin, 1));
        gmin = fminf(gmin, __shfl_xor(gmin, 2));
        gmin = fminf(gmin, __shfl_xor(gmin, 4));
        float sum = 0.f;
#pragma unroll
        for (int u = 0; u < 16; ++u) { vals[u] = __expf(gmin - vals[u]); sum += vals[u]; }
        sum += __shfl_xor(sum, 1);
        sum += __shfl_xor(sum, 2);
        sum += __shfl_xor(sum, 4);
        const float inv = 1.f / sum;
#pragma unroll
        for (int u = 0; u < 16; ++u)
            att_t[seg * 16 + u][r] = vals[u] * inv;
    }
    __syncthreads();

    const float be = beta_p[0];
    const int nc = t & 31, cgp = t >> 5;
    unsigned* Cb32 = (unsigned*)Cb;
    const unsigned* smC32 = (const unsigned*)smC;
    for (int chunk = 0; chunk < 4; ++chunk) {
        const int nb = ns * 256 + chunk * 64;
        for (int i = t; i < 8192; i += 256) {
            int d = i >> 6, nn = i & 63;
            s_buf[d * 64 + nn] = yc[(((size_t)b * 128 + d) << 12) + nb + nn];
        }
        __syncthreads();
        float a0[4] = {0, 0, 0, 0}, a1[4] = {0, 0, 0, 0};
        for (int d = 0; d < 128; ++d) {
            const float y0 = s_buf[d * 64 + nc];
            const float y1 = s_buf[d * 64 + nc + 32];
#pragma unroll
            for (int o = 0; o < 4; ++o) {
                const float wv = att_t[d][cgp * 4 + o];
                a0[o] += wv * y0; a1[o] += wv * y1;
            }
        }
#pragma unroll
        for (int o = 0; o < 4; ++o) {
            const int cl = cgp * 4 + o;
            const int c = cchunk * 32 + cl;
            smC[nc * 32 + cl]        = f2bf(be * a0[o] + s_buf[c * 64 + nc]);
            smC[(nc + 32) * 32 + cl] = f2bf(be * a1[o] + s_buf[c * 64 + nc + 32]);
        }
        __syncthreads();
        for (int i = t; i < 1024; i += 256) {
            const int row = i >> 4, u = i & 15;
            Cb32[((size_t)(b << 12) + nb + row) * 64 + (cchunk << 4) + u] = smC32[i];
        }
        __syncthreads();
    }
}

// ---------------- launcher ----------------
extern "C" void kernel_launch(void* const* d_in, const int* in_sizes, int n_in,
                              void* d_out, int out_size, void* d_ws, size_t ws_size,
                              hipStream_t stream)
{
    (void)in_sizes; (void)n_in; (void)out_size; (void)ws_size;
    const float* x    = (const float*)d_in[0];
    const float* wp1  = (const float*)d_in[1];
    const float* gp1  = (const float*)d_in[2];
    const float* bp1  = (const float*)d_in[3];
    const float* mp1  = (const float*)d_in[4];
    const float* vp1  = (const float*)d_in[5];
    const float* wc1  = (const float*)d_in[6];
    const float* gc1  = (const float*)d_in[7];
    const float* bc1  = (const float*)d_in[8];
    const float* mc1  = (const float*)d_in[9];
    const float* vc1  = (const float*)d_in[10];
    const float* pwb  = (const float*)d_in[11];
    const float* pbb  = (const float*)d_in[12];
    const float* pwc  = (const float*)d_in[13];
    const float* pbc  = (const float*)d_in[14];
    const float* pwd  = (const float*)d_in[15];
    const float* pbd  = (const float*)d_in[16];
    const float* alpha= (const float*)d_in[17];
    const float* beta = (const float*)d_in[18];
    const float* wp2  = (const float*)d_in[19];
    const float* gp2  = (const float*)d_in[20];
    const float* bp2  = (const float*)d_in[21];
    const float* mp2  = (const float*)d_in[22];
    const float* vp2  = (const float*)d_in[23];
    const float* wc2  = (const float*)d_in[24];
    const float* gc2  = (const float*)d_in[25];
    const float* bc2  = (const float*)d_in[26];
    const float* mc2  = (const float*)d_in[27];
    const float* vc2  = (const float*)d_in[28];

    float* W = (float*)d_ws;
    unsigned short* wb2p16 = (unsigned short*)(W + OFF_WB2P);
    unsigned short* wb2c16 = (unsigned short*)(W + OFF_WB2C);
    float* b1p = W + OFF_B1P;
    float* b1c = W + OFF_B1C;
    unsigned short* wt2p16 = (unsigned short*)(W + OFF_WT2P);
    unsigned short* wt2c16 = (unsigned short*)(W + OFF_WT2C);
    float* b2p = W + OFF_B2P;
    float* b2c = W + OFF_B2C;
    float* yp   = W + OFF_YP;
    float* yc   = W + OFF_YC;
    unsigned short* Qb16 = (unsigned short*)(W + OFF_Q);
    unsigned short* Kb16 = (unsigned short*)(W + OFF_K);
    unsigned short* VF16 = (unsigned short*)(W + OFF_V);
    unsigned short* Pb16 = (unsigned short*)(W + OFF_PB);
    unsigned short* Cb16 = (unsigned short*)(W + OFF_CB);
    float* GP   = W + OFF_GP;
    float* G    = W + OFF_G;
    unsigned short* xT16  = (unsigned short*)(W + OFF_PB);  // alias, dead after conv1
    unsigned short* zb16  = (unsigned short*)(W + OFF_Z);
    float* out  = (float*)d_out;

    hipMemsetAsync(zb16, 0, 4096 * sizeof(float), stream);

    x_transpose<<<dim3(64, 4, 4), 256, 0, stream>>>(x, xT16);
    prep_conv_mfma<<<2304, 256, 0, stream>>>(wp1, gp1, bp1, mp1, vp1, wb2p16, b1p, 512, 128);
    prep_conv_mfma<<<2304, 256, 0, stream>>>(wc1, gc1, bc1, mc1, vc1, wb2c16, b1c, 512, 128);
    prep_conv_mfma<<<144,  256, 0, stream>>>(wp2, gp2, bp2, mp2, vp2, wt2p16, b2p, 128, 32);
    prep_conv_mfma<<<144,  256, 0, stream>>>(wc2, gc2, bc2, mc2, vc2, wt2c16, b2c, 128, 32);

    conv1_mfma<<<dim3(128, 4), 256, 0, stream>>>(xT16, wb2p16, wb2c16, b1p, b1c, yp, yc, zb16);

    pam_proj<<<dim3(64, 4), 256, 0, stream>>>(yp, pwb, pbb, pwc, pbc, pwd, pbd, Qb16, Kb16, VF16);
    pam_attn_mfma<<<512, 512, 0, stream>>>(Qb16, Kb16, VF16, yp, alpha, Pb16);

    cam_gram_mfma<<<dim3(16, 4), 256, 0, stream>>>(yc, GP);
    cam_gram_reduce<<<dim3(16, 4), 256, 0, stream>>>(GP, G);
    cam_apply<<<dim3(64, 4), 256, 0, stream>>>(G, yc, beta, Cb16);

    conv2_mfma<<<128, 256, 0, stream>>>(Pb16, Cb16, wt2p16, wt2c16, b2p, b2c, out, zb16);
}